// Round 10
// baseline (390.016 us; speedup 1.0000x reference)
//
#include <hip/hip_runtime.h>
#include <hip/hip_bf16.h>

#define B_ 2
#define N_ 2048
#define C_ 1024
#define H_ 16
#define D_ 64
#define F_ 4096
#define M_ 4096  // B_*N_

typedef __attribute__((ext_vector_type(8))) short bf16x8;
typedef __attribute__((ext_vector_type(4))) float f32x4;

__device__ inline unsigned short f2bf(float f) {
  unsigned int u = __float_as_uint(f);
  u = (u + 0x7FFFu + ((u >> 16) & 1u)) >> 16;
  return (unsigned short)u;
}
__device__ inline float bf2f(unsigned short u) {
  unsigned int x = ((unsigned int)u) << 16;
  return __uint_as_float(x);
}

// ---------------- all-weights fp32 -> bf16 in one launch ---------------------
__global__ __launch_bounds__(256)
void cvt_all(const float4* __restrict__ s0, const float4* __restrict__ s1,
             const float4* __restrict__ s2, const float4* __restrict__ s3,
             const float4* __restrict__ s4, const float4* __restrict__ s5,
             ushort4* __restrict__ d0, ushort4* __restrict__ d1,
             ushort4* __restrict__ d2, ushort4* __restrict__ d3,
             ushort4* __restrict__ d4, ushort4* __restrict__ d5) {
  int b = blockIdx.x;
  const float4* s; ushort4* d; int i;
  if      (b < 1024) { s = s0; d = d0; i = b * 256 + threadIdx.x; }
  else if (b < 2048) { s = s1; d = d1; i = (b - 1024) * 256 + threadIdx.x; }
  else if (b < 3072) { s = s2; d = d2; i = (b - 2048) * 256 + threadIdx.x; }
  else if (b < 4096) { s = s3; d = d3; i = (b - 3072) * 256 + threadIdx.x; }
  else if (b < 8192) { s = s4; d = d4; i = (b - 4096) * 256 + threadIdx.x; }
  else               { s = s5; d = d5; i = (b - 8192) * 256 + threadIdx.x; }
  float4 f = s[i];
  ushort4 o;
  o.x = f2bf(f.x); o.y = f2bf(f.y); o.z = f2bf(f.z); o.w = f2bf(f.w);
  d[i] = o;
}

// ---------------- LayerNorm: fp32 in -> bf16 out ------------------------------
__global__ __launch_bounds__(256)
void ln_kernel(const float* __restrict__ x, const float* __restrict__ g,
               const float* __restrict__ b, unsigned short* __restrict__ out) {
  __shared__ float red[8];
  const int row = blockIdx.x;
  const int t = threadIdx.x;
  const float4 xv = *(const float4*)(x + row * 1024 + t * 4);
  float s  = xv.x + xv.y + xv.z + xv.w;
  float sq = xv.x * xv.x + xv.y * xv.y + xv.z * xv.z + xv.w * xv.w;
  #pragma unroll
  for (int off = 32; off >= 1; off >>= 1) {
    s  += __shfl_down(s, off);
    sq += __shfl_down(sq, off);
  }
  const int lane = t & 63, wave = t >> 6;
  if (lane == 0) { red[wave * 2] = s; red[wave * 2 + 1] = sq; }
  __syncthreads();
  float ts = red[0] + red[2] + red[4] + red[6];
  float tq = red[1] + red[3] + red[5] + red[7];
  float mean = ts * (1.0f / 1024.0f);
  float var  = tq * (1.0f / 1024.0f) - mean * mean;
  float rstd = rsqrtf(var + 1e-6f);
  float xs[4] = {xv.x, xv.y, xv.z, xv.w};
  #pragma unroll
  for (int i = 0; i < 4; i++) {
    int c = t * 4 + i;
    float y = (xs[i] - mean) * rstd * g[c] + b[c];
    out[row * 1024 + c] = f2bf(y);
  }
}

// ---------------- GEMM (128x64 tile, 3-buffer counted-vmcnt, T2, m-local) ----
// MODE 1: +bias +resid -> fp32 [O-proj]  MODE 2: +bias GELU -> bf16 [MLP1]
// MODE 3: +bias +resid -> fp32 [MLP2 -> d_out]
// T4 loop with EARLY stage issue: stage(kt+2) at the TOP of the iteration
// (the target buffer (cur+2)%3 was sealed by the previous barrier), giving
// each load ~2 iterations of latency cover instead of ~1. End-of-iter
// vmcnt(6) ledger unchanged: outstanding = 6(t+1, issued top of kt-1) +
// 6(t+2, issued top of kt) = 12 -> retires exactly t+1. Tail uses vmcnt(0)
// (at kt=nk-2 only 6 outstanding; vmcnt(6) would be a no-op).
template<int MODE, int BN>
__global__ __launch_bounds__(256)
void gemm_bt(const unsigned short* __restrict__ A,
             const unsigned short* __restrict__ Bw,
             int K, int Nout, int npc,
             const float* __restrict__ bias,
             const float* __restrict__ resid,
             unsigned short* __restrict__ out_bf,
             float* __restrict__ out_f32) {
  constexpr int NJ = BN / 32;
  static_assert(BN == 64, "vmcnt literal assumes 6 loads per stage");
  __shared__ unsigned short sA[3][128 * 64];
  __shared__ unsigned short sB[3][BN * 64];
  const int t = threadIdx.x;
  const int wave = t >> 6, lane = t & 63;
  const int quad = lane >> 4, l16 = lane & 15;
  const int wm = (wave & 1) * 64, wn = (wave >> 1) * (BN / 2);
  const int id = blockIdx.y * gridDim.x + blockIdx.x;
  const int xcd = id & 7, r_ = id >> 3;
  const int m_blk = xcd * 4 + (r_ & 3);
  const int n_blk = r_ >> 2;
  const int m0 = m_blk * 128, n0 = n_blk * BN;

  f32x4 acc[4][NJ];
  #pragma unroll
  for (int i = 0; i < 4; i++)
    #pragma unroll
    for (int j = 0; j < NJ; j++) acc[i][j] = (f32x4){0.f, 0.f, 0.f, 0.f};

  const int sc = (((t & 7) ^ ((t >> 3) & 7)) * 8);   // swizzled source chunk
  const unsigned short* gA = A  + (m0 + (t >> 3)) * K + sc;
  const unsigned short* gB = Bw + (n0 + (t >> 3)) * K + sc;

  auto stage = [&](int k0, int buf) {
    unsigned short* lA = &sA[buf][(wave * 8) * 64];
    unsigned short* lB = &sB[buf][(wave * 8) * 64];
    #pragma unroll
    for (int i = 0; i < 4; i++)
      __builtin_amdgcn_global_load_lds((const unsigned int*)(gA + (32 * i) * K + k0),
                                       (unsigned int*)(lA + 32 * i * 64), 16, 0, 0);
    #pragma unroll
    for (int i = 0; i < BN / 32; i++)
      __builtin_amdgcn_global_load_lds((const unsigned int*)(gB + (32 * i) * K + k0),
                                       (unsigned int*)(lB + 32 * i * 64), 16, 0, 0);
  };

  // prologue: tiles 0,1 -> bufs 0,1 (12 loads); retire tile 0 only.
  stage(0, 0);
  stage(64, 1);
  asm volatile("s_waitcnt vmcnt(6)" ::: "memory");
  __builtin_amdgcn_s_barrier();

  const int so0 = ((quad ^ (l16 & 7)) * 8);          // kk=0 read slot
  const int so1 = (((4 + quad) ^ (l16 & 7)) * 8);    // kk=1 read slot

  const int nk = K >> 6;
  int cur = 0;
  for (int kt = 0; kt < nk; kt++) {
    const unsigned short* rA = &sA[cur][0];
    const unsigned short* rB = &sB[cur][0];
    // early prefetch issue (distance 2) — target buffer sealed by prev barrier
    if (kt + 2 < nk) {
      const int nb = (cur + 2 >= 3) ? cur - 1 : cur + 2;   // (kt+2)%3
      stage((kt + 2) * 64, nb);
    }
    #pragma unroll
    for (int kk = 0; kk < 2; kk++) {
      const int so = kk ? so1 : so0;
      bf16x8 af[4], bfr[NJ];
      #pragma unroll
      for (int i = 0; i < 4; i++)
        af[i] = *(const bf16x8*)(&rA[(wm + i * 16 + l16) * 64 + so]);
      #pragma unroll
      for (int j = 0; j < NJ; j++)
        bfr[j] = *(const bf16x8*)(&rB[(wn + j * 16 + l16) * 64 + so]);
      #pragma unroll
      for (int i = 0; i < 4; i++)
        #pragma unroll
        for (int j = 0; j < NJ; j++)
          acc[i][j] = __builtin_amdgcn_mfma_f32_16x16x32_bf16(af[i], bfr[j], acc[i][j], 0, 0, 0);
    }
    if (kt + 2 < nk) {
      asm volatile("s_waitcnt vmcnt(6)" ::: "memory");
    } else {
      asm volatile("s_waitcnt vmcnt(0)" ::: "memory");
    }
    __builtin_amdgcn_s_barrier();
    cur = (cur == 2) ? 0 : cur + 1;
  }

  #pragma unroll
  for (int i = 0; i < 4; i++) {
    #pragma unroll
    for (int j = 0; j < NJ; j++) {
      int col = n0 + wn + j * 16 + l16;
      #pragma unroll
      for (int r = 0; r < 4; r++) {
        int row = m0 + wm + i * 16 + quad * 4 + r;
        float v = acc[i][j][r];
        if (MODE == 1 || MODE == 3) {
          out_f32[row * Nout + col] = v + bias[col] + resid[row * Nout + col];
        } else {
          v += bias[col];
          float w = v * (1.0f + 0.044715f * v * v);
          float gl = v / (1.0f + __expf(-1.5957691216f * w));
          out_bf[row * Nout + col] = f2bf(gl);
        }
      }
    }
  }
}

// ---------------- 256x256 counted-vmcnt pipelined GEMM core, v2 --------------
// (round-8 verified; used for QKV only — best measured structure for it)
template<int EPI>
__global__ __launch_bounds__(512, 1)
void gemm256(const unsigned short* __restrict__ A,
             const unsigned short* __restrict__ Bw,
             const float* __restrict__ bias,
             const float* __restrict__ bq, const float* __restrict__ bk,
             const float* __restrict__ bv,
             const float* __restrict__ rc, const float* __restrict__ rs,
             unsigned short* __restrict__ o0,   // EPI0: out_bf ; EPI1: qo
             unsigned short* __restrict__ ko, unsigned short* __restrict__ vt) {
  const int K = 1024;
  __shared__ unsigned short sA[2][256 * 64];
  __shared__ unsigned short sB[2][256 * 64];
  const int t = threadIdx.x;
  const int wave = t >> 6, lane = t & 63;
  const int quad = lane >> 4, l16 = lane & 15;
  const int wm = (wave & 1) * 128, wn = (wave >> 1) * 64;
  const int id = blockIdx.x;
  const int xcd = id & 7, r_ = id >> 3;
  int m_blk, n_blk;
  if (EPI == 0) { n_blk = xcd * 2 + (r_ >> 4); m_blk = r_ & 15; }   // B-local
  else          { m_blk = xcd * 2 + r_ / 12;   n_blk = r_ % 12; }   // A-local
  const int m0 = m_blk * 256, n0 = n_blk * 256;

  f32x4 acc[8][4];
  #pragma unroll
  for (int i = 0; i < 8; i++)
    #pragma unroll
    for (int j = 0; j < 4; j++) acc[i][j] = (f32x4){0.f, 0.f, 0.f, 0.f};

  const int sc = (((t & 7) ^ ((t >> 3) & 7)) * 8);
  const unsigned short* gA = A  + (m0 + (t >> 3)) * K + sc;
  const unsigned short* gB = Bw + (n0 + (t >> 3)) * K + sc;

  auto stage_pair = [&](int k0, int buf, int pr) {
    if (pr < 2) {
      unsigned short* lA = &sA[buf][(wave * 8) * 64];
      #pragma unroll
      for (int r = pr * 2; r < pr * 2 + 2; r++)
        __builtin_amdgcn_global_load_lds((const unsigned int*)(gA + (64 * r) * K + k0),
                                         (unsigned int*)(lA + 64 * r * 64), 16, 0, 0);
    } else {
      unsigned short* lB = &sB[buf][(wave * 8) * 64];
      #pragma unroll
      for (int r = (pr - 2) * 2; r < (pr - 2) * 2 + 2; r++)
        __builtin_amdgcn_global_load_lds((const unsigned int*)(gB + (64 * r) * K + k0),
                                         (unsigned int*)(lB + 64 * r * 64), 16, 0, 0);
    }
  };

  stage_pair(0, 0, 0); stage_pair(0, 0, 1); stage_pair(0, 0, 2); stage_pair(0, 0, 3);
  stage_pair(64, 1, 0);
  asm volatile("s_waitcnt vmcnt(2)" ::: "memory");
  __builtin_amdgcn_s_barrier();

  const int so0 = ((quad ^ (l16 & 7)) * 8);
  const int so1 = (((4 + quad) ^ (l16 & 7)) * 8);

  const int nk = K >> 6;   // 16
  for (int t_ = 0; t_ < nk; t_++) {
    const int R = t_ & 1;
    const unsigned short* rA = sA[R];
    const unsigned short* rB = sB[R];
    #pragma unroll
    for (int kk = 0; kk < 2; kk++) {
      const int so = kk ? so1 : so0;
      bf16x8 af[8], bfr[4];
      #pragma unroll
      for (int ii = 0; ii < 8; ii++)
        af[ii] = *(const bf16x8*)(&rA[(wm + ii * 16 + l16) * 64 + so]);
      #pragma unroll
      for (int j = 0; j < 4; j++)
        bfr[j] = *(const bf16x8*)(&rB[(wn + j * 16 + l16) * 64 + so]);
      if (t_ + 1 < nk) {
        if (kk == 0) {
          stage_pair((t_ + 1) * 64, R ^ 1, 1);
        } else {
          stage_pair((t_ + 1) * 64, R ^ 1, 2);
          stage_pair((t_ + 1) * 64, R ^ 1, 3);
        }
      }
      __builtin_amdgcn_s_barrier();
      asm volatile("s_waitcnt lgkmcnt(0)" ::: "memory");
      __builtin_amdgcn_sched_barrier(0);
      __builtin_amdgcn_s_setprio(1);
      #pragma unroll
      for (int ii = 0; ii < 8; ii++)
        #pragma unroll
        for (int j = 0; j < 4; j++)
          acc[ii][j] =
              __builtin_amdgcn_mfma_f32_16x16x32_bf16(af[ii], bfr[j], acc[ii][j], 0, 0, 0);
      __builtin_amdgcn_s_setprio(0);
      if (kk == 0) __builtin_amdgcn_s_barrier();
    }
    __builtin_amdgcn_s_barrier();          // seals reads of buf R
    if (t_ + 2 < nk) {
      stage_pair((t_ + 2) * 64, R, 0);     // pair0 of t+2 into freed buf
      asm volatile("s_waitcnt vmcnt(2)" ::: "memory");
      __builtin_amdgcn_s_barrier();
    } else if (t_ + 1 < nk) {
      asm volatile("s_waitcnt vmcnt(0)" ::: "memory");
      __builtin_amdgcn_s_barrier();
    }
  }

  if (EPI == 0) {
    #pragma unroll
    for (int i = 0; i < 8; i++) {
      #pragma unroll
      for (int j = 0; j < 4; j++) {
        int col = n0 + wn + j * 16 + l16;
        float bb = bias[col];
        #pragma unroll
        for (int r = 0; r < 4; r++) {
          int row = m0 + wm + i * 16 + quad * 4 + r;
          float v = acc[i][j][r] + bb;
          float w = v * (1.0f + 0.044715f * v * v);
          float gl = v / (1.0f + __expf(-1.5957691216f * w));
          o0[row * 4096 + col] = f2bf(gl);
        }
      }
    }
  } else {
    const int rgn = n_blk >> 2;                 // 0=q, 1=k, 2=v
    const int c0 = (n_blk & 3) * 256;
    if (rgn == 2) {
      #pragma unroll
      for (int i = 0; i < 8; i++) {
        int row0 = m0 + wm + i * 16 + quad * 4;
        int bidx = row0 >> 11, n0r = row0 & 2047;
        #pragma unroll
        for (int j = 0; j < 4; j++) {
          int d = j * 16 + l16;
          int c = c0 + wn + d;
          int h = c >> 6;
          float bb = bv[c];
          __hip_bfloat162 p01 = __float22bfloat162_rn(float2{acc[i][j][0] + bb, acc[i][j][1] + bb});
          __hip_bfloat162 p23 = __float22bfloat162_rn(float2{acc[i][j][2] + bb, acc[i][j][3] + bb});
          unsigned int u01, u23;
          __builtin_memcpy(&u01, &p01, 4);
          __builtin_memcpy(&u23, &p23, 4);
          *(uint2*)(vt + (((bidx * 16 + h) * 64) + d) * 2048 + n0r) = make_uint2(u01, u23);
        }
      }
    } else {
      const float* bia = (rgn == 0) ? bq : bk;
      unsigned short* outp = (rgn == 0) ? o0 : ko;
      #pragma unroll
      for (int i = 0; i < 8; i++) {
        #pragma unroll
        for (int r = 0; r < 4; r++) {
          int row = m0 + wm + i * 16 + quad * 4 + r;
          int bidx = row >> 11, n = row & 2047;
          #pragma unroll
          for (int j = 0; j < 4; j++) {
            int d = j * 16 + l16;
            int c = c0 + wn + d;
            int h = c >> 6;
            int oi = ((bidx * 16 + h) * 2048 + n) * 64 + d;
            float val = acc[i][j][r] + bia[c];
            float pv  = acc[i][j ^ 2][r] + bia[c ^ 32];
            float rot = (j < 2) ? -pv : pv;          // rotate_half
            float y = val * rc[n * 64 + d] + rot * rs[n * 64 + d];
            if (rgn == 0) y *= 0.125f;               // fold D^-0.5 into q
            outp[oi] = f2bf(y);
          }
        }
      }
    }
  }
}

// ---------------- Flash attention v7: 8-wave blocks + kv-split ---------------
__global__ __launch_bounds__(512)
void flash_attn(const unsigned short* __restrict__ q,
                const unsigned short* __restrict__ k,
                const unsigned short* __restrict__ vt,
                unsigned short* __restrict__ o0h,
                unsigned short* __restrict__ o1h,
                float* __restrict__ l0g, float* __restrict__ l1g) {
  __shared__ unsigned short sK[2][64 * 64];
  __shared__ unsigned short sVt[2][64 * 64];
  __shared__ unsigned short sPt[2][8][16 * 72];
  const int t = threadIdx.x;
  const int wave = t >> 6, lane = t & 63;
  const int quad = lane >> 4, l16 = lane & 15;
  const int id = blockIdx.x;
  const int bh = (id & 7) * 4 + ((id >> 3) & 3);  // 4 heads per XCD (L2-local)
  const int qb = (id >> 5) & 7;                   // 8 blocks of 256 q-rows
  const int kvh = id >> 8;                        // kv half
  const int base = bh * (N_ * D_);

  bf16x8 qa[2][2];
  #pragma unroll
  for (int qt = 0; qt < 2; qt++) {
    int qrow = qb * 256 + wave * 32 + qt * 16 + l16;
    #pragma unroll
    for (int kk = 0; kk < 2; kk++)
      qa[qt][kk] = *(const bf16x8*)(q + base + qrow * D_ + kk * 32 + quad * 8);
  }
  float l_i[2] = {0.f, 0.f};
  f32x4 o_acc[2][4];
  #pragma unroll
  for (int qt = 0; qt < 2; qt++)
    #pragma unroll
    for (int dt = 0; dt < 4; dt++) o_acc[qt][dt] = (f32x4){0.f, 0.f, 0.f, 0.f};

  const int sc = (((t & 7) ^ ((t >> 3) & 7)) * 8);   // T2 source chunk
  const unsigned short* gK  = k  + base + (t >> 3) * 64 + sc;
  const unsigned short* gVt = vt + bh * (64 * 2048) + (t >> 3) * 2048 + sc;

  auto stage = [&](int kt, int buf) {
    __builtin_amdgcn_global_load_lds((const unsigned int*)(gK + kt * 64 * 64),
                                     (unsigned int*)(&sK[buf][(wave * 8) * 64]), 16, 0, 0);
    __builtin_amdgcn_global_load_lds((const unsigned int*)(gVt + kt * 64),
                                     (unsigned int*)(&sVt[buf][(wave * 8) * 64]), 16, 0, 0);
  };
  const int kt0 = kvh * 16, kt1 = kt0 + 16;
  stage(kt0, 0);
  __syncthreads();

  const int so0 = ((quad ^ (l16 & 7)) * 8);          // kk=0 read slot
  const int so1 = (((4 + quad) ^ (l16 & 7)) * 8);    // kk=1 read slot

  for (int kt = kt0; kt < kt1; kt++) {
    const int cur = kt & 1;
    if (kt + 1 < kt1) stage(kt + 1, cur ^ 1);

    f32x4 s_acc[2][4];
    #pragma unroll
    for (int nt = 0; nt < 4; nt++) {
      bf16x8 kb0 = *(const bf16x8*)(&sK[cur][(nt * 16 + l16) * 64 + so0]);
      bf16x8 kb1 = *(const bf16x8*)(&sK[cur][(nt * 16 + l16) * 64 + so1]);
      #pragma unroll
      for (int qt = 0; qt < 2; qt++) {
        f32x4 a = (f32x4){0.f, 0.f, 0.f, 0.f};
        a = __builtin_amdgcn_mfma_f32_16x16x32_bf16(kb0, qa[qt][0], a, 0, 0, 0);
        a = __builtin_amdgcn_mfma_f32_16x16x32_bf16(kb1, qa[qt][1], a, 0, 0, 0);
        s_acc[qt][nt] = a;
      }
    }
    #pragma unroll
    for (int qt = 0; qt < 2; qt++) {
      float rsum = 0.f;
      #pragma unroll
      for (int nt = 0; nt < 4; nt++)
        #pragma unroll
        for (int r = 0; r < 4; r++) {
          float p = __expf(s_acc[qt][nt][r]);
          s_acc[qt][nt][r] = p;
          rsum += p;
        }
      rsum += __shfl_xor(rsum, 16);
      rsum += __shfl_xor(rsum, 32);
      l_i[qt] += rsum;
      #pragma unroll
      for (int nt = 0; nt < 4; nt++) {
        __hip_bfloat162 p01 = __float22bfloat162_rn(float2{s_acc[qt][nt][0], s_acc[qt][nt][1]});
        __hip_bfloat162 p23 = __float22bfloat162_rn(float2{s_acc[qt][nt][2], s_acc[qt][nt][3]});
        unsigned int u01, u23;
        __builtin_memcpy(&u01, &p01, 4);
        __builtin_memcpy(&u23, &p23, 4);
        *(uint2*)(&sPt[qt][wave][l16 * 72 + nt * 16 + quad * 4]) = make_uint2(u01, u23);
      }
    }
    __asm__ volatile("s_waitcnt lgkmcnt(0)" ::: "memory");
    bf16x8 pt[2][2];
    #pragma unroll
    for (int qt = 0; qt < 2; qt++) {
      pt[qt][0] = *(const bf16x8*)(&sPt[qt][wave][l16 * 72 + quad * 8]);
      pt[qt][1] = *(const bf16x8*)(&sPt[qt][wave][l16 * 72 + 32 + quad * 8]);
    }
    #pragma unroll
    for (int dt = 0; dt < 4; dt++) {
      int d0 = dt * 16 + l16;
      bf16x8 va0 = *(const bf16x8*)(&sVt[cur][d0 * 64 + so0]);
      bf16x8 va1 = *(const bf16x8*)(&sVt[cur][d0 * 64 + so1]);
      #pragma unroll
      for (int qt = 0; qt < 2; qt++) {
        o_acc[qt][dt] = __builtin_amdgcn_mfma_f32_16x16x32_bf16(va0, pt[qt][0], o_acc[qt][dt], 0, 0, 0);
        o_acc[qt][dt] = __builtin_amdgcn_mfma_f32_16x16x32_bf16(va1, pt[qt][1], o_acc[qt][dt], 0, 0, 0);
      }
    }
    __syncthreads();
  }

  unsigned short* op = kvh ? o1h : o0h;
  float* lp = kvh ? l1g : l0g;
  const int b = bh >> 4, h = bh & 15;
  #pragma unroll
  for (int qt = 0; qt < 2; qt++) {
    const int qrow = qb * 256 + wave * 32 + qt * 16 + l16;
    if (quad == 0) lp[bh * 2048 + qrow] = l_i[qt];
    const int tok = b * N_ + qrow;
    #pragma unroll
    for (int dt = 0; dt < 4; dt++) {
      __hip_bfloat162 p01 = __float22bfloat162_rn(float2{o_acc[qt][dt][0], o_acc[qt][dt][1]});
      __hip_bfloat162 p23 = __float22bfloat162_rn(float2{o_acc[qt][dt][2], o_acc[qt][dt][3]});
      unsigned int u01, u23;
      __builtin_memcpy(&u01, &p01, 4);
      __builtin_memcpy(&u23, &p23, 4);
      int col = h * 64 + dt * 16 + quad * 4;
      *(uint2*)(op + tok * C_ + col) = make_uint2(u01, u23);
    }
  }
}

// ---------------- combine the two kv halves: ao = (o0+o1)/(l0+l1) ------------
__global__ __launch_bounds__(256)
void attn_norm(const unsigned short* __restrict__ o0h,
               const unsigned short* __restrict__ o1h,
               const float* __restrict__ l0g, const float* __restrict__ l1g,
               unsigned short* __restrict__ o) {
  const int i = (blockIdx.x * 256 + threadIdx.x) * 8;
  const int row = i >> 10, c = i & 1023;
  const int h = c >> 6;
  const int b = row >> 11, n = row & 2047;
  const int li = (b * 16 + h) * 2048 + n;
  const float inv = 1.0f / (l0g[li] + l1g[li]);
  ushort4 a0 = *(const ushort4*)(o0h + i);
  ushort4 a1 = *(const ushort4*)(o0h + i + 4);
  ushort4 b0 = *(const ushort4*)(o1h + i);
  ushort4 b1 = *(const ushort4*)(o1h + i + 4);
  ushort4 r0, r1;
  r0.x = f2bf((bf2f(a0.x) + bf2f(b0.x)) * inv);
  r0.y = f2bf((bf2f(a0.y) + bf2f(b0.y)) * inv);
  r0.z = f2bf((bf2f(a0.z) + bf2f(b0.z)) * inv);
  r0.w = f2bf((bf2f(a0.w) + bf2f(b0.w)) * inv);
  r1.x = f2bf((bf2f(a1.x) + bf2f(b1.x)) * inv);
  r1.y = f2bf((bf2f(a1.y) + bf2f(b1.y)) * inv);
  r1.z = f2bf((bf2f(a1.z) + bf2f(b1.z)) * inv);
  r1.w = f2bf((bf2f(a1.w) + bf2f(b1.w)) * inv);
  *(ushort4*)(o + i) = r0;
  *(ushort4*)(o + i + 4) = r1;
}

// ---------------- launcher ---------------------------------------------------
extern "C" void kernel_launch(void* const* d_in, const int* in_sizes, int n_in,
                              void* d_out, int out_size, void* d_ws, size_t ws_size,
                              hipStream_t stream) {
  const float* x   = (const float*)d_in[0];
  const float* rc  = (const float*)d_in[1];
  const float* rs  = (const float*)d_in[2];
  const float* g1  = (const float*)d_in[3];
  const float* be1 = (const float*)d_in[4];
  const float* Wq  = (const float*)d_in[5];
  const float* bq  = (const float*)d_in[6];
  const float* Wk  = (const float*)d_in[7];
  const float* bk  = (const float*)d_in[8];
  const float* Wv  = (const float*)d_in[9];
  const float* bv  = (const float*)d_in[10];
  const float* Wo  = (const float*)d_in[11];
  const float* bo  = (const float*)d_in[12];
  const float* g2  = (const float*)d_in[13];
  const float* be2 = (const float*)d_in[14];
  const float* W1  = (const float*)d_in[15];
  const float* b1m = (const float*)d_in[16];
  const float* W2  = (const float*)d_in[17];
  const float* b2m = (const float*)d_in[18];
  float* out = (float*)d_out;

  char* ws = (char*)d_ws;
  unsigned short* wqkv = (unsigned short*)(ws + 0);           // 6 MB
  unsigned short* wo   = (unsigned short*)(ws + 6291456);     // 2 MB
  unsigned short* w1   = (unsigned short*)(ws + 8388608);     // 8 MB
  unsigned short* w2   = (unsigned short*)(ws + 16777216);    // 8 MB
  unsigned short* h1   = (unsigned short*)(ws + 25165824);    // 8 MB (ln out; attn o1 partial; ln2 out)
  unsigned short* qa   = (unsigned short*)(ws + 33554432);    // 8 MB
  unsigned short* ka   = (unsigned short*)(ws + 41943040);    // 8 MB
  unsigned short* va   = (unsigned short*)(ws + 50331648);    // 8 MB (V^T: B*H x D x N)
  unsigned short* ao   = (unsigned short*)(ws + 58720256);    // 8 MB (attn o0 partial -> normalized)
  float*          x1   = (float*)(ws + 67108864);             // 16 MB
  float*          l0   = (float*)(ws + 67108864);             // 256 KB (dead before x1 written)
  float*          l1   = l0 + 65536;                          // 256 KB
  unsigned short* u    = (unsigned short*)(ws + 33554432);    // overlays qa..ao (dead by MLP1)

  cvt_all<<<12288, 256, 0, stream>>>(
      (const float4*)Wq, (const float4*)Wk, (const float4*)Wv, (const float4*)Wo,
      (const float4*)W1, (const float4*)W2,
      (ushort4*)wqkv, (ushort4*)(wqkv + 1048576), (ushort4*)(wqkv + 2097152),
      (ushort4*)wo, (ushort4*)w1, (ushort4*)w2);

  ln_kernel<<<4096, 256, 0, stream>>>(x, g1, be1, h1);
  gemm256<1><<<192, 512, 0, stream>>>(h1, wqkv, nullptr, bq, bk, bv, rc, rs, qa, ka, va);
  flash_attn<<<512, 512, 0, stream>>>(qa, ka, va, ao, h1, l0, l1);
  attn_norm<<<2048, 256, 0, stream>>>(ao, h1, l0, l1, ao);
  gemm_bt<1, 64><<<dim3(16, 32), 256, 0, stream>>>(ao, wo, 1024, 1024, 2, bo, x, nullptr, x1);
  ln_kernel<<<4096, 256, 0, stream>>>(x1, g2, be2, h1);
  gemm_bt<2, 64><<<dim3(16, 128), 256, 0, stream>>>(h1, w1, 1024, 4096, 8, b1m, nullptr, u, nullptr);
  gemm_bt<3, 64><<<dim3(16, 32), 256, 0, stream>>>(u, w2, 4096, 1024, 2, b2m, x1, nullptr, out);
}

// Round 11
// 360.067 us; speedup vs baseline: 1.0832x; 1.0832x over previous
//
#include <hip/hip_runtime.h>
#include <hip/hip_bf16.h>

#define B_ 2
#define N_ 2048
#define C_ 1024
#define H_ 16
#define D_ 64
#define F_ 4096
#define M_ 4096  // B_*N_

typedef __attribute__((ext_vector_type(8))) short bf16x8;
typedef __attribute__((ext_vector_type(4))) float f32x4;

__device__ inline unsigned short f2bf(float f) {
  unsigned int u = __float_as_uint(f);
  u = (u + 0x7FFFu + ((u >> 16) & 1u)) >> 16;
  return (unsigned short)u;
}
__device__ inline float bf2f(unsigned short u) {
  unsigned int x = ((unsigned int)u) << 16;
  return __uint_as_float(x);
}

// ---------------- fused: all-weights fp32->bf16  +  LayerNorm1 ---------------
// Blocks [0,12288): weight convert (identical to old cvt_all).
// Blocks [12288,16384): LN rows (identical to ln_kernel).
// Both pure-BW; merging removes one dispatch and shares the BW window.
// All outputs complete at kernel end -> ready for gemm_qkv_t4.
__global__ __launch_bounds__(256)
void ln1_cvt(const float* __restrict__ x, const float* __restrict__ g,
             const float* __restrict__ bln, unsigned short* __restrict__ out,
             const float4* __restrict__ s0, const float4* __restrict__ s1,
             const float4* __restrict__ s2, const float4* __restrict__ s3,
             const float4* __restrict__ s4, const float4* __restrict__ s5,
             ushort4* __restrict__ d0, ushort4* __restrict__ d1,
             ushort4* __restrict__ d2, ushort4* __restrict__ d3,
             ushort4* __restrict__ d4, ushort4* __restrict__ d5) {
  const int b = blockIdx.x;
  if (b < 12288) {
    const float4* s; ushort4* d; int i;
    if      (b < 1024) { s = s0; d = d0; i = b * 256 + threadIdx.x; }
    else if (b < 2048) { s = s1; d = d1; i = (b - 1024) * 256 + threadIdx.x; }
    else if (b < 3072) { s = s2; d = d2; i = (b - 2048) * 256 + threadIdx.x; }
    else if (b < 4096) { s = s3; d = d3; i = (b - 3072) * 256 + threadIdx.x; }
    else if (b < 8192) { s = s4; d = d4; i = (b - 4096) * 256 + threadIdx.x; }
    else               { s = s5; d = d5; i = (b - 8192) * 256 + threadIdx.x; }
    float4 f = s[i];
    ushort4 o;
    o.x = f2bf(f.x); o.y = f2bf(f.y); o.z = f2bf(f.z); o.w = f2bf(f.w);
    d[i] = o;
    return;
  }
  __shared__ float red[8];
  const int row = b - 12288;
  const int t = threadIdx.x;
  const float4 xv = *(const float4*)(x + row * 1024 + t * 4);
  float s  = xv.x + xv.y + xv.z + xv.w;
  float sq = xv.x * xv.x + xv.y * xv.y + xv.z * xv.z + xv.w * xv.w;
  #pragma unroll
  for (int off = 32; off >= 1; off >>= 1) {
    s  += __shfl_down(s, off);
    sq += __shfl_down(sq, off);
  }
  const int lane = t & 63, wave = t >> 6;
  if (lane == 0) { red[wave * 2] = s; red[wave * 2 + 1] = sq; }
  __syncthreads();
  float ts = red[0] + red[2] + red[4] + red[6];
  float tq = red[1] + red[3] + red[5] + red[7];
  float mean = ts * (1.0f / 1024.0f);
  float var  = tq * (1.0f / 1024.0f) - mean * mean;
  float rstd = rsqrtf(var + 1e-6f);
  float xs[4] = {xv.x, xv.y, xv.z, xv.w};
  #pragma unroll
  for (int i = 0; i < 4; i++) {
    int c = t * 4 + i;
    float y = (xs[i] - mean) * rstd * g[c] + bln[c];
    out[row * 1024 + c] = f2bf(y);
  }
}

// ---------------- LayerNorm: fp32 in -> bf16 out (ln2) ------------------------
__global__ __launch_bounds__(256)
void ln_kernel(const float* __restrict__ x, const float* __restrict__ g,
               const float* __restrict__ b, unsigned short* __restrict__ out) {
  __shared__ float red[8];
  const int row = blockIdx.x;
  const int t = threadIdx.x;
  const float4 xv = *(const float4*)(x + row * 1024 + t * 4);
  float s  = xv.x + xv.y + xv.z + xv.w;
  float sq = xv.x * xv.x + xv.y * xv.y + xv.z * xv.z + xv.w * xv.w;
  #pragma unroll
  for (int off = 32; off >= 1; off >>= 1) {
    s  += __shfl_down(s, off);
    sq += __shfl_down(sq, off);
  }
  const int lane = t & 63, wave = t >> 6;
  if (lane == 0) { red[wave * 2] = s; red[wave * 2 + 1] = sq; }
  __syncthreads();
  float ts = red[0] + red[2] + red[4] + red[6];
  float tq = red[1] + red[3] + red[5] + red[7];
  float mean = ts * (1.0f / 1024.0f);
  float var  = tq * (1.0f / 1024.0f) - mean * mean;
  float rstd = rsqrtf(var + 1e-6f);
  float xs[4] = {xv.x, xv.y, xv.z, xv.w};
  #pragma unroll
  for (int i = 0; i < 4; i++) {
    int c = t * 4 + i;
    float y = (xs[i] - mean) * rstd * g[c] + b[c];
    out[row * 1024 + c] = f2bf(y);
  }
}

// ---------------- GEMM (128x64 tile, 3-buffer counted-vmcnt, T2, m-local) ----
// MODE 1: +bias +resid -> fp32 [O-proj]  MODE 2: +bias GELU -> bf16 [MLP1]
// MODE 3: +bias +resid -> fp32 [MLP2 -> d_out]
// Round-9 verified T4 loop (LATE stage issue — the round-10 early-issue code
// motion regressed +3 us/kernel and was reverted): 3-buffer rotation,
// prefetch distance 2, counted vmcnt(6) + raw s_barrier; never drains to 0
// in steady state. Ledger: at the wait, outstanding = 6(t+1) + 6(t+2) = 12
// -> vmcnt(6) retires exactly tile t+1, leaves t+2 in flight.
template<int MODE, int BN>
__global__ __launch_bounds__(256)
void gemm_bt(const unsigned short* __restrict__ A,
             const unsigned short* __restrict__ Bw,
             int K, int Nout, int npc,
             const float* __restrict__ bias,
             const float* __restrict__ resid,
             unsigned short* __restrict__ out_bf,
             float* __restrict__ out_f32) {
  constexpr int NJ = BN / 32;
  static_assert(BN == 64, "vmcnt literal assumes 6 loads per stage");
  __shared__ unsigned short sA[3][128 * 64];
  __shared__ unsigned short sB[3][BN * 64];
  const int t = threadIdx.x;
  const int wave = t >> 6, lane = t & 63;
  const int quad = lane >> 4, l16 = lane & 15;
  const int wm = (wave & 1) * 64, wn = (wave >> 1) * (BN / 2);
  const int id = blockIdx.y * gridDim.x + blockIdx.x;
  const int xcd = id & 7, r_ = id >> 3;
  const int m_blk = xcd * 4 + (r_ & 3);
  const int n_blk = r_ >> 2;
  const int m0 = m_blk * 128, n0 = n_blk * BN;

  f32x4 acc[4][NJ];
  #pragma unroll
  for (int i = 0; i < 4; i++)
    #pragma unroll
    for (int j = 0; j < NJ; j++) acc[i][j] = (f32x4){0.f, 0.f, 0.f, 0.f};

  const int sc = (((t & 7) ^ ((t >> 3) & 7)) * 8);   // swizzled source chunk
  const unsigned short* gA = A  + (m0 + (t >> 3)) * K + sc;
  const unsigned short* gB = Bw + (n0 + (t >> 3)) * K + sc;

  auto stage = [&](int k0, int buf) {
    unsigned short* lA = &sA[buf][(wave * 8) * 64];
    unsigned short* lB = &sB[buf][(wave * 8) * 64];
    #pragma unroll
    for (int i = 0; i < 4; i++)
      __builtin_amdgcn_global_load_lds((const unsigned int*)(gA + (32 * i) * K + k0),
                                       (unsigned int*)(lA + 32 * i * 64), 16, 0, 0);
    #pragma unroll
    for (int i = 0; i < BN / 32; i++)
      __builtin_amdgcn_global_load_lds((const unsigned int*)(gB + (32 * i) * K + k0),
                                       (unsigned int*)(lB + 32 * i * 64), 16, 0, 0);
  };

  // prologue: tiles 0,1 -> bufs 0,1 (12 loads); retire tile 0 only.
  stage(0, 0);
  stage(64, 1);
  asm volatile("s_waitcnt vmcnt(6)" ::: "memory");
  __builtin_amdgcn_s_barrier();

  const int so0 = ((quad ^ (l16 & 7)) * 8);          // kk=0 read slot
  const int so1 = (((4 + quad) ^ (l16 & 7)) * 8);    // kk=1 read slot

  const int nk = K >> 6;
  int cur = 0;
  for (int kt = 0; kt < nk; kt++) {
    const unsigned short* rA = &sA[cur][0];
    const unsigned short* rB = &sB[cur][0];
    #pragma unroll
    for (int kk = 0; kk < 2; kk++) {
      const int so = kk ? so1 : so0;
      bf16x8 af[4], bfr[NJ];
      #pragma unroll
      for (int i = 0; i < 4; i++)
        af[i] = *(const bf16x8*)(&rA[(wm + i * 16 + l16) * 64 + so]);
      #pragma unroll
      for (int j = 0; j < NJ; j++)
        bfr[j] = *(const bf16x8*)(&rB[(wn + j * 16 + l16) * 64 + so]);
      #pragma unroll
      for (int i = 0; i < 4; i++)
        #pragma unroll
        for (int j = 0; j < NJ; j++)
          acc[i][j] = __builtin_amdgcn_mfma_f32_16x16x32_bf16(af[i], bfr[j], acc[i][j], 0, 0, 0);
    }
    if (kt + 2 < nk) {
      const int nb = (cur + 2 >= 3) ? cur - 1 : cur + 2;   // (kt+2)%3
      stage((kt + 2) * 64, nb);
      asm volatile("s_waitcnt vmcnt(6)" ::: "memory");
    } else {
      asm volatile("s_waitcnt vmcnt(0)" ::: "memory");
    }
    __builtin_amdgcn_s_barrier();
    cur = (cur == 2) ? 0 : cur + 1;
  }

  #pragma unroll
  for (int i = 0; i < 4; i++) {
    #pragma unroll
    for (int j = 0; j < NJ; j++) {
      int col = n0 + wn + j * 16 + l16;
      #pragma unroll
      for (int r = 0; r < 4; r++) {
        int row = m0 + wm + i * 16 + quad * 4 + r;
        float v = acc[i][j][r];
        if (MODE == 1 || MODE == 3) {
          out_f32[row * Nout + col] = v + bias[col] + resid[row * Nout + col];
        } else {
          v += bias[col];
          float w = v * (1.0f + 0.044715f * v * v);
          float gl = v / (1.0f + __expf(-1.5957691216f * w));
          out_bf[row * Nout + col] = f2bf(gl);
        }
      }
    }
  }
}

// ---------------- QKV GEMM on the T4 skeleton, RoPE epilogue -----------------
// (round-9 verified — part of the 360.4 best config)
__global__ __launch_bounds__(256)
void gemm_qkv_t4(const unsigned short* __restrict__ A,
                 const unsigned short* __restrict__ Bw,
                 const float* __restrict__ bq, const float* __restrict__ bk,
                 const float* __restrict__ bv,
                 const float* __restrict__ rc, const float* __restrict__ rs,
                 unsigned short* __restrict__ qo, unsigned short* __restrict__ ko,
                 unsigned short* __restrict__ vt) {
  const int K = C_;
  __shared__ unsigned short sA[3][128 * 64];
  __shared__ unsigned short sB[3][64 * 64];
  const int t = threadIdx.x;
  const int wave = t >> 6, lane = t & 63;
  const int quad = lane >> 4, l16 = lane & 15;
  const int wm = wave * 32;                        // 4m x 1n wave grid
  const int id = blockIdx.x;                       // [0,1536)
  const int xcd = id & 7, r_ = id >> 3;            // r_ in [0,192)
  const int m_blk = xcd * 4 + (r_ & 3);            // [0,32)  A-local
  const int n_blk = r_ >> 2;                       // [0,48)
  const int m0 = m_blk * 128, n0 = n_blk * 64;

  f32x4 acc[2][4];
  #pragma unroll
  for (int i = 0; i < 2; i++)
    #pragma unroll
    for (int j = 0; j < 4; j++) acc[i][j] = (f32x4){0.f, 0.f, 0.f, 0.f};

  const int sc = (((t & 7) ^ ((t >> 3) & 7)) * 8);
  const unsigned short* gA = A  + (m0 + (t >> 3)) * K + sc;
  const unsigned short* gB = Bw + (n0 + (t >> 3)) * K + sc;

  auto stage = [&](int k0, int buf) {
    unsigned short* lA = &sA[buf][(wave * 8) * 64];
    unsigned short* lB = &sB[buf][(wave * 8) * 64];
    #pragma unroll
    for (int i = 0; i < 4; i++)
      __builtin_amdgcn_global_load_lds((const unsigned int*)(gA + (32 * i) * K + k0),
                                       (unsigned int*)(lA + 32 * i * 64), 16, 0, 0);
    #pragma unroll
    for (int i = 0; i < 2; i++)
      __builtin_amdgcn_global_load_lds((const unsigned int*)(gB + (32 * i) * K + k0),
                                       (unsigned int*)(lB + 32 * i * 64), 16, 0, 0);
  };

  stage(0, 0);
  stage(64, 1);
  asm volatile("s_waitcnt vmcnt(6)" ::: "memory");
  __builtin_amdgcn_s_barrier();

  const int so0 = ((quad ^ (l16 & 7)) * 8);
  const int so1 = (((4 + quad) ^ (l16 & 7)) * 8);

  const int nk = K >> 6;   // 16
  int cur = 0;
  for (int kt = 0; kt < nk; kt++) {
    const unsigned short* rA = &sA[cur][0];
    const unsigned short* rB = &sB[cur][0];
    #pragma unroll
    for (int kk = 0; kk < 2; kk++) {
      const int so = kk ? so1 : so0;
      bf16x8 af[2], bfr[4];
      #pragma unroll
      for (int i = 0; i < 2; i++)
        af[i] = *(const bf16x8*)(&rA[(wm + i * 16 + l16) * 64 + so]);
      #pragma unroll
      for (int j = 0; j < 4; j++)
        bfr[j] = *(const bf16x8*)(&rB[(j * 16 + l16) * 64 + so]);
      #pragma unroll
      for (int i = 0; i < 2; i++)
        #pragma unroll
        for (int j = 0; j < 4; j++)
          acc[i][j] = __builtin_amdgcn_mfma_f32_16x16x32_bf16(af[i], bfr[j], acc[i][j], 0, 0, 0);
    }
    if (kt + 2 < nk) {
      const int nb = (cur + 2 >= 3) ? cur - 1 : cur + 2;   // (kt+2)%3
      stage((kt + 2) * 64, nb);
      asm volatile("s_waitcnt vmcnt(6)" ::: "memory");
    } else {
      asm volatile("s_waitcnt vmcnt(0)" ::: "memory");
    }
    __builtin_amdgcn_s_barrier();
    cur = (cur == 2) ? 0 : cur + 1;
  }

  const int rgn = n_blk >> 4;                 // 0=q, 1=k, 2=v
  const int h   = n_blk & 15;

  if (rgn == 2) {
    #pragma unroll
    for (int i = 0; i < 2; i++) {
      int row0 = m0 + wm + i * 16 + quad * 4;      // token of r=0
      int bidx = row0 >> 11, n0r = row0 & 2047;
      #pragma unroll
      for (int j = 0; j < 4; j++) {
        int d = j * 16 + l16;
        float bb = bv[h * 64 + d];
        __hip_bfloat162 p01 = __float22bfloat162_rn(float2{acc[i][j][0] + bb, acc[i][j][1] + bb});
        __hip_bfloat162 p23 = __float22bfloat162_rn(float2{acc[i][j][2] + bb, acc[i][j][3] + bb});
        unsigned int u01, u23;
        __builtin_memcpy(&u01, &p01, 4);
        __builtin_memcpy(&u23, &p23, 4);
        *(uint2*)(vt + (((bidx * 16 + h) * 64) + d) * 2048 + n0r) = make_uint2(u01, u23);
      }
    }
  } else {
    const float* bia = (rgn == 0) ? bq : bk;
    unsigned short* outp = (rgn == 0) ? qo : ko;
    #pragma unroll
    for (int i = 0; i < 2; i++) {
      #pragma unroll
      for (int r = 0; r < 4; r++) {
        int row = m0 + wm + i * 16 + quad * 4 + r;
        int bidx = row >> 11, n = row & 2047;
        #pragma unroll
        for (int j = 0; j < 4; j++) {
          int d = j * 16 + l16;
          int c = h * 64 + d;                      // within-region column
          int oi = ((bidx * 16 + h) * 2048 + n) * 64 + d;
          float val = acc[i][j][r] + bia[c];
          float pv  = acc[i][j ^ 2][r] + bia[c ^ 32];
          float rot = (j < 2) ? -pv : pv;          // rotate_half
          float y = val * rc[n * 64 + d] + rot * rs[n * 64 + d];
          if (rgn == 0) y *= 0.125f;               // fold D^-0.5 into q
          outp[oi] = f2bf(y);
        }
      }
    }
  }
}

// ---------------- Flash attention v7: 8-wave blocks + kv-split ---------------
__global__ __launch_bounds__(512)
void flash_attn(const unsigned short* __restrict__ q,
                const unsigned short* __restrict__ k,
                const unsigned short* __restrict__ vt,
                unsigned short* __restrict__ o0h,
                unsigned short* __restrict__ o1h,
                float* __restrict__ l0g, float* __restrict__ l1g) {
  __shared__ unsigned short sK[2][64 * 64];
  __shared__ unsigned short sVt[2][64 * 64];
  __shared__ unsigned short sPt[2][8][16 * 72];
  const int t = threadIdx.x;
  const int wave = t >> 6, lane = t & 63;
  const int quad = lane >> 4, l16 = lane & 15;
  const int id = blockIdx.x;
  const int bh = (id & 7) * 4 + ((id >> 3) & 3);  // 4 heads per XCD (L2-local)
  const int qb = (id >> 5) & 7;                   // 8 blocks of 256 q-rows
  const int kvh = id >> 8;                        // kv half
  const int base = bh * (N_ * D_);

  bf16x8 qa[2][2];
  #pragma unroll
  for (int qt = 0; qt < 2; qt++) {
    int qrow = qb * 256 + wave * 32 + qt * 16 + l16;
    #pragma unroll
    for (int kk = 0; kk < 2; kk++)
      qa[qt][kk] = *(const bf16x8*)(q + base + qrow * D_ + kk * 32 + quad * 8);
  }
  float l_i[2] = {0.f, 0.f};
  f32x4 o_acc[2][4];
  #pragma unroll
  for (int qt = 0; qt < 2; qt++)
    #pragma unroll
    for (int dt = 0; dt < 4; dt++) o_acc[qt][dt] = (f32x4){0.f, 0.f, 0.f, 0.f};

  const int sc = (((t & 7) ^ ((t >> 3) & 7)) * 8);   // T2 source chunk
  const unsigned short* gK  = k  + base + (t >> 3) * 64 + sc;
  const unsigned short* gVt = vt + bh * (64 * 2048) + (t >> 3) * 2048 + sc;

  auto stage = [&](int kt, int buf) {
    __builtin_amdgcn_global_load_lds((const unsigned int*)(gK + kt * 64 * 64),
                                     (unsigned int*)(&sK[buf][(wave * 8) * 64]), 16, 0, 0);
    __builtin_amdgcn_global_load_lds((const unsigned int*)(gVt + kt * 64),
                                     (unsigned int*)(&sVt[buf][(wave * 8) * 64]), 16, 0, 0);
  };
  const int kt0 = kvh * 16, kt1 = kt0 + 16;
  stage(kt0, 0);
  __syncthreads();

  const int so0 = ((quad ^ (l16 & 7)) * 8);          // kk=0 read slot
  const int so1 = (((4 + quad) ^ (l16 & 7)) * 8);    // kk=1 read slot

  for (int kt = kt0; kt < kt1; kt++) {
    const int cur = kt & 1;
    if (kt + 1 < kt1) stage(kt + 1, cur ^ 1);

    f32x4 s_acc[2][4];
    #pragma unroll
    for (int nt = 0; nt < 4; nt++) {
      bf16x8 kb0 = *(const bf16x8*)(&sK[cur][(nt * 16 + l16) * 64 + so0]);
      bf16x8 kb1 = *(const bf16x8*)(&sK[cur][(nt * 16 + l16) * 64 + so1]);
      #pragma unroll
      for (int qt = 0; qt < 2; qt++) {
        f32x4 a = (f32x4){0.f, 0.f, 0.f, 0.f};
        a = __builtin_amdgcn_mfma_f32_16x16x32_bf16(kb0, qa[qt][0], a, 0, 0, 0);
        a = __builtin_amdgcn_mfma_f32_16x16x32_bf16(kb1, qa[qt][1], a, 0, 0, 0);
        s_acc[qt][nt] = a;
      }
    }
    #pragma unroll
    for (int qt = 0; qt < 2; qt++) {
      float rsum = 0.f;
      #pragma unroll
      for (int nt = 0; nt < 4; nt++)
        #pragma unroll
        for (int r = 0; r < 4; r++) {
          float p = __expf(s_acc[qt][nt][r]);
          s_acc[qt][nt][r] = p;
          rsum += p;
        }
      rsum += __shfl_xor(rsum, 16);
      rsum += __shfl_xor(rsum, 32);
      l_i[qt] += rsum;
      #pragma unroll
      for (int nt = 0; nt < 4; nt++) {
        __hip_bfloat162 p01 = __float22bfloat162_rn(float2{s_acc[qt][nt][0], s_acc[qt][nt][1]});
        __hip_bfloat162 p23 = __float22bfloat162_rn(float2{s_acc[qt][nt][2], s_acc[qt][nt][3]});
        unsigned int u01, u23;
        __builtin_memcpy(&u01, &p01, 4);
        __builtin_memcpy(&u23, &p23, 4);
        *(uint2*)(&sPt[qt][wave][l16 * 72 + nt * 16 + quad * 4]) = make_uint2(u01, u23);
      }
    }
    __asm__ volatile("s_waitcnt lgkmcnt(0)" ::: "memory");
    bf16x8 pt[2][2];
    #pragma unroll
    for (int qt = 0; qt < 2; qt++) {
      pt[qt][0] = *(const bf16x8*)(&sPt[qt][wave][l16 * 72 + quad * 8]);
      pt[qt][1] = *(const bf16x8*)(&sPt[qt][wave][l16 * 72 + 32 + quad * 8]);
    }
    #pragma unroll
    for (int dt = 0; dt < 4; dt++) {
      int d0 = dt * 16 + l16;
      bf16x8 va0 = *(const bf16x8*)(&sVt[cur][d0 * 64 + so0]);
      bf16x8 va1 = *(const bf16x8*)(&sVt[cur][d0 * 64 + so1]);
      #pragma unroll
      for (int qt = 0; qt < 2; qt++) {
        o_acc[qt][dt] = __builtin_amdgcn_mfma_f32_16x16x32_bf16(va0, pt[qt][0], o_acc[qt][dt], 0, 0, 0);
        o_acc[qt][dt] = __builtin_amdgcn_mfma_f32_16x16x32_bf16(va1, pt[qt][1], o_acc[qt][dt], 0, 0, 0);
      }
    }
    __syncthreads();
  }

  unsigned short* op = kvh ? o1h : o0h;
  float* lp = kvh ? l1g : l0g;
  const int b = bh >> 4, h = bh & 15;
  #pragma unroll
  for (int qt = 0; qt < 2; qt++) {
    const int qrow = qb * 256 + wave * 32 + qt * 16 + l16;
    if (quad == 0) lp[bh * 2048 + qrow] = l_i[qt];
    const int tok = b * N_ + qrow;
    #pragma unroll
    for (int dt = 0; dt < 4; dt++) {
      __hip_bfloat162 p01 = __float22bfloat162_rn(float2{o_acc[qt][dt][0], o_acc[qt][dt][1]});
      __hip_bfloat162 p23 = __float22bfloat162_rn(float2{o_acc[qt][dt][2], o_acc[qt][dt][3]});
      unsigned int u01, u23;
      __builtin_memcpy(&u01, &p01, 4);
      __builtin_memcpy(&u23, &p23, 4);
      int col = h * 64 + dt * 16 + quad * 4;
      *(uint2*)(op + tok * C_ + col) = make_uint2(u01, u23);
    }
  }
}

// ---------------- combine the two kv halves: ao = (o0+o1)/(l0+l1) ------------
__global__ __launch_bounds__(256)
void attn_norm(const unsigned short* __restrict__ o0h,
               const unsigned short* __restrict__ o1h,
               const float* __restrict__ l0g, const float* __restrict__ l1g,
               unsigned short* __restrict__ o) {
  const int i = (blockIdx.x * 256 + threadIdx.x) * 8;
  const int row = i >> 10, c = i & 1023;
  const int h = c >> 6;
  const int b = row >> 11, n = row & 2047;
  const int li = (b * 16 + h) * 2048 + n;
  const float inv = 1.0f / (l0g[li] + l1g[li]);
  ushort4 a0 = *(const ushort4*)(o0h + i);
  ushort4 a1 = *(const ushort4*)(o0h + i + 4);
  ushort4 b0 = *(const ushort4*)(o1h + i);
  ushort4 b1 = *(const ushort4*)(o1h + i + 4);
  ushort4 r0, r1;
  r0.x = f2bf((bf2f(a0.x) + bf2f(b0.x)) * inv);
  r0.y = f2bf((bf2f(a0.y) + bf2f(b0.y)) * inv);
  r0.z = f2bf((bf2f(a0.z) + bf2f(b0.z)) * inv);
  r0.w = f2bf((bf2f(a0.w) + bf2f(b0.w)) * inv);
  r1.x = f2bf((bf2f(a1.x) + bf2f(b1.x)) * inv);
  r1.y = f2bf((bf2f(a1.y) + bf2f(b1.y)) * inv);
  r1.z = f2bf((bf2f(a1.z) + bf2f(b1.z)) * inv);
  r1.w = f2bf((bf2f(a1.w) + bf2f(b1.w)) * inv);
  *(ushort4*)(o + i) = r0;
  *(ushort4*)(o + i + 4) = r1;
}

// ---------------- launcher ---------------------------------------------------
extern "C" void kernel_launch(void* const* d_in, const int* in_sizes, int n_in,
                              void* d_out, int out_size, void* d_ws, size_t ws_size,
                              hipStream_t stream) {
  const float* x   = (const float*)d_in[0];
  const float* rc  = (const float*)d_in[1];
  const float* rs  = (const float*)d_in[2];
  const float* g1  = (const float*)d_in[3];
  const float* be1 = (const float*)d_in[4];
  const float* Wq  = (const float*)d_in[5];
  const float* bq  = (const float*)d_in[6];
  const float* Wk  = (const float*)d_in[7];
  const float* bk  = (const float*)d_in[8];
  const float* Wv  = (const float*)d_in[9];
  const float* bv  = (const float*)d_in[10];
  const float* Wo  = (const float*)d_in[11];
  const float* bo  = (const float*)d_in[12];
  const float* g2  = (const float*)d_in[13];
  const float* be2 = (const float*)d_in[14];
  const float* W1  = (const float*)d_in[15];
  const float* b1m = (const float*)d_in[16];
  const float* W2  = (const float*)d_in[17];
  const float* b2m = (const float*)d_in[18];
  float* out = (float*)d_out;

  char* ws = (char*)d_ws;
  unsigned short* wqkv = (unsigned short*)(ws + 0);           // 6 MB
  unsigned short* wo   = (unsigned short*)(ws + 6291456);     // 2 MB
  unsigned short* w1   = (unsigned short*)(ws + 8388608);     // 8 MB
  unsigned short* w2   = (unsigned short*)(ws + 16777216);    // 8 MB
  unsigned short* h1   = (unsigned short*)(ws + 25165824);    // 8 MB (ln out; attn o1 partial; ln2 out)
  unsigned short* qa   = (unsigned short*)(ws + 33554432);    // 8 MB
  unsigned short* ka   = (unsigned short*)(ws + 41943040);    // 8 MB
  unsigned short* va   = (unsigned short*)(ws + 50331648);    // 8 MB (V^T: B*H x D x N)
  unsigned short* ao   = (unsigned short*)(ws + 58720256);    // 8 MB (attn o0 partial -> normalized)
  float*          x1   = (float*)(ws + 67108864);             // 16 MB
  float*          l0   = (float*)(ws + 67108864);             // 256 KB (dead before x1 written)
  float*          l1   = l0 + 65536;                          // 256 KB
  unsigned short* u    = (unsigned short*)(ws + 33554432);    // overlays qa..ao (dead by MLP1)

  // fused weight-cvt + LN1 (one dispatch; all outputs ready before QKV)
  ln1_cvt<<<16384, 256, 0, stream>>>(
      x, g1, be1, h1,
      (const float4*)Wq, (const float4*)Wk, (const float4*)Wv, (const float4*)Wo,
      (const float4*)W1, (const float4*)W2,
      (ushort4*)wqkv, (ushort4*)(wqkv + 1048576), (ushort4*)(wqkv + 2097152),
      (ushort4*)wo, (ushort4*)w1, (ushort4*)w2);

  gemm_qkv_t4<<<1536, 256, 0, stream>>>(h1, wqkv, bq, bk, bv, rc, rs, qa, ka, va);
  flash_attn<<<512, 512, 0, stream>>>(qa, ka, va, ao, h1, l0, l1);
  attn_norm<<<2048, 256, 0, stream>>>(ao, h1, l0, l1, ao);
  gemm_bt<1, 64><<<dim3(16, 32), 256, 0, stream>>>(ao, wo, 1024, 1024, 2, bo, x, nullptr, x1);
  ln_kernel<<<4096, 256, 0, stream>>>(x1, g2, be2, h1);
  gemm_bt<2, 64><<<dim3(16, 128), 256, 0, stream>>>(h1, w1, 1024, 4096, 8, b1m, nullptr, u, nullptr);
  gemm_bt<3, 64><<<dim3(16, 32), 256, 0, stream>>>(u, w2, 4096, 1024, 2, b2m, x1, nullptr, out);
}

// Round 12
// 358.593 us; speedup vs baseline: 1.0876x; 1.0041x over previous
//
#include <hip/hip_runtime.h>
#include <hip/hip_bf16.h>

#define B_ 2
#define N_ 2048
#define C_ 1024
#define H_ 16
#define D_ 64
#define F_ 4096
#define M_ 4096  // B_*N_

typedef __attribute__((ext_vector_type(8))) short bf16x8;
typedef __attribute__((ext_vector_type(4))) float f32x4;

__device__ inline unsigned short f2bf(float f) {
  unsigned int u = __float_as_uint(f);
  u = (u + 0x7FFFu + ((u >> 16) & 1u)) >> 16;
  return (unsigned short)u;
}
__device__ inline float bf2f(unsigned short u) {
  unsigned int x = ((unsigned int)u) << 16;
  return __uint_as_float(x);
}

// ---------------- fused: all-weights fp32->bf16  +  LayerNorm1 ---------------
__global__ __launch_bounds__(256)
void ln1_cvt(const float* __restrict__ x, const float* __restrict__ g,
             const float* __restrict__ bln, unsigned short* __restrict__ out,
             const float4* __restrict__ s0, const float4* __restrict__ s1,
             const float4* __restrict__ s2, const float4* __restrict__ s3,
             const float4* __restrict__ s4, const float4* __restrict__ s5,
             ushort4* __restrict__ d0, ushort4* __restrict__ d1,
             ushort4* __restrict__ d2, ushort4* __restrict__ d3,
             ushort4* __restrict__ d4, ushort4* __restrict__ d5) {
  const int b = blockIdx.x;
  if (b < 12288) {
    const float4* s; ushort4* d; int i;
    if      (b < 1024) { s = s0; d = d0; i = b * 256 + threadIdx.x; }
    else if (b < 2048) { s = s1; d = d1; i = (b - 1024) * 256 + threadIdx.x; }
    else if (b < 3072) { s = s2; d = d2; i = (b - 2048) * 256 + threadIdx.x; }
    else if (b < 4096) { s = s3; d = d3; i = (b - 3072) * 256 + threadIdx.x; }
    else if (b < 8192) { s = s4; d = d4; i = (b - 4096) * 256 + threadIdx.x; }
    else               { s = s5; d = d5; i = (b - 8192) * 256 + threadIdx.x; }
    float4 f = s[i];
    ushort4 o;
    o.x = f2bf(f.x); o.y = f2bf(f.y); o.z = f2bf(f.z); o.w = f2bf(f.w);
    d[i] = o;
    return;
  }
  __shared__ float red[8];
  const int row = b - 12288;
  const int t = threadIdx.x;
  const float4 xv = *(const float4*)(x + row * 1024 + t * 4);
  float s  = xv.x + xv.y + xv.z + xv.w;
  float sq = xv.x * xv.x + xv.y * xv.y + xv.z * xv.z + xv.w * xv.w;
  #pragma unroll
  for (int off = 32; off >= 1; off >>= 1) {
    s  += __shfl_down(s, off);
    sq += __shfl_down(sq, off);
  }
  const int lane = t & 63, wave = t >> 6;
  if (lane == 0) { red[wave * 2] = s; red[wave * 2 + 1] = sq; }
  __syncthreads();
  float ts = red[0] + red[2] + red[4] + red[6];
  float tq = red[1] + red[3] + red[5] + red[7];
  float mean = ts * (1.0f / 1024.0f);
  float var  = tq * (1.0f / 1024.0f) - mean * mean;
  float rstd = rsqrtf(var + 1e-6f);
  float xs[4] = {xv.x, xv.y, xv.z, xv.w};
  #pragma unroll
  for (int i = 0; i < 4; i++) {
    int c = t * 4 + i;
    float y = (xs[i] - mean) * rstd * g[c] + bln[c];
    out[row * 1024 + c] = f2bf(y);
  }
}

// ---------------- LayerNorm: fp32 in -> bf16 out (ln2) ------------------------
__global__ __launch_bounds__(256)
void ln_kernel(const float* __restrict__ x, const float* __restrict__ g,
               const float* __restrict__ b, unsigned short* __restrict__ out) {
  __shared__ float red[8];
  const int row = blockIdx.x;
  const int t = threadIdx.x;
  const float4 xv = *(const float4*)(x + row * 1024 + t * 4);
  float s  = xv.x + xv.y + xv.z + xv.w;
  float sq = xv.x * xv.x + xv.y * xv.y + xv.z * xv.z + xv.w * xv.w;
  #pragma unroll
  for (int off = 32; off >= 1; off >>= 1) {
    s  += __shfl_down(s, off);
    sq += __shfl_down(sq, off);
  }
  const int lane = t & 63, wave = t >> 6;
  if (lane == 0) { red[wave * 2] = s; red[wave * 2 + 1] = sq; }
  __syncthreads();
  float ts = red[0] + red[2] + red[4] + red[6];
  float tq = red[1] + red[3] + red[5] + red[7];
  float mean = ts * (1.0f / 1024.0f);
  float var  = tq * (1.0f / 1024.0f) - mean * mean;
  float rstd = rsqrtf(var + 1e-6f);
  float xs[4] = {xv.x, xv.y, xv.z, xv.w};
  #pragma unroll
  for (int i = 0; i < 4; i++) {
    int c = t * 4 + i;
    float y = (xs[i] - mean) * rstd * g[c] + b[c];
    out[row * 1024 + c] = f2bf(y);
  }
}

// ---------------- GEMM (128x64 tile, 3-buffer counted-vmcnt, T2, m-local) ----
// MODE 1: +bias +resid -> fp32 [O-proj]  MODE 2: +bias GELU -> bf16 [MLP1]
// MODE 3: +bias +resid -> fp32 [MLP2 -> d_out]
// Round-9/11 verified T4 loop (late stage issue). THIS ROUND: isolated T5
// probe — s_setprio(1) around the MFMA cluster only (2 blocks/CU, waves of
// the two blocks are independent -> scheduler has something to arbitrate;
// matches m191's win regime, not m190's lockstep null).
template<int MODE, int BN>
__global__ __launch_bounds__(256)
void gemm_bt(const unsigned short* __restrict__ A,
             const unsigned short* __restrict__ Bw,
             int K, int Nout, int npc,
             const float* __restrict__ bias,
             const float* __restrict__ resid,
             unsigned short* __restrict__ out_bf,
             float* __restrict__ out_f32) {
  constexpr int NJ = BN / 32;
  static_assert(BN == 64, "vmcnt literal assumes 6 loads per stage");
  __shared__ unsigned short sA[3][128 * 64];
  __shared__ unsigned short sB[3][BN * 64];
  const int t = threadIdx.x;
  const int wave = t >> 6, lane = t & 63;
  const int quad = lane >> 4, l16 = lane & 15;
  const int wm = (wave & 1) * 64, wn = (wave >> 1) * (BN / 2);
  const int id = blockIdx.y * gridDim.x + blockIdx.x;
  const int xcd = id & 7, r_ = id >> 3;
  const int m_blk = xcd * 4 + (r_ & 3);
  const int n_blk = r_ >> 2;
  const int m0 = m_blk * 128, n0 = n_blk * BN;

  f32x4 acc[4][NJ];
  #pragma unroll
  for (int i = 0; i < 4; i++)
    #pragma unroll
    for (int j = 0; j < NJ; j++) acc[i][j] = (f32x4){0.f, 0.f, 0.f, 0.f};

  const int sc = (((t & 7) ^ ((t >> 3) & 7)) * 8);   // swizzled source chunk
  const unsigned short* gA = A  + (m0 + (t >> 3)) * K + sc;
  const unsigned short* gB = Bw + (n0 + (t >> 3)) * K + sc;

  auto stage = [&](int k0, int buf) {
    unsigned short* lA = &sA[buf][(wave * 8) * 64];
    unsigned short* lB = &sB[buf][(wave * 8) * 64];
    #pragma unroll
    for (int i = 0; i < 4; i++)
      __builtin_amdgcn_global_load_lds((const unsigned int*)(gA + (32 * i) * K + k0),
                                       (unsigned int*)(lA + 32 * i * 64), 16, 0, 0);
    #pragma unroll
    for (int i = 0; i < BN / 32; i++)
      __builtin_amdgcn_global_load_lds((const unsigned int*)(gB + (32 * i) * K + k0),
                                       (unsigned int*)(lB + 32 * i * 64), 16, 0, 0);
  };

  // prologue: tiles 0,1 -> bufs 0,1 (12 loads); retire tile 0 only.
  stage(0, 0);
  stage(64, 1);
  asm volatile("s_waitcnt vmcnt(6)" ::: "memory");
  __builtin_amdgcn_s_barrier();

  const int so0 = ((quad ^ (l16 & 7)) * 8);          // kk=0 read slot
  const int so1 = (((4 + quad) ^ (l16 & 7)) * 8);    // kk=1 read slot

  const int nk = K >> 6;
  int cur = 0;
  for (int kt = 0; kt < nk; kt++) {
    const unsigned short* rA = &sA[cur][0];
    const unsigned short* rB = &sB[cur][0];
    #pragma unroll
    for (int kk = 0; kk < 2; kk++) {
      const int so = kk ? so1 : so0;
      bf16x8 af[4], bfr[NJ];
      #pragma unroll
      for (int i = 0; i < 4; i++)
        af[i] = *(const bf16x8*)(&rA[(wm + i * 16 + l16) * 64 + so]);
      #pragma unroll
      for (int j = 0; j < NJ; j++)
        bfr[j] = *(const bf16x8*)(&rB[(wn + j * 16 + l16) * 64 + so]);
      __builtin_amdgcn_s_setprio(1);
      #pragma unroll
      for (int i = 0; i < 4; i++)
        #pragma unroll
        for (int j = 0; j < NJ; j++)
          acc[i][j] = __builtin_amdgcn_mfma_f32_16x16x32_bf16(af[i], bfr[j], acc[i][j], 0, 0, 0);
      __builtin_amdgcn_s_setprio(0);
    }
    if (kt + 2 < nk) {
      const int nb = (cur + 2 >= 3) ? cur - 1 : cur + 2;   // (kt+2)%3
      stage((kt + 2) * 64, nb);
      asm volatile("s_waitcnt vmcnt(6)" ::: "memory");
    } else {
      asm volatile("s_waitcnt vmcnt(0)" ::: "memory");
    }
    __builtin_amdgcn_s_barrier();
    cur = (cur == 2) ? 0 : cur + 1;
  }

  #pragma unroll
  for (int i = 0; i < 4; i++) {
    #pragma unroll
    for (int j = 0; j < NJ; j++) {
      int col = n0 + wn + j * 16 + l16;
      #pragma unroll
      for (int r = 0; r < 4; r++) {
        int row = m0 + wm + i * 16 + quad * 4 + r;
        float v = acc[i][j][r];
        if (MODE == 1 || MODE == 3) {
          out_f32[row * Nout + col] = v + bias[col] + resid[row * Nout + col];
        } else {
          v += bias[col];
          float w = v * (1.0f + 0.044715f * v * v);
          float gl = v / (1.0f + __expf(-1.5957691216f * w));
          out_bf[row * Nout + col] = f2bf(gl);
        }
      }
    }
  }
}

// ---------------- QKV GEMM on the T4 skeleton, RoPE epilogue -----------------
// (round-9/11 verified; + T5 setprio around MFMA cluster)
__global__ __launch_bounds__(256)
void gemm_qkv_t4(const unsigned short* __restrict__ A,
                 const unsigned short* __restrict__ Bw,
                 const float* __restrict__ bq, const float* __restrict__ bk,
                 const float* __restrict__ bv,
                 const float* __restrict__ rc, const float* __restrict__ rs,
                 unsigned short* __restrict__ qo, unsigned short* __restrict__ ko,
                 unsigned short* __restrict__ vt) {
  const int K = C_;
  __shared__ unsigned short sA[3][128 * 64];
  __shared__ unsigned short sB[3][64 * 64];
  const int t = threadIdx.x;
  const int wave = t >> 6, lane = t & 63;
  const int quad = lane >> 4, l16 = lane & 15;
  const int wm = wave * 32;                        // 4m x 1n wave grid
  const int id = blockIdx.x;                       // [0,1536)
  const int xcd = id & 7, r_ = id >> 3;            // r_ in [0,192)
  const int m_blk = xcd * 4 + (r_ & 3);            // [0,32)  A-local
  const int n_blk = r_ >> 2;                       // [0,48)
  const int m0 = m_blk * 128, n0 = n_blk * 64;

  f32x4 acc[2][4];
  #pragma unroll
  for (int i = 0; i < 2; i++)
    #pragma unroll
    for (int j = 0; j < 4; j++) acc[i][j] = (f32x4){0.f, 0.f, 0.f, 0.f};

  const int sc = (((t & 7) ^ ((t >> 3) & 7)) * 8);
  const unsigned short* gA = A  + (m0 + (t >> 3)) * K + sc;
  const unsigned short* gB = Bw + (n0 + (t >> 3)) * K + sc;

  auto stage = [&](int k0, int buf) {
    unsigned short* lA = &sA[buf][(wave * 8) * 64];
    unsigned short* lB = &sB[buf][(wave * 8) * 64];
    #pragma unroll
    for (int i = 0; i < 4; i++)
      __builtin_amdgcn_global_load_lds((const unsigned int*)(gA + (32 * i) * K + k0),
                                       (unsigned int*)(lA + 32 * i * 64), 16, 0, 0);
    #pragma unroll
    for (int i = 0; i < 2; i++)
      __builtin_amdgcn_global_load_lds((const unsigned int*)(gB + (32 * i) * K + k0),
                                       (unsigned int*)(lB + 32 * i * 64), 16, 0, 0);
  };

  stage(0, 0);
  stage(64, 1);
  asm volatile("s_waitcnt vmcnt(6)" ::: "memory");
  __builtin_amdgcn_s_barrier();

  const int so0 = ((quad ^ (l16 & 7)) * 8);
  const int so1 = (((4 + quad) ^ (l16 & 7)) * 8);

  const int nk = K >> 6;   // 16
  int cur = 0;
  for (int kt = 0; kt < nk; kt++) {
    const unsigned short* rA = &sA[cur][0];
    const unsigned short* rB = &sB[cur][0];
    #pragma unroll
    for (int kk = 0; kk < 2; kk++) {
      const int so = kk ? so1 : so0;
      bf16x8 af[2], bfr[4];
      #pragma unroll
      for (int i = 0; i < 2; i++)
        af[i] = *(const bf16x8*)(&rA[(wm + i * 16 + l16) * 64 + so]);
      #pragma unroll
      for (int j = 0; j < 4; j++)
        bfr[j] = *(const bf16x8*)(&rB[(j * 16 + l16) * 64 + so]);
      __builtin_amdgcn_s_setprio(1);
      #pragma unroll
      for (int i = 0; i < 2; i++)
        #pragma unroll
        for (int j = 0; j < 4; j++)
          acc[i][j] = __builtin_amdgcn_mfma_f32_16x16x32_bf16(af[i], bfr[j], acc[i][j], 0, 0, 0);
      __builtin_amdgcn_s_setprio(0);
    }
    if (kt + 2 < nk) {
      const int nb = (cur + 2 >= 3) ? cur - 1 : cur + 2;   // (kt+2)%3
      stage((kt + 2) * 64, nb);
      asm volatile("s_waitcnt vmcnt(6)" ::: "memory");
    } else {
      asm volatile("s_waitcnt vmcnt(0)" ::: "memory");
    }
    __builtin_amdgcn_s_barrier();
    cur = (cur == 2) ? 0 : cur + 1;
  }

  const int rgn = n_blk >> 4;                 // 0=q, 1=k, 2=v
  const int h   = n_blk & 15;

  if (rgn == 2) {
    #pragma unroll
    for (int i = 0; i < 2; i++) {
      int row0 = m0 + wm + i * 16 + quad * 4;      // token of r=0
      int bidx = row0 >> 11, n0r = row0 & 2047;
      #pragma unroll
      for (int j = 0; j < 4; j++) {
        int d = j * 16 + l16;
        float bb = bv[h * 64 + d];
        __hip_bfloat162 p01 = __float22bfloat162_rn(float2{acc[i][j][0] + bb, acc[i][j][1] + bb});
        __hip_bfloat162 p23 = __float22bfloat162_rn(float2{acc[i][j][2] + bb, acc[i][j][3] + bb});
        unsigned int u01, u23;
        __builtin_memcpy(&u01, &p01, 4);
        __builtin_memcpy(&u23, &p23, 4);
        *(uint2*)(vt + (((bidx * 16 + h) * 64) + d) * 2048 + n0r) = make_uint2(u01, u23);
      }
    }
  } else {
    const float* bia = (rgn == 0) ? bq : bk;
    unsigned short* outp = (rgn == 0) ? qo : ko;
    #pragma unroll
    for (int i = 0; i < 2; i++) {
      #pragma unroll
      for (int r = 0; r < 4; r++) {
        int row = m0 + wm + i * 16 + quad * 4 + r;
        int bidx = row >> 11, n = row & 2047;
        #pragma unroll
        for (int j = 0; j < 4; j++) {
          int d = j * 16 + l16;
          int c = h * 64 + d;                      // within-region column
          int oi = ((bidx * 16 + h) * 2048 + n) * 64 + d;
          float val = acc[i][j][r] + bia[c];
          float pv  = acc[i][j ^ 2][r] + bia[c ^ 32];
          float rot = (j < 2) ? -pv : pv;          // rotate_half
          float y = val * rc[n * 64 + d] + rot * rs[n * 64 + d];
          if (rgn == 0) y *= 0.125f;               // fold D^-0.5 into q
          outp[oi] = f2bf(y);
        }
      }
    }
  }
}

// ---------------- Flash attention v7: 8-wave blocks + kv-split + T5 ----------
__global__ __launch_bounds__(512)
void flash_attn(const unsigned short* __restrict__ q,
                const unsigned short* __restrict__ k,
                const unsigned short* __restrict__ vt,
                unsigned short* __restrict__ o0h,
                unsigned short* __restrict__ o1h,
                float* __restrict__ l0g, float* __restrict__ l1g) {
  __shared__ unsigned short sK[2][64 * 64];
  __shared__ unsigned short sVt[2][64 * 64];
  __shared__ unsigned short sPt[2][8][16 * 72];
  const int t = threadIdx.x;
  const int wave = t >> 6, lane = t & 63;
  const int quad = lane >> 4, l16 = lane & 15;
  const int id = blockIdx.x;
  const int bh = (id & 7) * 4 + ((id >> 3) & 3);  // 4 heads per XCD (L2-local)
  const int qb = (id >> 5) & 7;                   // 8 blocks of 256 q-rows
  const int kvh = id >> 8;                        // kv half
  const int base = bh * (N_ * D_);

  bf16x8 qa[2][2];
  #pragma unroll
  for (int qt = 0; qt < 2; qt++) {
    int qrow = qb * 256 + wave * 32 + qt * 16 + l16;
    #pragma unroll
    for (int kk = 0; kk < 2; kk++)
      qa[qt][kk] = *(const bf16x8*)(q + base + qrow * D_ + kk * 32 + quad * 8);
  }
  float l_i[2] = {0.f, 0.f};
  f32x4 o_acc[2][4];
  #pragma unroll
  for (int qt = 0; qt < 2; qt++)
    #pragma unroll
    for (int dt = 0; dt < 4; dt++) o_acc[qt][dt] = (f32x4){0.f, 0.f, 0.f, 0.f};

  const int sc = (((t & 7) ^ ((t >> 3) & 7)) * 8);   // T2 source chunk
  const unsigned short* gK  = k  + base + (t >> 3) * 64 + sc;
  const unsigned short* gVt = vt + bh * (64 * 2048) + (t >> 3) * 2048 + sc;

  auto stage = [&](int kt, int buf) {
    __builtin_amdgcn_global_load_lds((const unsigned int*)(gK + kt * 64 * 64),
                                     (unsigned int*)(&sK[buf][(wave * 8) * 64]), 16, 0, 0);
    __builtin_amdgcn_global_load_lds((const unsigned int*)(gVt + kt * 64),
                                     (unsigned int*)(&sVt[buf][(wave * 8) * 64]), 16, 0, 0);
  };
  const int kt0 = kvh * 16, kt1 = kt0 + 16;
  stage(kt0, 0);
  __syncthreads();

  const int so0 = ((quad ^ (l16 & 7)) * 8);          // kk=0 read slot
  const int so1 = (((4 + quad) ^ (l16 & 7)) * 8);    // kk=1 read slot

  for (int kt = kt0; kt < kt1; kt++) {
    const int cur = kt & 1;
    if (kt + 1 < kt1) stage(kt + 1, cur ^ 1);

    f32x4 s_acc[2][4];
    __builtin_amdgcn_s_setprio(1);
    #pragma unroll
    for (int nt = 0; nt < 4; nt++) {
      bf16x8 kb0 = *(const bf16x8*)(&sK[cur][(nt * 16 + l16) * 64 + so0]);
      bf16x8 kb1 = *(const bf16x8*)(&sK[cur][(nt * 16 + l16) * 64 + so1]);
      #pragma unroll
      for (int qt = 0; qt < 2; qt++) {
        f32x4 a = (f32x4){0.f, 0.f, 0.f, 0.f};
        a = __builtin_amdgcn_mfma_f32_16x16x32_bf16(kb0, qa[qt][0], a, 0, 0, 0);
        a = __builtin_amdgcn_mfma_f32_16x16x32_bf16(kb1, qa[qt][1], a, 0, 0, 0);
        s_acc[qt][nt] = a;
      }
    }
    __builtin_amdgcn_s_setprio(0);
    #pragma unroll
    for (int qt = 0; qt < 2; qt++) {
      float rsum = 0.f;
      #pragma unroll
      for (int nt = 0; nt < 4; nt++)
        #pragma unroll
        for (int r = 0; r < 4; r++) {
          float p = __expf(s_acc[qt][nt][r]);
          s_acc[qt][nt][r] = p;
          rsum += p;
        }
      rsum += __shfl_xor(rsum, 16);
      rsum += __shfl_xor(rsum, 32);
      l_i[qt] += rsum;
      #pragma unroll
      for (int nt = 0; nt < 4; nt++) {
        __hip_bfloat162 p01 = __float22bfloat162_rn(float2{s_acc[qt][nt][0], s_acc[qt][nt][1]});
        __hip_bfloat162 p23 = __float22bfloat162_rn(float2{s_acc[qt][nt][2], s_acc[qt][nt][3]});
        unsigned int u01, u23;
        __builtin_memcpy(&u01, &p01, 4);
        __builtin_memcpy(&u23, &p23, 4);
        *(uint2*)(&sPt[qt][wave][l16 * 72 + nt * 16 + quad * 4]) = make_uint2(u01, u23);
      }
    }
    __asm__ volatile("s_waitcnt lgkmcnt(0)" ::: "memory");
    bf16x8 pt[2][2];
    #pragma unroll
    for (int qt = 0; qt < 2; qt++) {
      pt[qt][0] = *(const bf16x8*)(&sPt[qt][wave][l16 * 72 + quad * 8]);
      pt[qt][1] = *(const bf16x8*)(&sPt[qt][wave][l16 * 72 + 32 + quad * 8]);
    }
    __builtin_amdgcn_s_setprio(1);
    #pragma unroll
    for (int dt = 0; dt < 4; dt++) {
      int d0 = dt * 16 + l16;
      bf16x8 va0 = *(const bf16x8*)(&sVt[cur][d0 * 64 + so0]);
      bf16x8 va1 = *(const bf16x8*)(&sVt[cur][d0 * 64 + so1]);
      #pragma unroll
      for (int qt = 0; qt < 2; qt++) {
        o_acc[qt][dt] = __builtin_amdgcn_mfma_f32_16x16x32_bf16(va0, pt[qt][0], o_acc[qt][dt], 0, 0, 0);
        o_acc[qt][dt] = __builtin_amdgcn_mfma_f32_16x16x32_bf16(va1, pt[qt][1], o_acc[qt][dt], 0, 0, 0);
      }
    }
    __builtin_amdgcn_s_setprio(0);
    __syncthreads();
  }

  unsigned short* op = kvh ? o1h : o0h;
  float* lp = kvh ? l1g : l0g;
  const int b = bh >> 4, h = bh & 15;
  #pragma unroll
  for (int qt = 0; qt < 2; qt++) {
    const int qrow = qb * 256 + wave * 32 + qt * 16 + l16;
    if (quad == 0) lp[bh * 2048 + qrow] = l_i[qt];
    const int tok = b * N_ + qrow;
    #pragma unroll
    for (int dt = 0; dt < 4; dt++) {
      __hip_bfloat162 p01 = __float22bfloat162_rn(float2{o_acc[qt][dt][0], o_acc[qt][dt][1]});
      __hip_bfloat162 p23 = __float22bfloat162_rn(float2{o_acc[qt][dt][2], o_acc[qt][dt][3]});
      unsigned int u01, u23;
      __builtin_memcpy(&u01, &p01, 4);
      __builtin_memcpy(&u23, &p23, 4);
      int col = h * 64 + dt * 16 + quad * 4;
      *(uint2*)(op + tok * C_ + col) = make_uint2(u01, u23);
    }
  }
}

// ---------------- combine the two kv halves: ao = (o0+o1)/(l0+l1) ------------
__global__ __launch_bounds__(256)
void attn_norm(const unsigned short* __restrict__ o0h,
               const unsigned short* __restrict__ o1h,
               const float* __restrict__ l0g, const float* __restrict__ l1g,
               unsigned short* __restrict__ o) {
  const int i = (blockIdx.x * 256 + threadIdx.x) * 8;
  const int row = i >> 10, c = i & 1023;
  const int h = c >> 6;
  const int b = row >> 11, n = row & 2047;
  const int li = (b * 16 + h) * 2048 + n;
  const float inv = 1.0f / (l0g[li] + l1g[li]);
  ushort4 a0 = *(const ushort4*)(o0h + i);
  ushort4 a1 = *(const ushort4*)(o0h + i + 4);
  ushort4 b0 = *(const ushort4*)(o1h + i);
  ushort4 b1 = *(const ushort4*)(o1h + i + 4);
  ushort4 r0, r1;
  r0.x = f2bf((bf2f(a0.x) + bf2f(b0.x)) * inv);
  r0.y = f2bf((bf2f(a0.y) + bf2f(b0.y)) * inv);
  r0.z = f2bf((bf2f(a0.z) + bf2f(b0.z)) * inv);
  r0.w = f2bf((bf2f(a0.w) + bf2f(b0.w)) * inv);
  r1.x = f2bf((bf2f(a1.x) + bf2f(b1.x)) * inv);
  r1.y = f2bf((bf2f(a1.y) + bf2f(b1.y)) * inv);
  r1.z = f2bf((bf2f(a1.z) + bf2f(b1.z)) * inv);
  r1.w = f2bf((bf2f(a1.w) + bf2f(b1.w)) * inv);
  *(ushort4*)(o + i) = r0;
  *(ushort4*)(o + i + 4) = r1;
}

// ---------------- launcher ---------------------------------------------------
extern "C" void kernel_launch(void* const* d_in, const int* in_sizes, int n_in,
                              void* d_out, int out_size, void* d_ws, size_t ws_size,
                              hipStream_t stream) {
  const float* x   = (const float*)d_in[0];
  const float* rc  = (const float*)d_in[1];
  const float* rs  = (const float*)d_in[2];
  const float* g1  = (const float*)d_in[3];
  const float* be1 = (const float*)d_in[4];
  const float* Wq  = (const float*)d_in[5];
  const float* bq  = (const float*)d_in[6];
  const float* Wk  = (const float*)d_in[7];
  const float* bk  = (const float*)d_in[8];
  const float* Wv  = (const float*)d_in[9];
  const float* bv  = (const float*)d_in[10];
  const float* Wo  = (const float*)d_in[11];
  const float* bo  = (const float*)d_in[12];
  const float* g2  = (const float*)d_in[13];
  const float* be2 = (const float*)d_in[14];
  const float* W1  = (const float*)d_in[15];
  const float* b1m = (const float*)d_in[16];
  const float* W2  = (const float*)d_in[17];
  const float* b2m = (const float*)d_in[18];
  float* out = (float*)d_out;

  char* ws = (char*)d_ws;
  unsigned short* wqkv = (unsigned short*)(ws + 0);           // 6 MB
  unsigned short* wo   = (unsigned short*)(ws + 6291456);     // 2 MB
  unsigned short* w1   = (unsigned short*)(ws + 8388608);     // 8 MB
  unsigned short* w2   = (unsigned short*)(ws + 16777216);    // 8 MB
  unsigned short* h1   = (unsigned short*)(ws + 25165824);    // 8 MB (ln out; attn o1 partial; ln2 out)
  unsigned short* qa   = (unsigned short*)(ws + 33554432);    // 8 MB
  unsigned short* ka   = (unsigned short*)(ws + 41943040);    // 8 MB
  unsigned short* va   = (unsigned short*)(ws + 50331648);    // 8 MB (V^T: B*H x D x N)
  unsigned short* ao   = (unsigned short*)(ws + 58720256);    // 8 MB (attn o0 partial -> normalized)
  float*          x1   = (float*)(ws + 67108864);             // 16 MB
  float*          l0   = (float*)(ws + 67108864);             // 256 KB (dead before x1 written)
  float*          l1   = l0 + 65536;                          // 256 KB
  unsigned short* u    = (unsigned short*)(ws + 33554432);    // overlays qa..ao (dead by MLP1)

  // fused weight-cvt + LN1 (one dispatch; all outputs ready before QKV)
  ln1_cvt<<<16384, 256, 0, stream>>>(
      x, g1, be1, h1,
      (const float4*)Wq, (const float4*)Wk, (const float4*)Wv, (const float4*)Wo,
      (const float4*)W1, (const float4*)W2,
      (ushort4*)wqkv, (ushort4*)(wqkv + 1048576), (ushort4*)(wqkv + 2097152),
      (ushort4*)wo, (ushort4*)w1, (ushort4*)w2);

  gemm_qkv_t4<<<1536, 256, 0, stream>>>(h1, wqkv, bq, bk, bv, rc, rs, qa, ka, va);
  flash_attn<<<512, 512, 0, stream>>>(qa, ka, va, ao, h1, l0, l1);
  attn_norm<<<2048, 256, 0, stream>>>(ao, h1, l0, l1, ao);
  gemm_bt<1, 64><<<dim3(16, 32), 256, 0, stream>>>(ao, wo, 1024, 1024, 2, bo, x, nullptr, x1);
  ln_kernel<<<4096, 256, 0, stream>>>(x1, g2, be2, h1);
  gemm_bt<2, 64><<<dim3(16, 128), 256, 0, stream>>>(h1, w1, 1024, 4096, 8, b1m, nullptr, u, nullptr);
  gemm_bt<3, 64><<<dim3(16, 32), 256, 0, stream>>>(u, w2, 4096, 1024, 2, b2m, x1, nullptr, out);
}

// Round 13
// 355.194 us; speedup vs baseline: 1.0980x; 1.0096x over previous
//
#include <hip/hip_runtime.h>
#include <hip/hip_bf16.h>

#define B_ 2
#define N_ 2048
#define C_ 1024
#define H_ 16
#define D_ 64
#define F_ 4096
#define M_ 4096  // B_*N_

typedef __attribute__((ext_vector_type(8))) short bf16x8;
typedef __attribute__((ext_vector_type(4))) float f32x4;

__device__ inline unsigned short f2bf(float f) {
  unsigned int u = __float_as_uint(f);
  u = (u + 0x7FFFu + ((u >> 16) & 1u)) >> 16;
  return (unsigned short)u;
}
__device__ inline float bf2f(unsigned short u) {
  unsigned int x = ((unsigned int)u) << 16;
  return __uint_as_float(x);
}

// ---------------- fused: all-weights fp32->bf16  +  LayerNorm1 ---------------
__global__ __launch_bounds__(256)
void ln1_cvt(const float* __restrict__ x, const float* __restrict__ g,
             const float* __restrict__ bln, unsigned short* __restrict__ out,
             const float4* __restrict__ s0, const float4* __restrict__ s1,
             const float4* __restrict__ s2, const float4* __restrict__ s3,
             const float4* __restrict__ s4, const float4* __restrict__ s5,
             ushort4* __restrict__ d0, ushort4* __restrict__ d1,
             ushort4* __restrict__ d2, ushort4* __restrict__ d3,
             ushort4* __restrict__ d4, ushort4* __restrict__ d5) {
  const int b = blockIdx.x;
  if (b < 12288) {
    const float4* s; ushort4* d; int i;
    if      (b < 1024) { s = s0; d = d0; i = b * 256 + threadIdx.x; }
    else if (b < 2048) { s = s1; d = d1; i = (b - 1024) * 256 + threadIdx.x; }
    else if (b < 3072) { s = s2; d = d2; i = (b - 2048) * 256 + threadIdx.x; }
    else if (b < 4096) { s = s3; d = d3; i = (b - 3072) * 256 + threadIdx.x; }
    else if (b < 8192) { s = s4; d = d4; i = (b - 4096) * 256 + threadIdx.x; }
    else               { s = s5; d = d5; i = (b - 8192) * 256 + threadIdx.x; }
    float4 f = s[i];
    ushort4 o;
    o.x = f2bf(f.x); o.y = f2bf(f.y); o.z = f2bf(f.z); o.w = f2bf(f.w);
    d[i] = o;
    return;
  }
  __shared__ float red[8];
  const int row = b - 12288;
  const int t = threadIdx.x;
  const float4 xv = *(const float4*)(x + row * 1024 + t * 4);
  float s  = xv.x + xv.y + xv.z + xv.w;
  float sq = xv.x * xv.x + xv.y * xv.y + xv.z * xv.z + xv.w * xv.w;
  #pragma unroll
  for (int off = 32; off >= 1; off >>= 1) {
    s  += __shfl_down(s, off);
    sq += __shfl_down(sq, off);
  }
  const int lane = t & 63, wave = t >> 6;
  if (lane == 0) { red[wave * 2] = s; red[wave * 2 + 1] = sq; }
  __syncthreads();
  float ts = red[0] + red[2] + red[4] + red[6];
  float tq = red[1] + red[3] + red[5] + red[7];
  float mean = ts * (1.0f / 1024.0f);
  float var  = tq * (1.0f / 1024.0f) - mean * mean;
  float rstd = rsqrtf(var + 1e-6f);
  float xs[4] = {xv.x, xv.y, xv.z, xv.w};
  #pragma unroll
  for (int i = 0; i < 4; i++) {
    int c = t * 4 + i;
    float y = (xs[i] - mean) * rstd * g[c] + bln[c];
    out[row * 1024 + c] = f2bf(y);
  }
}

// ---------------- LayerNorm: fp32 in -> bf16 out (ln2) ------------------------
__global__ __launch_bounds__(256)
void ln_kernel(const float* __restrict__ x, const float* __restrict__ g,
               const float* __restrict__ b, unsigned short* __restrict__ out) {
  __shared__ float red[8];
  const int row = blockIdx.x;
  const int t = threadIdx.x;
  const float4 xv = *(const float4*)(x + row * 1024 + t * 4);
  float s  = xv.x + xv.y + xv.z + xv.w;
  float sq = xv.x * xv.x + xv.y * xv.y + xv.z * xv.z + xv.w * xv.w;
  #pragma unroll
  for (int off = 32; off >= 1; off >>= 1) {
    s  += __shfl_down(s, off);
    sq += __shfl_down(sq, off);
  }
  const int lane = t & 63, wave = t >> 6;
  if (lane == 0) { red[wave * 2] = s; red[wave * 2 + 1] = sq; }
  __syncthreads();
  float ts = red[0] + red[2] + red[4] + red[6];
  float tq = red[1] + red[3] + red[5] + red[7];
  float mean = ts * (1.0f / 1024.0f);
  float var  = tq * (1.0f / 1024.0f) - mean * mean;
  float rstd = rsqrtf(var + 1e-6f);
  float xs[4] = {xv.x, xv.y, xv.z, xv.w};
  #pragma unroll
  for (int i = 0; i < 4; i++) {
    int c = t * 4 + i;
    float y = (xs[i] - mean) * rstd * g[c] + b[c];
    out[row * 1024 + c] = f2bf(y);
  }
}

// ---------------- GEMM (128x64 tile, 3-buffer counted-vmcnt, T2, m-local) ----
// MODE 1: +bias +resid -> fp32 [O-proj]   MODE 3: same [MLP2 -> d_out]
// Round-12 verified (T4 late-issue + T5 setprio).
template<int MODE, int BN>
__global__ __launch_bounds__(256)
void gemm_bt(const unsigned short* __restrict__ A,
             const unsigned short* __restrict__ Bw,
             int K, int Nout, int npc,
             const float* __restrict__ bias,
             const float* __restrict__ resid,
             unsigned short* __restrict__ out_bf,
             float* __restrict__ out_f32) {
  constexpr int NJ = BN / 32;
  static_assert(BN == 64, "vmcnt literal assumes 6 loads per stage");
  __shared__ unsigned short sA[3][128 * 64];
  __shared__ unsigned short sB[3][BN * 64];
  const int t = threadIdx.x;
  const int wave = t >> 6, lane = t & 63;
  const int quad = lane >> 4, l16 = lane & 15;
  const int wm = (wave & 1) * 64, wn = (wave >> 1) * (BN / 2);
  const int id = blockIdx.y * gridDim.x + blockIdx.x;
  const int xcd = id & 7, r_ = id >> 3;
  const int m_blk = xcd * 4 + (r_ & 3);
  const int n_blk = r_ >> 2;
  const int m0 = m_blk * 128, n0 = n_blk * BN;

  f32x4 acc[4][NJ];
  #pragma unroll
  for (int i = 0; i < 4; i++)
    #pragma unroll
    for (int j = 0; j < NJ; j++) acc[i][j] = (f32x4){0.f, 0.f, 0.f, 0.f};

  const int sc = (((t & 7) ^ ((t >> 3) & 7)) * 8);   // swizzled source chunk
  const unsigned short* gA = A  + (m0 + (t >> 3)) * K + sc;
  const unsigned short* gB = Bw + (n0 + (t >> 3)) * K + sc;

  auto stage = [&](int k0, int buf) {
    unsigned short* lA = &sA[buf][(wave * 8) * 64];
    unsigned short* lB = &sB[buf][(wave * 8) * 64];
    #pragma unroll
    for (int i = 0; i < 4; i++)
      __builtin_amdgcn_global_load_lds((const unsigned int*)(gA + (32 * i) * K + k0),
                                       (unsigned int*)(lA + 32 * i * 64), 16, 0, 0);
    #pragma unroll
    for (int i = 0; i < BN / 32; i++)
      __builtin_amdgcn_global_load_lds((const unsigned int*)(gB + (32 * i) * K + k0),
                                       (unsigned int*)(lB + 32 * i * 64), 16, 0, 0);
  };

  // prologue: tiles 0,1 -> bufs 0,1 (12 loads); retire tile 0 only.
  stage(0, 0);
  stage(64, 1);
  asm volatile("s_waitcnt vmcnt(6)" ::: "memory");
  __builtin_amdgcn_s_barrier();

  const int so0 = ((quad ^ (l16 & 7)) * 8);          // kk=0 read slot
  const int so1 = (((4 + quad) ^ (l16 & 7)) * 8);    // kk=1 read slot

  const int nk = K >> 6;
  int cur = 0;
  for (int kt = 0; kt < nk; kt++) {
    const unsigned short* rA = &sA[cur][0];
    const unsigned short* rB = &sB[cur][0];
    #pragma unroll
    for (int kk = 0; kk < 2; kk++) {
      const int so = kk ? so1 : so0;
      bf16x8 af[4], bfr[NJ];
      #pragma unroll
      for (int i = 0; i < 4; i++)
        af[i] = *(const bf16x8*)(&rA[(wm + i * 16 + l16) * 64 + so]);
      #pragma unroll
      for (int j = 0; j < NJ; j++)
        bfr[j] = *(const bf16x8*)(&rB[(wn + j * 16 + l16) * 64 + so]);
      __builtin_amdgcn_s_setprio(1);
      #pragma unroll
      for (int i = 0; i < 4; i++)
        #pragma unroll
        for (int j = 0; j < NJ; j++)
          acc[i][j] = __builtin_amdgcn_mfma_f32_16x16x32_bf16(af[i], bfr[j], acc[i][j], 0, 0, 0);
      __builtin_amdgcn_s_setprio(0);
    }
    if (kt + 2 < nk) {
      const int nb = (cur + 2 >= 3) ? cur - 1 : cur + 2;   // (kt+2)%3
      stage((kt + 2) * 64, nb);
      asm volatile("s_waitcnt vmcnt(6)" ::: "memory");
    } else {
      asm volatile("s_waitcnt vmcnt(0)" ::: "memory");
    }
    __builtin_amdgcn_s_barrier();
    cur = (cur == 2) ? 0 : cur + 1;
  }

  #pragma unroll
  for (int i = 0; i < 4; i++) {
    #pragma unroll
    for (int j = 0; j < NJ; j++) {
      int col = n0 + wn + j * 16 + l16;
      #pragma unroll
      for (int r = 0; r < 4; r++) {
        int row = m0 + wm + i * 16 + quad * 4 + r;
        float v = acc[i][j][r];
        if (MODE == 1 || MODE == 3) {
          out_f32[row * Nout + col] = v + bias[col] + resid[row * Nout + col];
        } else {
          v += bias[col];
          float w = v * (1.0f + 0.044715f * v * v);
          float gl = v / (1.0f + __expf(-1.5957691216f * w));
          out_bf[row * Nout + col] = f2bf(gl);
        }
      }
    }
  }
}

// ---------------- MLP1: 256x128 tile, 512 thr, 2-buf (L2-traffic fix) --------
// MLP1 was L2-staging-BW bound: (128+64) tile staged 786 MB total = ~80% of
// the per-CU L2 share. Staged-bytes/output ~ 1/BM + 1/BN: (256,128) halves it
// (786 -> ~393 MB) and doubles per-wave MFMA amortization (32/K-tile).
// 8 waves (4m x 2n, wave owns 64x64, acc[4][4]), 96KB LDS (1 block/CU,
// 8 waves = same 2 waves/SIMD as before), grid 512 = 2 rounds.
// 2-buffer: stage(t+1) issued before compute; vmcnt(0) drain after compute
// (exposure = DMA - compute, small; volume is the dominant term here).
// T2 swizzle + A-local XCD map as verified elsewhere.
__global__ __launch_bounds__(512, 1)
void gemm_mlp1(const unsigned short* __restrict__ A,
               const unsigned short* __restrict__ Bw,
               const float* __restrict__ bias,
               unsigned short* __restrict__ out_bf) {
  const int K = 1024;
  __shared__ unsigned short sA[2][256 * 64];
  __shared__ unsigned short sB[2][128 * 64];
  const int t = threadIdx.x;
  const int wave = t >> 6, lane = t & 63;
  const int quad = lane >> 4, l16 = lane & 15;
  const int wm = (wave >> 1) * 64, wn = (wave & 1) * 64;   // 4m x 2n
  const int id = blockIdx.x;
  const int xcd = id & 7, r_ = id >> 3;        // r_ in [0,64)
  const int m_blk = xcd * 2 + (r_ & 1);        // [0,16)  A-local
  const int n_blk = r_ >> 1;                   // [0,32)
  const int m0 = m_blk * 256, n0 = n_blk * 128;

  f32x4 acc[4][4];
  #pragma unroll
  for (int i = 0; i < 4; i++)
    #pragma unroll
    for (int j = 0; j < 4; j++) acc[i][j] = (f32x4){0.f, 0.f, 0.f, 0.f};

  const int sc = (((t & 7) ^ ((t >> 3) & 7)) * 8);   // swizzled source chunk
  const unsigned short* gA = A  + (m0 + (t >> 3)) * K + sc;   // t>>3 in [0,64)
  const unsigned short* gB = Bw + (n0 + (t >> 3)) * K + sc;

  auto stage = [&](int k0, int buf) {
    // 512 threads cover 64 rows per gload; wave w owns rows [8w,8w+8)
    #pragma unroll
    for (int i = 0; i < 4; i++)
      __builtin_amdgcn_global_load_lds((const unsigned int*)(gA + (64 * i) * K + k0),
                                       (unsigned int*)(&sA[buf][(64 * i + wave * 8) * 64]), 16, 0, 0);
    #pragma unroll
    for (int i = 0; i < 2; i++)
      __builtin_amdgcn_global_load_lds((const unsigned int*)(gB + (64 * i) * K + k0),
                                       (unsigned int*)(&sB[buf][(64 * i + wave * 8) * 64]), 16, 0, 0);
  };

  stage(0, 0);
  asm volatile("s_waitcnt vmcnt(0)" ::: "memory");
  __builtin_amdgcn_s_barrier();

  const int so0 = ((quad ^ (l16 & 7)) * 8);          // kk=0 read slot
  const int so1 = (((4 + quad) ^ (l16 & 7)) * 8);    // kk=1 read slot

  const int nk = K >> 6;   // 16
  for (int kt = 0; kt < nk; kt++) {
    const int cur = kt & 1;
    if (kt + 1 < nk) stage((kt + 1) * 64, cur ^ 1);
    const unsigned short* rA = &sA[cur][0];
    const unsigned short* rB = &sB[cur][0];
    #pragma unroll
    for (int kk = 0; kk < 2; kk++) {
      const int so = kk ? so1 : so0;
      bf16x8 af[4], bfr[4];
      #pragma unroll
      for (int i = 0; i < 4; i++)
        af[i] = *(const bf16x8*)(&rA[(wm + i * 16 + l16) * 64 + so]);
      #pragma unroll
      for (int j = 0; j < 4; j++)
        bfr[j] = *(const bf16x8*)(&rB[(wn + j * 16 + l16) * 64 + so]);
      __builtin_amdgcn_s_setprio(1);
      #pragma unroll
      for (int i = 0; i < 4; i++)
        #pragma unroll
        for (int j = 0; j < 4; j++)
          acc[i][j] = __builtin_amdgcn_mfma_f32_16x16x32_bf16(af[i], bfr[j], acc[i][j], 0, 0, 0);
      __builtin_amdgcn_s_setprio(0);
    }
    asm volatile("s_waitcnt vmcnt(0)" ::: "memory");
    __builtin_amdgcn_s_barrier();
  }

  #pragma unroll
  for (int i = 0; i < 4; i++) {
    #pragma unroll
    for (int j = 0; j < 4; j++) {
      int col = n0 + wn + j * 16 + l16;
      float bb = bias[col];
      #pragma unroll
      for (int r = 0; r < 4; r++) {
        int row = m0 + wm + i * 16 + quad * 4 + r;
        float v = acc[i][j][r] + bb;
        float w = v * (1.0f + 0.044715f * v * v);
        float gl = v / (1.0f + __expf(-1.5957691216f * w));
        out_bf[row * 4096 + col] = f2bf(gl);
      }
    }
  }
}

// ---------------- QKV GEMM on the T4 skeleton, RoPE epilogue -----------------
// (round-12 verified)
__global__ __launch_bounds__(256)
void gemm_qkv_t4(const unsigned short* __restrict__ A,
                 const unsigned short* __restrict__ Bw,
                 const float* __restrict__ bq, const float* __restrict__ bk,
                 const float* __restrict__ bv,
                 const float* __restrict__ rc, const float* __restrict__ rs,
                 unsigned short* __restrict__ qo, unsigned short* __restrict__ ko,
                 unsigned short* __restrict__ vt) {
  const int K = C_;
  __shared__ unsigned short sA[3][128 * 64];
  __shared__ unsigned short sB[3][64 * 64];
  const int t = threadIdx.x;
  const int wave = t >> 6, lane = t & 63;
  const int quad = lane >> 4, l16 = lane & 15;
  const int wm = wave * 32;                        // 4m x 1n wave grid
  const int id = blockIdx.x;                       // [0,1536)
  const int xcd = id & 7, r_ = id >> 3;            // r_ in [0,192)
  const int m_blk = xcd * 4 + (r_ & 3);            // [0,32)  A-local
  const int n_blk = r_ >> 2;                       // [0,48)
  const int m0 = m_blk * 128, n0 = n_blk * 64;

  f32x4 acc[2][4];
  #pragma unroll
  for (int i = 0; i < 2; i++)
    #pragma unroll
    for (int j = 0; j < 4; j++) acc[i][j] = (f32x4){0.f, 0.f, 0.f, 0.f};

  const int sc = (((t & 7) ^ ((t >> 3) & 7)) * 8);
  const unsigned short* gA = A  + (m0 + (t >> 3)) * K + sc;
  const unsigned short* gB = Bw + (n0 + (t >> 3)) * K + sc;

  auto stage = [&](int k0, int buf) {
    unsigned short* lA = &sA[buf][(wave * 8) * 64];
    unsigned short* lB = &sB[buf][(wave * 8) * 64];
    #pragma unroll
    for (int i = 0; i < 4; i++)
      __builtin_amdgcn_global_load_lds((const unsigned int*)(gA + (32 * i) * K + k0),
                                       (unsigned int*)(lA + 32 * i * 64), 16, 0, 0);
    #pragma unroll
    for (int i = 0; i < 2; i++)
      __builtin_amdgcn_global_load_lds((const unsigned int*)(gB + (32 * i) * K + k0),
                                       (unsigned int*)(lB + 32 * i * 64), 16, 0, 0);
  };

  stage(0, 0);
  stage(64, 1);
  asm volatile("s_waitcnt vmcnt(6)" ::: "memory");
  __builtin_amdgcn_s_barrier();

  const int so0 = ((quad ^ (l16 & 7)) * 8);
  const int so1 = (((4 + quad) ^ (l16 & 7)) * 8);

  const int nk = K >> 6;   // 16
  int cur = 0;
  for (int kt = 0; kt < nk; kt++) {
    const unsigned short* rA = &sA[cur][0];
    const unsigned short* rB = &sB[cur][0];
    #pragma unroll
    for (int kk = 0; kk < 2; kk++) {
      const int so = kk ? so1 : so0;
      bf16x8 af[2], bfr[4];
      #pragma unroll
      for (int i = 0; i < 2; i++)
        af[i] = *(const bf16x8*)(&rA[(wm + i * 16 + l16) * 64 + so]);
      #pragma unroll
      for (int j = 0; j < 4; j++)
        bfr[j] = *(const bf16x8*)(&rB[(j * 16 + l16) * 64 + so]);
      __builtin_amdgcn_s_setprio(1);
      #pragma unroll
      for (int i = 0; i < 2; i++)
        #pragma unroll
        for (int j = 0; j < 4; j++)
          acc[i][j] = __builtin_amdgcn_mfma_f32_16x16x32_bf16(af[i], bfr[j], acc[i][j], 0, 0, 0);
      __builtin_amdgcn_s_setprio(0);
    }
    if (kt + 2 < nk) {
      const int nb = (cur + 2 >= 3) ? cur - 1 : cur + 2;   // (kt+2)%3
      stage((kt + 2) * 64, nb);
      asm volatile("s_waitcnt vmcnt(6)" ::: "memory");
    } else {
      asm volatile("s_waitcnt vmcnt(0)" ::: "memory");
    }
    __builtin_amdgcn_s_barrier();
    cur = (cur == 2) ? 0 : cur + 1;
  }

  const int rgn = n_blk >> 4;                 // 0=q, 1=k, 2=v
  const int h   = n_blk & 15;

  if (rgn == 2) {
    #pragma unroll
    for (int i = 0; i < 2; i++) {
      int row0 = m0 + wm + i * 16 + quad * 4;      // token of r=0
      int bidx = row0 >> 11, n0r = row0 & 2047;
      #pragma unroll
      for (int j = 0; j < 4; j++) {
        int d = j * 16 + l16;
        float bb = bv[h * 64 + d];
        __hip_bfloat162 p01 = __float22bfloat162_rn(float2{acc[i][j][0] + bb, acc[i][j][1] + bb});
        __hip_bfloat162 p23 = __float22bfloat162_rn(float2{acc[i][j][2] + bb, acc[i][j][3] + bb});
        unsigned int u01, u23;
        __builtin_memcpy(&u01, &p01, 4);
        __builtin_memcpy(&u23, &p23, 4);
        *(uint2*)(vt + (((bidx * 16 + h) * 64) + d) * 2048 + n0r) = make_uint2(u01, u23);
      }
    }
  } else {
    const float* bia = (rgn == 0) ? bq : bk;
    unsigned short* outp = (rgn == 0) ? qo : ko;
    #pragma unroll
    for (int i = 0; i < 2; i++) {
      #pragma unroll
      for (int r = 0; r < 4; r++) {
        int row = m0 + wm + i * 16 + quad * 4 + r;
        int bidx = row >> 11, n = row & 2047;
        #pragma unroll
        for (int j = 0; j < 4; j++) {
          int d = j * 16 + l16;
          int c = h * 64 + d;                      // within-region column
          int oi = ((bidx * 16 + h) * 2048 + n) * 64 + d;
          float val = acc[i][j][r] + bia[c];
          float pv  = acc[i][j ^ 2][r] + bia[c ^ 32];
          float rot = (j < 2) ? -pv : pv;          // rotate_half
          float y = val * rc[n * 64 + d] + rot * rs[n * 64 + d];
          if (rgn == 0) y *= 0.125f;               // fold D^-0.5 into q
          outp[oi] = f2bf(y);
        }
      }
    }
  }
}

// ---------------- Flash attention v7: 8-wave blocks + kv-split + T5 ----------
__global__ __launch_bounds__(512)
void flash_attn(const unsigned short* __restrict__ q,
                const unsigned short* __restrict__ k,
                const unsigned short* __restrict__ vt,
                unsigned short* __restrict__ o0h,
                unsigned short* __restrict__ o1h,
                float* __restrict__ l0g, float* __restrict__ l1g) {
  __shared__ unsigned short sK[2][64 * 64];
  __shared__ unsigned short sVt[2][64 * 64];
  __shared__ unsigned short sPt[2][8][16 * 72];
  const int t = threadIdx.x;
  const int wave = t >> 6, lane = t & 63;
  const int quad = lane >> 4, l16 = lane & 15;
  const int id = blockIdx.x;
  const int bh = (id & 7) * 4 + ((id >> 3) & 3);  // 4 heads per XCD (L2-local)
  const int qb = (id >> 5) & 7;                   // 8 blocks of 256 q-rows
  const int kvh = id >> 8;                        // kv half
  const int base = bh * (N_ * D_);

  bf16x8 qa[2][2];
  #pragma unroll
  for (int qt = 0; qt < 2; qt++) {
    int qrow = qb * 256 + wave * 32 + qt * 16 + l16;
    #pragma unroll
    for (int kk = 0; kk < 2; kk++)
      qa[qt][kk] = *(const bf16x8*)(q + base + qrow * D_ + kk * 32 + quad * 8);
  }
  float l_i[2] = {0.f, 0.f};
  f32x4 o_acc[2][4];
  #pragma unroll
  for (int qt = 0; qt < 2; qt++)
    #pragma unroll
    for (int dt = 0; dt < 4; dt++) o_acc[qt][dt] = (f32x4){0.f, 0.f, 0.f, 0.f};

  const int sc = (((t & 7) ^ ((t >> 3) & 7)) * 8);   // T2 source chunk
  const unsigned short* gK  = k  + base + (t >> 3) * 64 + sc;
  const unsigned short* gVt = vt + bh * (64 * 2048) + (t >> 3) * 2048 + sc;

  auto stage = [&](int kt, int buf) {
    __builtin_amdgcn_global_load_lds((const unsigned int*)(gK + kt * 64 * 64),
                                     (unsigned int*)(&sK[buf][(wave * 8) * 64]), 16, 0, 0);
    __builtin_amdgcn_global_load_lds((const unsigned int*)(gVt + kt * 64),
                                     (unsigned int*)(&sVt[buf][(wave * 8) * 64]), 16, 0, 0);
  };
  const int kt0 = kvh * 16, kt1 = kt0 + 16;
  stage(kt0, 0);
  __syncthreads();

  const int so0 = ((quad ^ (l16 & 7)) * 8);          // kk=0 read slot
  const int so1 = (((4 + quad) ^ (l16 & 7)) * 8);    // kk=1 read slot

  for (int kt = kt0; kt < kt1; kt++) {
    const int cur = kt & 1;
    if (kt + 1 < kt1) stage(kt + 1, cur ^ 1);

    f32x4 s_acc[2][4];
    __builtin_amdgcn_s_setprio(1);
    #pragma unroll
    for (int nt = 0; nt < 4; nt++) {
      bf16x8 kb0 = *(const bf16x8*)(&sK[cur][(nt * 16 + l16) * 64 + so0]);
      bf16x8 kb1 = *(const bf16x8*)(&sK[cur][(nt * 16 + l16) * 64 + so1]);
      #pragma unroll
      for (int qt = 0; qt < 2; qt++) {
        f32x4 a = (f32x4){0.f, 0.f, 0.f, 0.f};
        a = __builtin_amdgcn_mfma_f32_16x16x32_bf16(kb0, qa[qt][0], a, 0, 0, 0);
        a = __builtin_amdgcn_mfma_f32_16x16x32_bf16(kb1, qa[qt][1], a, 0, 0, 0);
        s_acc[qt][nt] = a;
      }
    }
    __builtin_amdgcn_s_setprio(0);
    #pragma unroll
    for (int qt = 0; qt < 2; qt++) {
      float rsum = 0.f;
      #pragma unroll
      for (int nt = 0; nt < 4; nt++)
        #pragma unroll
        for (int r = 0; r < 4; r++) {
          float p = __expf(s_acc[qt][nt][r]);
          s_acc[qt][nt][r] = p;
          rsum += p;
        }
      rsum += __shfl_xor(rsum, 16);
      rsum += __shfl_xor(rsum, 32);
      l_i[qt] += rsum;
      #pragma unroll
      for (int nt = 0; nt < 4; nt++) {
        __hip_bfloat162 p01 = __float22bfloat162_rn(float2{s_acc[qt][nt][0], s_acc[qt][nt][1]});
        __hip_bfloat162 p23 = __float22bfloat162_rn(float2{s_acc[qt][nt][2], s_acc[qt][nt][3]});
        unsigned int u01, u23;
        __builtin_memcpy(&u01, &p01, 4);
        __builtin_memcpy(&u23, &p23, 4);
        *(uint2*)(&sPt[qt][wave][l16 * 72 + nt * 16 + quad * 4]) = make_uint2(u01, u23);
      }
    }
    __asm__ volatile("s_waitcnt lgkmcnt(0)" ::: "memory");
    bf16x8 pt[2][2];
    #pragma unroll
    for (int qt = 0; qt < 2; qt++) {
      pt[qt][0] = *(const bf16x8*)(&sPt[qt][wave][l16 * 72 + quad * 8]);
      pt[qt][1] = *(const bf16x8*)(&sPt[qt][wave][l16 * 72 + 32 + quad * 8]);
    }
    __builtin_amdgcn_s_setprio(1);
    #pragma unroll
    for (int dt = 0; dt < 4; dt++) {
      int d0 = dt * 16 + l16;
      bf16x8 va0 = *(const bf16x8*)(&sVt[cur][d0 * 64 + so0]);
      bf16x8 va1 = *(const bf16x8*)(&sVt[cur][d0 * 64 + so1]);
      #pragma unroll
      for (int qt = 0; qt < 2; qt++) {
        o_acc[qt][dt] = __builtin_amdgcn_mfma_f32_16x16x32_bf16(va0, pt[qt][0], o_acc[qt][dt], 0, 0, 0);
        o_acc[qt][dt] = __builtin_amdgcn_mfma_f32_16x16x32_bf16(va1, pt[qt][1], o_acc[qt][dt], 0, 0, 0);
      }
    }
    __builtin_amdgcn_s_setprio(0);
    __syncthreads();
  }

  unsigned short* op = kvh ? o1h : o0h;
  float* lp = kvh ? l1g : l0g;
  const int b = bh >> 4, h = bh & 15;
  #pragma unroll
  for (int qt = 0; qt < 2; qt++) {
    const int qrow = qb * 256 + wave * 32 + qt * 16 + l16;
    if (quad == 0) lp[bh * 2048 + qrow] = l_i[qt];
    const int tok = b * N_ + qrow;
    #pragma unroll
    for (int dt = 0; dt < 4; dt++) {
      __hip_bfloat162 p01 = __float22bfloat162_rn(float2{o_acc[qt][dt][0], o_acc[qt][dt][1]});
      __hip_bfloat162 p23 = __float22bfloat162_rn(float2{o_acc[qt][dt][2], o_acc[qt][dt][3]});
      unsigned int u01, u23;
      __builtin_memcpy(&u01, &p01, 4);
      __builtin_memcpy(&u23, &p23, 4);
      int col = h * 64 + dt * 16 + quad * 4;
      *(uint2*)(op + tok * C_ + col) = make_uint2(u01, u23);
    }
  }
}

// ---------------- combine the two kv halves: ao = (o0+o1)/(l0+l1) ------------
__global__ __launch_bounds__(256)
void attn_norm(const unsigned short* __restrict__ o0h,
               const unsigned short* __restrict__ o1h,
               const float* __restrict__ l0g, const float* __restrict__ l1g,
               unsigned short* __restrict__ o) {
  const int i = (blockIdx.x * 256 + threadIdx.x) * 8;
  const int row = i >> 10, c = i & 1023;
  const int h = c >> 6;
  const int b = row >> 11, n = row & 2047;
  const int li = (b * 16 + h) * 2048 + n;
  const float inv = 1.0f / (l0g[li] + l1g[li]);
  ushort4 a0 = *(const ushort4*)(o0h + i);
  ushort4 a1 = *(const ushort4*)(o0h + i + 4);
  ushort4 b0 = *(const ushort4*)(o1h + i);
  ushort4 b1 = *(const ushort4*)(o1h + i + 4);
  ushort4 r0, r1;
  r0.x = f2bf((bf2f(a0.x) + bf2f(b0.x)) * inv);
  r0.y = f2bf((bf2f(a0.y) + bf2f(b0.y)) * inv);
  r0.z = f2bf((bf2f(a0.z) + bf2f(b0.z)) * inv);
  r0.w = f2bf((bf2f(a0.w) + bf2f(b0.w)) * inv);
  r1.x = f2bf((bf2f(a1.x) + bf2f(b1.x)) * inv);
  r1.y = f2bf((bf2f(a1.y) + bf2f(b1.y)) * inv);
  r1.z = f2bf((bf2f(a1.z) + bf2f(b1.z)) * inv);
  r1.w = f2bf((bf2f(a1.w) + bf2f(b1.w)) * inv);
  *(ushort4*)(o + i) = r0;
  *(ushort4*)(o + i + 4) = r1;
}

// ---------------- launcher ---------------------------------------------------
extern "C" void kernel_launch(void* const* d_in, const int* in_sizes, int n_in,
                              void* d_out, int out_size, void* d_ws, size_t ws_size,
                              hipStream_t stream) {
  const float* x   = (const float*)d_in[0];
  const float* rc  = (const float*)d_in[1];
  const float* rs  = (const float*)d_in[2];
  const float* g1  = (const float*)d_in[3];
  const float* be1 = (const float*)d_in[4];
  const float* Wq  = (const float*)d_in[5];
  const float* bq  = (const float*)d_in[6];
  const float* Wk  = (const float*)d_in[7];
  const float* bk  = (const float*)d_in[8];
  const float* Wv  = (const float*)d_in[9];
  const float* bv  = (const float*)d_in[10];
  const float* Wo  = (const float*)d_in[11];
  const float* bo  = (const float*)d_in[12];
  const float* g2  = (const float*)d_in[13];
  const float* be2 = (const float*)d_in[14];
  const float* W1  = (const float*)d_in[15];
  const float* b1m = (const float*)d_in[16];
  const float* W2  = (const float*)d_in[17];
  const float* b2m = (const float*)d_in[18];
  float* out = (float*)d_out;

  char* ws = (char*)d_ws;
  unsigned short* wqkv = (unsigned short*)(ws + 0);           // 6 MB
  unsigned short* wo   = (unsigned short*)(ws + 6291456);     // 2 MB
  unsigned short* w1   = (unsigned short*)(ws + 8388608);     // 8 MB
  unsigned short* w2   = (unsigned short*)(ws + 16777216);    // 8 MB
  unsigned short* h1   = (unsigned short*)(ws + 25165824);    // 8 MB (ln out; attn o1 partial; ln2 out)
  unsigned short* qa   = (unsigned short*)(ws + 33554432);    // 8 MB
  unsigned short* ka   = (unsigned short*)(ws + 41943040);    // 8 MB
  unsigned short* va   = (unsigned short*)(ws + 50331648);    // 8 MB (V^T: B*H x D x N)
  unsigned short* ao   = (unsigned short*)(ws + 58720256);    // 8 MB (attn o0 partial -> normalized)
  float*          x1   = (float*)(ws + 67108864);             // 16 MB
  float*          l0   = (float*)(ws + 67108864);             // 256 KB (dead before x1 written)
  float*          l1   = l0 + 65536;                          // 256 KB
  unsigned short* u    = (unsigned short*)(ws + 33554432);    // overlays qa..ao (dead by MLP1)

  // fused weight-cvt + LN1 (one dispatch; all outputs ready before QKV)
  ln1_cvt<<<16384, 256, 0, stream>>>(
      x, g1, be1, h1,
      (const float4*)Wq, (const float4*)Wk, (const float4*)Wv, (const float4*)Wo,
      (const float4*)W1, (const float4*)W2,
      (ushort4*)wqkv, (ushort4*)(wqkv + 1048576), (ushort4*)(wqkv + 2097152),
      (ushort4*)wo, (ushort4*)w1, (ushort4*)w2);

  gemm_qkv_t4<<<1536, 256, 0, stream>>>(h1, wqkv, bq, bk, bv, rc, rs, qa, ka, va);
  flash_attn<<<512, 512, 0, stream>>>(qa, ka, va, ao, h1, l0, l1);
  attn_norm<<<2048, 256, 0, stream>>>(ao, h1, l0, l1, ao);
  gemm_bt<1, 64><<<dim3(16, 32), 256, 0, stream>>>(ao, wo, 1024, 1024, 2, bo, x, nullptr, x1);
  ln_kernel<<<4096, 256, 0, stream>>>(x1, g2, be2, h1);
  gemm_mlp1<<<512, 512, 0, stream>>>(h1, w1, b1m, u);
  gemm_bt<3, 64><<<dim3(16, 32), 256, 0, stream>>>(u, w2, 4096, 1024, 2, b2m, x1, nullptr, out);
}

// Round 14
// 347.923 us; speedup vs baseline: 1.1210x; 1.0209x over previous
//
#include <hip/hip_runtime.h>
#include <hip/hip_bf16.h>

#define B_ 2
#define N_ 2048
#define C_ 1024
#define H_ 16
#define D_ 64
#define F_ 4096
#define M_ 4096  // B_*N_

typedef __attribute__((ext_vector_type(8))) short bf16x8;
typedef __attribute__((ext_vector_type(4))) float f32x4;

__device__ inline unsigned short f2bf(float f) {
  unsigned int u = __float_as_uint(f);
  u = (u + 0x7FFFu + ((u >> 16) & 1u)) >> 16;
  return (unsigned short)u;
}
__device__ inline float bf2f(unsigned short u) {
  unsigned int x = ((unsigned int)u) << 16;
  return __uint_as_float(x);
}

// ---------------- fused: all-weights fp32->bf16  +  LayerNorm1 ---------------
__global__ __launch_bounds__(256)
void ln1_cvt(const float* __restrict__ x, const float* __restrict__ g,
             const float* __restrict__ bln, unsigned short* __restrict__ out,
             const float4* __restrict__ s0, const float4* __restrict__ s1,
             const float4* __restrict__ s2, const float4* __restrict__ s3,
             const float4* __restrict__ s4, const float4* __restrict__ s5,
             ushort4* __restrict__ d0, ushort4* __restrict__ d1,
             ushort4* __restrict__ d2, ushort4* __restrict__ d3,
             ushort4* __restrict__ d4, ushort4* __restrict__ d5) {
  const int b = blockIdx.x;
  if (b < 12288) {
    const float4* s; ushort4* d; int i;
    if      (b < 1024) { s = s0; d = d0; i = b * 256 + threadIdx.x; }
    else if (b < 2048) { s = s1; d = d1; i = (b - 1024) * 256 + threadIdx.x; }
    else if (b < 3072) { s = s2; d = d2; i = (b - 2048) * 256 + threadIdx.x; }
    else if (b < 4096) { s = s3; d = d3; i = (b - 3072) * 256 + threadIdx.x; }
    else if (b < 8192) { s = s4; d = d4; i = (b - 4096) * 256 + threadIdx.x; }
    else               { s = s5; d = d5; i = (b - 8192) * 256 + threadIdx.x; }
    float4 f = s[i];
    ushort4 o;
    o.x = f2bf(f.x); o.y = f2bf(f.y); o.z = f2bf(f.z); o.w = f2bf(f.w);
    d[i] = o;
    return;
  }
  __shared__ float red[8];
  const int row = b - 12288;
  const int t = threadIdx.x;
  const float4 xv = *(const float4*)(x + row * 1024 + t * 4);
  float s  = xv.x + xv.y + xv.z + xv.w;
  float sq = xv.x * xv.x + xv.y * xv.y + xv.z * xv.z + xv.w * xv.w;
  #pragma unroll
  for (int off = 32; off >= 1; off >>= 1) {
    s  += __shfl_down(s, off);
    sq += __shfl_down(sq, off);
  }
  const int lane = t & 63, wave = t >> 6;
  if (lane == 0) { red[wave * 2] = s; red[wave * 2 + 1] = sq; }
  __syncthreads();
  float ts = red[0] + red[2] + red[4] + red[6];
  float tq = red[1] + red[3] + red[5] + red[7];
  float mean = ts * (1.0f / 1024.0f);
  float var  = tq * (1.0f / 1024.0f) - mean * mean;
  float rstd = rsqrtf(var + 1e-6f);
  float xs[4] = {xv.x, xv.y, xv.z, xv.w};
  #pragma unroll
  for (int i = 0; i < 4; i++) {
    int c = t * 4 + i;
    float y = (xs[i] - mean) * rstd * g[c] + bln[c];
    out[row * 1024 + c] = f2bf(y);
  }
}

// ---------------- LayerNorm: fp32 in -> bf16 out (ln2) ------------------------
__global__ __launch_bounds__(256)
void ln_kernel(const float* __restrict__ x, const float* __restrict__ g,
               const float* __restrict__ b, unsigned short* __restrict__ out) {
  __shared__ float red[8];
  const int row = blockIdx.x;
  const int t = threadIdx.x;
  const float4 xv = *(const float4*)(x + row * 1024 + t * 4);
  float s  = xv.x + xv.y + xv.z + xv.w;
  float sq = xv.x * xv.x + xv.y * xv.y + xv.z * xv.z + xv.w * xv.w;
  #pragma unroll
  for (int off = 32; off >= 1; off >>= 1) {
    s  += __shfl_down(s, off);
    sq += __shfl_down(sq, off);
  }
  const int lane = t & 63, wave = t >> 6;
  if (lane == 0) { red[wave * 2] = s; red[wave * 2 + 1] = sq; }
  __syncthreads();
  float ts = red[0] + red[2] + red[4] + red[6];
  float tq = red[1] + red[3] + red[5] + red[7];
  float mean = ts * (1.0f / 1024.0f);
  float var  = tq * (1.0f / 1024.0f) - mean * mean;
  float rstd = rsqrtf(var + 1e-6f);
  float xs[4] = {xv.x, xv.y, xv.z, xv.w};
  #pragma unroll
  for (int i = 0; i < 4; i++) {
    int c = t * 4 + i;
    float y = (xs[i] - mean) * rstd * g[c] + b[c];
    out[row * 1024 + c] = f2bf(y);
  }
}

// ---------------- GEMM (128x64 tile, 3-buffer counted-vmcnt, T2, m-local) ----
// MODE 1: +bias +resid -> fp32 [O-proj]   MODE 3: same [MLP2 -> d_out]
// Round-12 verified (T4 late-issue + T5 setprio).
template<int MODE, int BN>
__global__ __launch_bounds__(256)
void gemm_bt(const unsigned short* __restrict__ A,
             const unsigned short* __restrict__ Bw,
             int K, int Nout, int npc,
             const float* __restrict__ bias,
             const float* __restrict__ resid,
             unsigned short* __restrict__ out_bf,
             float* __restrict__ out_f32) {
  constexpr int NJ = BN / 32;
  static_assert(BN == 64, "vmcnt literal assumes 6 loads per stage");
  __shared__ unsigned short sA[3][128 * 64];
  __shared__ unsigned short sB[3][BN * 64];
  const int t = threadIdx.x;
  const int wave = t >> 6, lane = t & 63;
  const int quad = lane >> 4, l16 = lane & 15;
  const int wm = (wave & 1) * 64, wn = (wave >> 1) * (BN / 2);
  const int id = blockIdx.y * gridDim.x + blockIdx.x;
  const int xcd = id & 7, r_ = id >> 3;
  const int m_blk = xcd * 4 + (r_ & 3);
  const int n_blk = r_ >> 2;
  const int m0 = m_blk * 128, n0 = n_blk * BN;

  f32x4 acc[4][NJ];
  #pragma unroll
  for (int i = 0; i < 4; i++)
    #pragma unroll
    for (int j = 0; j < NJ; j++) acc[i][j] = (f32x4){0.f, 0.f, 0.f, 0.f};

  const int sc = (((t & 7) ^ ((t >> 3) & 7)) * 8);   // swizzled source chunk
  const unsigned short* gA = A  + (m0 + (t >> 3)) * K + sc;
  const unsigned short* gB = Bw + (n0 + (t >> 3)) * K + sc;

  auto stage = [&](int k0, int buf) {
    unsigned short* lA = &sA[buf][(wave * 8) * 64];
    unsigned short* lB = &sB[buf][(wave * 8) * 64];
    #pragma unroll
    for (int i = 0; i < 4; i++)
      __builtin_amdgcn_global_load_lds((const unsigned int*)(gA + (32 * i) * K + k0),
                                       (unsigned int*)(lA + 32 * i * 64), 16, 0, 0);
    #pragma unroll
    for (int i = 0; i < BN / 32; i++)
      __builtin_amdgcn_global_load_lds((const unsigned int*)(gB + (32 * i) * K + k0),
                                       (unsigned int*)(lB + 32 * i * 64), 16, 0, 0);
  };

  // prologue: tiles 0,1 -> bufs 0,1 (12 loads); retire tile 0 only.
  stage(0, 0);
  stage(64, 1);
  asm volatile("s_waitcnt vmcnt(6)" ::: "memory");
  __builtin_amdgcn_s_barrier();

  const int so0 = ((quad ^ (l16 & 7)) * 8);          // kk=0 read slot
  const int so1 = (((4 + quad) ^ (l16 & 7)) * 8);    // kk=1 read slot

  const int nk = K >> 6;
  int cur = 0;
  for (int kt = 0; kt < nk; kt++) {
    const unsigned short* rA = &sA[cur][0];
    const unsigned short* rB = &sB[cur][0];
    #pragma unroll
    for (int kk = 0; kk < 2; kk++) {
      const int so = kk ? so1 : so0;
      bf16x8 af[4], bfr[NJ];
      #pragma unroll
      for (int i = 0; i < 4; i++)
        af[i] = *(const bf16x8*)(&rA[(wm + i * 16 + l16) * 64 + so]);
      #pragma unroll
      for (int j = 0; j < NJ; j++)
        bfr[j] = *(const bf16x8*)(&rB[(wn + j * 16 + l16) * 64 + so]);
      __builtin_amdgcn_s_setprio(1);
      #pragma unroll
      for (int i = 0; i < 4; i++)
        #pragma unroll
        for (int j = 0; j < NJ; j++)
          acc[i][j] = __builtin_amdgcn_mfma_f32_16x16x32_bf16(af[i], bfr[j], acc[i][j], 0, 0, 0);
      __builtin_amdgcn_s_setprio(0);
    }
    if (kt + 2 < nk) {
      const int nb = (cur + 2 >= 3) ? cur - 1 : cur + 2;   // (kt+2)%3
      stage((kt + 2) * 64, nb);
      asm volatile("s_waitcnt vmcnt(6)" ::: "memory");
    } else {
      asm volatile("s_waitcnt vmcnt(0)" ::: "memory");
    }
    __builtin_amdgcn_s_barrier();
    cur = (cur == 2) ? 0 : cur + 1;
  }

  #pragma unroll
  for (int i = 0; i < 4; i++) {
    #pragma unroll
    for (int j = 0; j < NJ; j++) {
      int col = n0 + wn + j * 16 + l16;
      #pragma unroll
      for (int r = 0; r < 4; r++) {
        int row = m0 + wm + i * 16 + quad * 4 + r;
        float v = acc[i][j][r];
        if (MODE == 1 || MODE == 3) {
          out_f32[row * Nout + col] = v + bias[col] + resid[row * Nout + col];
        } else {
          v += bias[col];
          float w = v * (1.0f + 0.044715f * v * v);
          float gl = v / (1.0f + __expf(-1.5957691216f * w));
          out_bf[row * Nout + col] = f2bf(gl);
        }
      }
    }
  }
}

// ---------------- MLP1: 256x128 tile, 512 thr, 3-buffer counted-vmcnt --------
// Round-13 proved the (256,128) tile (L2 traffic halved, dur 68.4->61.4) but
// its 2-buf vmcnt(0) drain exposed full DMA latency per K-tile (~4600 cyc vs
// ~850 demand). THIS ROUND: the round-8-verified T4 skeleton at this tile —
// 3 LDS buffers (144 KB <= 160), prefetch distance 2, late stage issue,
// counted vmcnt(6) + raw s_barrier, tail vmcnt(0). Ledger (6 gloads/thread/
// stage): at the wait, outstanding = 6(t+1)+6(t+2)=12 -> vmcnt(6) retires
// exactly t+1, leaves t+2 in flight. stage targets (cur+2)%3, sealed by the
// previous barrier. 8 waves (4m x 2n, wave owns 64x64), T2 swizzle, A-local.
__global__ __launch_bounds__(512, 1)
void gemm_mlp1(const unsigned short* __restrict__ A,
               const unsigned short* __restrict__ Bw,
               const float* __restrict__ bias,
               unsigned short* __restrict__ out_bf) {
  const int K = 1024;
  __shared__ unsigned short sA[3][256 * 64];
  __shared__ unsigned short sB[3][128 * 64];
  const int t = threadIdx.x;
  const int wave = t >> 6, lane = t & 63;
  const int quad = lane >> 4, l16 = lane & 15;
  const int wm = (wave >> 1) * 64, wn = (wave & 1) * 64;   // 4m x 2n
  const int id = blockIdx.x;
  const int xcd = id & 7, r_ = id >> 3;        // r_ in [0,64)
  const int m_blk = xcd * 2 + (r_ & 1);        // [0,16)  A-local
  const int n_blk = r_ >> 1;                   // [0,32)
  const int m0 = m_blk * 256, n0 = n_blk * 128;

  f32x4 acc[4][4];
  #pragma unroll
  for (int i = 0; i < 4; i++)
    #pragma unroll
    for (int j = 0; j < 4; j++) acc[i][j] = (f32x4){0.f, 0.f, 0.f, 0.f};

  const int sc = (((t & 7) ^ ((t >> 3) & 7)) * 8);   // swizzled source chunk
  const unsigned short* gA = A  + (m0 + (t >> 3)) * K + sc;   // t>>3 in [0,64)
  const unsigned short* gB = Bw + (n0 + (t >> 3)) * K + sc;

  auto stage = [&](int k0, int buf) {
    // 512 threads cover 64 rows per gload; wave w owns rows [8w,8w+8)
    #pragma unroll
    for (int i = 0; i < 4; i++)
      __builtin_amdgcn_global_load_lds((const unsigned int*)(gA + (64 * i) * K + k0),
                                       (unsigned int*)(&sA[buf][(64 * i + wave * 8) * 64]), 16, 0, 0);
    #pragma unroll
    for (int i = 0; i < 2; i++)
      __builtin_amdgcn_global_load_lds((const unsigned int*)(gB + (64 * i) * K + k0),
                                       (unsigned int*)(&sB[buf][(64 * i + wave * 8) * 64]), 16, 0, 0);
  };

  // prologue: tiles 0,1 -> bufs 0,1 (12 loads/thread); retire tile 0 only.
  stage(0, 0);
  stage(64, 1);
  asm volatile("s_waitcnt vmcnt(6)" ::: "memory");
  __builtin_amdgcn_s_barrier();

  const int so0 = ((quad ^ (l16 & 7)) * 8);          // kk=0 read slot
  const int so1 = (((4 + quad) ^ (l16 & 7)) * 8);    // kk=1 read slot

  const int nk = K >> 6;   // 16
  int cur = 0;
  for (int kt = 0; kt < nk; kt++) {
    const unsigned short* rA = &sA[cur][0];
    const unsigned short* rB = &sB[cur][0];
    #pragma unroll
    for (int kk = 0; kk < 2; kk++) {
      const int so = kk ? so1 : so0;
      bf16x8 af[4], bfr[4];
      #pragma unroll
      for (int i = 0; i < 4; i++)
        af[i] = *(const bf16x8*)(&rA[(wm + i * 16 + l16) * 64 + so]);
      #pragma unroll
      for (int j = 0; j < 4; j++)
        bfr[j] = *(const bf16x8*)(&rB[(wn + j * 16 + l16) * 64 + so]);
      __builtin_amdgcn_s_setprio(1);
      #pragma unroll
      for (int i = 0; i < 4; i++)
        #pragma unroll
        for (int j = 0; j < 4; j++)
          acc[i][j] = __builtin_amdgcn_mfma_f32_16x16x32_bf16(af[i], bfr[j], acc[i][j], 0, 0, 0);
      __builtin_amdgcn_s_setprio(0);
    }
    if (kt + 2 < nk) {
      const int nb = (cur + 2 >= 3) ? cur - 1 : cur + 2;   // (kt+2)%3
      stage((kt + 2) * 64, nb);
      asm volatile("s_waitcnt vmcnt(6)" ::: "memory");
    } else {
      asm volatile("s_waitcnt vmcnt(0)" ::: "memory");
    }
    __builtin_amdgcn_s_barrier();
    cur = (cur == 2) ? 0 : cur + 1;
  }

  #pragma unroll
  for (int i = 0; i < 4; i++) {
    #pragma unroll
    for (int j = 0; j < 4; j++) {
      int col = n0 + wn + j * 16 + l16;
      float bb = bias[col];
      #pragma unroll
      for (int r = 0; r < 4; r++) {
        int row = m0 + wm + i * 16 + quad * 4 + r;
        float v = acc[i][j][r] + bb;
        float w = v * (1.0f + 0.044715f * v * v);
        float gl = v / (1.0f + __expf(-1.5957691216f * w));
        out_bf[row * 4096 + col] = f2bf(gl);
      }
    }
  }
}

// ---------------- QKV GEMM on the T4 skeleton, RoPE epilogue -----------------
// (round-12/13 verified)
__global__ __launch_bounds__(256)
void gemm_qkv_t4(const unsigned short* __restrict__ A,
                 const unsigned short* __restrict__ Bw,
                 const float* __restrict__ bq, const float* __restrict__ bk,
                 const float* __restrict__ bv,
                 const float* __restrict__ rc, const float* __restrict__ rs,
                 unsigned short* __restrict__ qo, unsigned short* __restrict__ ko,
                 unsigned short* __restrict__ vt) {
  const int K = C_;
  __shared__ unsigned short sA[3][128 * 64];
  __shared__ unsigned short sB[3][64 * 64];
  const int t = threadIdx.x;
  const int wave = t >> 6, lane = t & 63;
  const int quad = lane >> 4, l16 = lane & 15;
  const int wm = wave * 32;                        // 4m x 1n wave grid
  const int id = blockIdx.x;                       // [0,1536)
  const int xcd = id & 7, r_ = id >> 3;            // r_ in [0,192)
  const int m_blk = xcd * 4 + (r_ & 3);            // [0,32)  A-local
  const int n_blk = r_ >> 2;                       // [0,48)
  const int m0 = m_blk * 128, n0 = n_blk * 64;

  f32x4 acc[2][4];
  #pragma unroll
  for (int i = 0; i < 2; i++)
    #pragma unroll
    for (int j = 0; j < 4; j++) acc[i][j] = (f32x4){0.f, 0.f, 0.f, 0.f};

  const int sc = (((t & 7) ^ ((t >> 3) & 7)) * 8);
  const unsigned short* gA = A  + (m0 + (t >> 3)) * K + sc;
  const unsigned short* gB = Bw + (n0 + (t >> 3)) * K + sc;

  auto stage = [&](int k0, int buf) {
    unsigned short* lA = &sA[buf][(wave * 8) * 64];
    unsigned short* lB = &sB[buf][(wave * 8) * 64];
    #pragma unroll
    for (int i = 0; i < 4; i++)
      __builtin_amdgcn_global_load_lds((const unsigned int*)(gA + (32 * i) * K + k0),
                                       (unsigned int*)(lA + 32 * i * 64), 16, 0, 0);
    #pragma unroll
    for (int i = 0; i < 2; i++)
      __builtin_amdgcn_global_load_lds((const unsigned int*)(gB + (32 * i) * K + k0),
                                       (unsigned int*)(lB + 32 * i * 64), 16, 0, 0);
  };

  stage(0, 0);
  stage(64, 1);
  asm volatile("s_waitcnt vmcnt(6)" ::: "memory");
  __builtin_amdgcn_s_barrier();

  const int so0 = ((quad ^ (l16 & 7)) * 8);
  const int so1 = (((4 + quad) ^ (l16 & 7)) * 8);

  const int nk = K >> 6;   // 16
  int cur = 0;
  for (int kt = 0; kt < nk; kt++) {
    const unsigned short* rA = &sA[cur][0];
    const unsigned short* rB = &sB[cur][0];
    #pragma unroll
    for (int kk = 0; kk < 2; kk++) {
      const int so = kk ? so1 : so0;
      bf16x8 af[2], bfr[4];
      #pragma unroll
      for (int i = 0; i < 2; i++)
        af[i] = *(const bf16x8*)(&rA[(wm + i * 16 + l16) * 64 + so]);
      #pragma unroll
      for (int j = 0; j < 4; j++)
        bfr[j] = *(const bf16x8*)(&rB[(j * 16 + l16) * 64 + so]);
      __builtin_amdgcn_s_setprio(1);
      #pragma unroll
      for (int i = 0; i < 2; i++)
        #pragma unroll
        for (int j = 0; j < 4; j++)
          acc[i][j] = __builtin_amdgcn_mfma_f32_16x16x32_bf16(af[i], bfr[j], acc[i][j], 0, 0, 0);
      __builtin_amdgcn_s_setprio(0);
    }
    if (kt + 2 < nk) {
      const int nb = (cur + 2 >= 3) ? cur - 1 : cur + 2;   // (kt+2)%3
      stage((kt + 2) * 64, nb);
      asm volatile("s_waitcnt vmcnt(6)" ::: "memory");
    } else {
      asm volatile("s_waitcnt vmcnt(0)" ::: "memory");
    }
    __builtin_amdgcn_s_barrier();
    cur = (cur == 2) ? 0 : cur + 1;
  }

  const int rgn = n_blk >> 4;                 // 0=q, 1=k, 2=v
  const int h   = n_blk & 15;

  if (rgn == 2) {
    #pragma unroll
    for (int i = 0; i < 2; i++) {
      int row0 = m0 + wm + i * 16 + quad * 4;      // token of r=0
      int bidx = row0 >> 11, n0r = row0 & 2047;
      #pragma unroll
      for (int j = 0; j < 4; j++) {
        int d = j * 16 + l16;
        float bb = bv[h * 64 + d];
        __hip_bfloat162 p01 = __float22bfloat162_rn(float2{acc[i][j][0] + bb, acc[i][j][1] + bb});
        __hip_bfloat162 p23 = __float22bfloat162_rn(float2{acc[i][j][2] + bb, acc[i][j][3] + bb});
        unsigned int u01, u23;
        __builtin_memcpy(&u01, &p01, 4);
        __builtin_memcpy(&u23, &p23, 4);
        *(uint2*)(vt + (((bidx * 16 + h) * 64) + d) * 2048 + n0r) = make_uint2(u01, u23);
      }
    }
  } else {
    const float* bia = (rgn == 0) ? bq : bk;
    unsigned short* outp = (rgn == 0) ? qo : ko;
    #pragma unroll
    for (int i = 0; i < 2; i++) {
      #pragma unroll
      for (int r = 0; r < 4; r++) {
        int row = m0 + wm + i * 16 + quad * 4 + r;
        int bidx = row >> 11, n = row & 2047;
        #pragma unroll
        for (int j = 0; j < 4; j++) {
          int d = j * 16 + l16;
          int c = h * 64 + d;                      // within-region column
          int oi = ((bidx * 16 + h) * 2048 + n) * 64 + d;
          float val = acc[i][j][r] + bia[c];
          float pv  = acc[i][j ^ 2][r] + bia[c ^ 32];
          float rot = (j < 2) ? -pv : pv;          // rotate_half
          float y = val * rc[n * 64 + d] + rot * rs[n * 64 + d];
          if (rgn == 0) y *= 0.125f;               // fold D^-0.5 into q
          outp[oi] = f2bf(y);
        }
      }
    }
  }
}

// ---------------- Flash attention v7: 8-wave blocks + kv-split + T5 ----------
__global__ __launch_bounds__(512)
void flash_attn(const unsigned short* __restrict__ q,
                const unsigned short* __restrict__ k,
                const unsigned short* __restrict__ vt,
                unsigned short* __restrict__ o0h,
                unsigned short* __restrict__ o1h,
                float* __restrict__ l0g, float* __restrict__ l1g) {
  __shared__ unsigned short sK[2][64 * 64];
  __shared__ unsigned short sVt[2][64 * 64];
  __shared__ unsigned short sPt[2][8][16 * 72];
  const int t = threadIdx.x;
  const int wave = t >> 6, lane = t & 63;
  const int quad = lane >> 4, l16 = lane & 15;
  const int id = blockIdx.x;
  const int bh = (id & 7) * 4 + ((id >> 3) & 3);  // 4 heads per XCD (L2-local)
  const int qb = (id >> 5) & 7;                   // 8 blocks of 256 q-rows
  const int kvh = id >> 8;                        // kv half
  const int base = bh * (N_ * D_);

  bf16x8 qa[2][2];
  #pragma unroll
  for (int qt = 0; qt < 2; qt++) {
    int qrow = qb * 256 + wave * 32 + qt * 16 + l16;
    #pragma unroll
    for (int kk = 0; kk < 2; kk++)
      qa[qt][kk] = *(const bf16x8*)(q + base + qrow * D_ + kk * 32 + quad * 8);
  }
  float l_i[2] = {0.f, 0.f};
  f32x4 o_acc[2][4];
  #pragma unroll
  for (int qt = 0; qt < 2; qt++)
    #pragma unroll
    for (int dt = 0; dt < 4; dt++) o_acc[qt][dt] = (f32x4){0.f, 0.f, 0.f, 0.f};

  const int sc = (((t & 7) ^ ((t >> 3) & 7)) * 8);   // T2 source chunk
  const unsigned short* gK  = k  + base + (t >> 3) * 64 + sc;
  const unsigned short* gVt = vt + bh * (64 * 2048) + (t >> 3) * 2048 + sc;

  auto stage = [&](int kt, int buf) {
    __builtin_amdgcn_global_load_lds((const unsigned int*)(gK + kt * 64 * 64),
                                     (unsigned int*)(&sK[buf][(wave * 8) * 64]), 16, 0, 0);
    __builtin_amdgcn_global_load_lds((const unsigned int*)(gVt + kt * 64),
                                     (unsigned int*)(&sVt[buf][(wave * 8) * 64]), 16, 0, 0);
  };
  const int kt0 = kvh * 16, kt1 = kt0 + 16;
  stage(kt0, 0);
  __syncthreads();

  const int so0 = ((quad ^ (l16 & 7)) * 8);          // kk=0 read slot
  const int so1 = (((4 + quad) ^ (l16 & 7)) * 8);    // kk=1 read slot

  for (int kt = kt0; kt < kt1; kt++) {
    const int cur = kt & 1;
    if (kt + 1 < kt1) stage(kt + 1, cur ^ 1);

    f32x4 s_acc[2][4];
    __builtin_amdgcn_s_setprio(1);
    #pragma unroll
    for (int nt = 0; nt < 4; nt++) {
      bf16x8 kb0 = *(const bf16x8*)(&sK[cur][(nt * 16 + l16) * 64 + so0]);
      bf16x8 kb1 = *(const bf16x8*)(&sK[cur][(nt * 16 + l16) * 64 + so1]);
      #pragma unroll
      for (int qt = 0; qt < 2; qt++) {
        f32x4 a = (f32x4){0.f, 0.f, 0.f, 0.f};
        a = __builtin_amdgcn_mfma_f32_16x16x32_bf16(kb0, qa[qt][0], a, 0, 0, 0);
        a = __builtin_amdgcn_mfma_f32_16x16x32_bf16(kb1, qa[qt][1], a, 0, 0, 0);
        s_acc[qt][nt] = a;
      }
    }
    __builtin_amdgcn_s_setprio(0);
    #pragma unroll
    for (int qt = 0; qt < 2; qt++) {
      float rsum = 0.f;
      #pragma unroll
      for (int nt = 0; nt < 4; nt++)
        #pragma unroll
        for (int r = 0; r < 4; r++) {
          float p = __expf(s_acc[qt][nt][r]);
          s_acc[qt][nt][r] = p;
          rsum += p;
        }
      rsum += __shfl_xor(rsum, 16);
      rsum += __shfl_xor(rsum, 32);
      l_i[qt] += rsum;
      #pragma unroll
      for (int nt = 0; nt < 4; nt++) {
        __hip_bfloat162 p01 = __float22bfloat162_rn(float2{s_acc[qt][nt][0], s_acc[qt][nt][1]});
        __hip_bfloat162 p23 = __float22bfloat162_rn(float2{s_acc[qt][nt][2], s_acc[qt][nt][3]});
        unsigned int u01, u23;
        __builtin_memcpy(&u01, &p01, 4);
        __builtin_memcpy(&u23, &p23, 4);
        *(uint2*)(&sPt[qt][wave][l16 * 72 + nt * 16 + quad * 4]) = make_uint2(u01, u23);
      }
    }
    __asm__ volatile("s_waitcnt lgkmcnt(0)" ::: "memory");
    bf16x8 pt[2][2];
    #pragma unroll
    for (int qt = 0; qt < 2; qt++) {
      pt[qt][0] = *(const bf16x8*)(&sPt[qt][wave][l16 * 72 + quad * 8]);
      pt[qt][1] = *(const bf16x8*)(&sPt[qt][wave][l16 * 72 + 32 + quad * 8]);
    }
    __builtin_amdgcn_s_setprio(1);
    #pragma unroll
    for (int dt = 0; dt < 4; dt++) {
      int d0 = dt * 16 + l16;
      bf16x8 va0 = *(const bf16x8*)(&sVt[cur][d0 * 64 + so0]);
      bf16x8 va1 = *(const bf16x8*)(&sVt[cur][d0 * 64 + so1]);
      #pragma unroll
      for (int qt = 0; qt < 2; qt++) {
        o_acc[qt][dt] = __builtin_amdgcn_mfma_f32_16x16x32_bf16(va0, pt[qt][0], o_acc[qt][dt], 0, 0, 0);
        o_acc[qt][dt] = __builtin_amdgcn_mfma_f32_16x16x32_bf16(va1, pt[qt][1], o_acc[qt][dt], 0, 0, 0);
      }
    }
    __builtin_amdgcn_s_setprio(0);
    __syncthreads();
  }

  unsigned short* op = kvh ? o1h : o0h;
  float* lp = kvh ? l1g : l0g;
  const int b = bh >> 4, h = bh & 15;
  #pragma unroll
  for (int qt = 0; qt < 2; qt++) {
    const int qrow = qb * 256 + wave * 32 + qt * 16 + l16;
    if (quad == 0) lp[bh * 2048 + qrow] = l_i[qt];
    const int tok = b * N_ + qrow;
    #pragma unroll
    for (int dt = 0; dt < 4; dt++) {
      __hip_bfloat162 p01 = __float22bfloat162_rn(float2{o_acc[qt][dt][0], o_acc[qt][dt][1]});
      __hip_bfloat162 p23 = __float22bfloat162_rn(float2{o_acc[qt][dt][2], o_acc[qt][dt][3]});
      unsigned int u01, u23;
      __builtin_memcpy(&u01, &p01, 4);
      __builtin_memcpy(&u23, &p23, 4);
      int col = h * 64 + dt * 16 + quad * 4;
      *(uint2*)(op + tok * C_ + col) = make_uint2(u01, u23);
    }
  }
}

// ---------------- combine the two kv halves: ao = (o0+o1)/(l0+l1) ------------
__global__ __launch_bounds__(256)
void attn_norm(const unsigned short* __restrict__ o0h,
               const unsigned short* __restrict__ o1h,
               const float* __restrict__ l0g, const float* __restrict__ l1g,
               unsigned short* __restrict__ o) {
  const int i = (blockIdx.x * 256 + threadIdx.x) * 8;
  const int row = i >> 10, c = i & 1023;
  const int h = c >> 6;
  const int b = row >> 11, n = row & 2047;
  const int li = (b * 16 + h) * 2048 + n;
  const float inv = 1.0f / (l0g[li] + l1g[li]);
  ushort4 a0 = *(const ushort4*)(o0h + i);
  ushort4 a1 = *(const ushort4*)(o0h + i + 4);
  ushort4 b0 = *(const ushort4*)(o1h + i);
  ushort4 b1 = *(const ushort4*)(o1h + i + 4);
  ushort4 r0, r1;
  r0.x = f2bf((bf2f(a0.x) + bf2f(b0.x)) * inv);
  r0.y = f2bf((bf2f(a0.y) + bf2f(b0.y)) * inv);
  r0.z = f2bf((bf2f(a0.z) + bf2f(b0.z)) * inv);
  r0.w = f2bf((bf2f(a0.w) + bf2f(b0.w)) * inv);
  r1.x = f2bf((bf2f(a1.x) + bf2f(b1.x)) * inv);
  r1.y = f2bf((bf2f(a1.y) + bf2f(b1.y)) * inv);
  r1.z = f2bf((bf2f(a1.z) + bf2f(b1.z)) * inv);
  r1.w = f2bf((bf2f(a1.w) + bf2f(b1.w)) * inv);
  *(ushort4*)(o + i) = r0;
  *(ushort4*)(o + i + 4) = r1;
}

// ---------------- launcher ---------------------------------------------------
extern "C" void kernel_launch(void* const* d_in, const int* in_sizes, int n_in,
                              void* d_out, int out_size, void* d_ws, size_t ws_size,
                              hipStream_t stream) {
  const float* x   = (const float*)d_in[0];
  const float* rc  = (const float*)d_in[1];
  const float* rs  = (const float*)d_in[2];
  const float* g1  = (const float*)d_in[3];
  const float* be1 = (const float*)d_in[4];
  const float* Wq  = (const float*)d_in[5];
  const float* bq  = (const float*)d_in[6];
  const float* Wk  = (const float*)d_in[7];
  const float* bk  = (const float*)d_in[8];
  const float* Wv  = (const float*)d_in[9];
  const float* bv  = (const float*)d_in[10];
  const float* Wo  = (const float*)d_in[11];
  const float* bo  = (const float*)d_in[12];
  const float* g2  = (const float*)d_in[13];
  const float* be2 = (const float*)d_in[14];
  const float* W1  = (const float*)d_in[15];
  const float* b1m = (const float*)d_in[16];
  const float* W2  = (const float*)d_in[17];
  const float* b2m = (const float*)d_in[18];
  float* out = (float*)d_out;

  char* ws = (char*)d_ws;
  unsigned short* wqkv = (unsigned short*)(ws + 0);           // 6 MB
  unsigned short* wo   = (unsigned short*)(ws + 6291456);     // 2 MB
  unsigned short* w1   = (unsigned short*)(ws + 8388608);     // 8 MB
  unsigned short* w2   = (unsigned short*)(ws + 16777216);    // 8 MB
  unsigned short* h1   = (unsigned short*)(ws + 25165824);    // 8 MB (ln out; attn o1 partial; ln2 out)
  unsigned short* qa   = (unsigned short*)(ws + 33554432);    // 8 MB
  unsigned short* ka   = (unsigned short*)(ws + 41943040);    // 8 MB
  unsigned short* va   = (unsigned short*)(ws + 50331648);    // 8 MB (V^T: B*H x D x N)
  unsigned short* ao   = (unsigned short*)(ws + 58720256);    // 8 MB (attn o0 partial -> normalized)
  float*          x1   = (float*)(ws + 67108864);             // 16 MB
  float*          l0   = (float*)(ws + 67108864);             // 256 KB (dead before x1 written)
  float*          l1   = l0 + 65536;                          // 256 KB
  unsigned short* u    = (unsigned short*)(ws + 33554432);    // overlays qa..ao (dead by MLP1)

  // fused weight-cvt + LN1 (one dispatch; all outputs ready before QKV)
  ln1_cvt<<<16384, 256, 0, stream>>>(
      x, g1, be1, h1,
      (const float4*)Wq, (const float4*)Wk, (const float4*)Wv, (const float4*)Wo,
      (const float4*)W1, (const float4*)W2,
      (ushort4*)wqkv, (ushort4*)(wqkv + 1048576), (ushort4*)(wqkv + 2097152),
      (ushort4*)wo, (ushort4*)w1, (ushort4*)w2);

  gemm_qkv_t4<<<1536, 256, 0, stream>>>(h1, wqkv, bq, bk, bv, rc, rs, qa, ka, va);
  flash_attn<<<512, 512, 0, stream>>>(qa, ka, va, ao, h1, l0, l1);
  attn_norm<<<2048, 256, 0, stream>>>(ao, h1, l0, l1, ao);
  gemm_bt<1, 64><<<dim3(16, 32), 256, 0, stream>>>(ao, wo, 1024, 1024, 2, bo, x, nullptr, x1);
  ln_kernel<<<4096, 256, 0, stream>>>(x1, g2, be2, h1);
  gemm_mlp1<<<512, 512, 0, stream>>>(h1, w1, b1m, u);
  gemm_bt<3, 64><<<dim3(16, 32), 256, 0, stream>>>(u, w2, 4096, 1024, 2, b2m, x1, nullptr, out);
}

// Round 15
// 345.694 us; speedup vs baseline: 1.1282x; 1.0064x over previous
//
#include <hip/hip_runtime.h>
#include <hip/hip_bf16.h>

#define B_ 2
#define N_ 2048
#define C_ 1024
#define H_ 16
#define D_ 64
#define F_ 4096
#define M_ 4096  // B_*N_

typedef __attribute__((ext_vector_type(8))) short bf16x8;
typedef __attribute__((ext_vector_type(4))) float f32x4;

__device__ inline unsigned short f2bf(float f) {
  unsigned int u = __float_as_uint(f);
  u = (u + 0x7FFFu + ((u >> 16) & 1u)) >> 16;
  return (unsigned short)u;
}
__device__ inline float bf2f(unsigned short u) {
  unsigned int x = ((unsigned int)u) << 16;
  return __uint_as_float(x);
}

// ---------------- fused: all-weights fp32->bf16  +  LayerNorm1 ---------------
__global__ __launch_bounds__(256)
void ln1_cvt(const float* __restrict__ x, const float* __restrict__ g,
             const float* __restrict__ bln, unsigned short* __restrict__ out,
             const float4* __restrict__ s0, const float4* __restrict__ s1,
             const float4* __restrict__ s2, const float4* __restrict__ s3,
             const float4* __restrict__ s4, const float4* __restrict__ s5,
             ushort4* __restrict__ d0, ushort4* __restrict__ d1,
             ushort4* __restrict__ d2, ushort4* __restrict__ d3,
             ushort4* __restrict__ d4, ushort4* __restrict__ d5) {
  const int b = blockIdx.x;
  if (b < 12288) {
    const float4* s; ushort4* d; int i;
    if      (b < 1024) { s = s0; d = d0; i = b * 256 + threadIdx.x; }
    else if (b < 2048) { s = s1; d = d1; i = (b - 1024) * 256 + threadIdx.x; }
    else if (b < 3072) { s = s2; d = d2; i = (b - 2048) * 256 + threadIdx.x; }
    else if (b < 4096) { s = s3; d = d3; i = (b - 3072) * 256 + threadIdx.x; }
    else if (b < 8192) { s = s4; d = d4; i = (b - 4096) * 256 + threadIdx.x; }
    else               { s = s5; d = d5; i = (b - 8192) * 256 + threadIdx.x; }
    float4 f = s[i];
    ushort4 o;
    o.x = f2bf(f.x); o.y = f2bf(f.y); o.z = f2bf(f.z); o.w = f2bf(f.w);
    d[i] = o;
    return;
  }
  __shared__ float red[8];
  const int row = b - 12288;
  const int t = threadIdx.x;
  const float4 xv = *(const float4*)(x + row * 1024 + t * 4);
  float s  = xv.x + xv.y + xv.z + xv.w;
  float sq = xv.x * xv.x + xv.y * xv.y + xv.z * xv.z + xv.w * xv.w;
  #pragma unroll
  for (int off = 32; off >= 1; off >>= 1) {
    s  += __shfl_down(s, off);
    sq += __shfl_down(sq, off);
  }
  const int lane = t & 63, wave = t >> 6;
  if (lane == 0) { red[wave * 2] = s; red[wave * 2 + 1] = sq; }
  __syncthreads();
  float ts = red[0] + red[2] + red[4] + red[6];
  float tq = red[1] + red[3] + red[5] + red[7];
  float mean = ts * (1.0f / 1024.0f);
  float var  = tq * (1.0f / 1024.0f) - mean * mean;
  float rstd = rsqrtf(var + 1e-6f);
  float xs[4] = {xv.x, xv.y, xv.z, xv.w};
  #pragma unroll
  for (int i = 0; i < 4; i++) {
    int c = t * 4 + i;
    float y = (xs[i] - mean) * rstd * g[c] + bln[c];
    out[row * 1024 + c] = f2bf(y);
  }
}

// ---------------- LayerNorm: fp32 in -> bf16 out (ln2) ------------------------
__global__ __launch_bounds__(256)
void ln_kernel(const float* __restrict__ x, const float* __restrict__ g,
               const float* __restrict__ b, unsigned short* __restrict__ out) {
  __shared__ float red[8];
  const int row = blockIdx.x;
  const int t = threadIdx.x;
  const float4 xv = *(const float4*)(x + row * 1024 + t * 4);
  float s  = xv.x + xv.y + xv.z + xv.w;
  float sq = xv.x * xv.x + xv.y * xv.y + xv.z * xv.z + xv.w * xv.w;
  #pragma unroll
  for (int off = 32; off >= 1; off >>= 1) {
    s  += __shfl_down(s, off);
    sq += __shfl_down(sq, off);
  }
  const int lane = t & 63, wave = t >> 6;
  if (lane == 0) { red[wave * 2] = s; red[wave * 2 + 1] = sq; }
  __syncthreads();
  float ts = red[0] + red[2] + red[4] + red[6];
  float tq = red[1] + red[3] + red[5] + red[7];
  float mean = ts * (1.0f / 1024.0f);
  float var  = tq * (1.0f / 1024.0f) - mean * mean;
  float rstd = rsqrtf(var + 1e-6f);
  float xs[4] = {xv.x, xv.y, xv.z, xv.w};
  #pragma unroll
  for (int i = 0; i < 4; i++) {
    int c = t * 4 + i;
    float y = (xs[i] - mean) * rstd * g[c] + b[c];
    out[row * 1024 + c] = f2bf(y);
  }
}

// ---------------- GEMM (128x64 tile, 3-buffer counted-vmcnt, T2, m-local) ----
// MODE 1: +bias +resid -> fp32 [O-proj]  (K=1024, grid 512, 2 blocks/CU)
template<int MODE, int BN>
__global__ __launch_bounds__(256)
void gemm_bt(const unsigned short* __restrict__ A,
             const unsigned short* __restrict__ Bw,
             int K, int Nout, int npc,
             const float* __restrict__ bias,
             const float* __restrict__ resid,
             unsigned short* __restrict__ out_bf,
             float* __restrict__ out_f32) {
  constexpr int NJ = BN / 32;
  static_assert(BN == 64, "vmcnt literal assumes 6 loads per stage");
  __shared__ unsigned short sA[3][128 * 64];
  __shared__ unsigned short sB[3][BN * 64];
  const int t = threadIdx.x;
  const int wave = t >> 6, lane = t & 63;
  const int quad = lane >> 4, l16 = lane & 15;
  const int wm = (wave & 1) * 64, wn = (wave >> 1) * (BN / 2);
  const int id = blockIdx.y * gridDim.x + blockIdx.x;
  const int xcd = id & 7, r_ = id >> 3;
  const int m_blk = xcd * 4 + (r_ & 3);
  const int n_blk = r_ >> 2;
  const int m0 = m_blk * 128, n0 = n_blk * BN;

  f32x4 acc[4][NJ];
  #pragma unroll
  for (int i = 0; i < 4; i++)
    #pragma unroll
    for (int j = 0; j < NJ; j++) acc[i][j] = (f32x4){0.f, 0.f, 0.f, 0.f};

  const int sc = (((t & 7) ^ ((t >> 3) & 7)) * 8);   // swizzled source chunk
  const unsigned short* gA = A  + (m0 + (t >> 3)) * K + sc;
  const unsigned short* gB = Bw + (n0 + (t >> 3)) * K + sc;

  auto stage = [&](int k0, int buf) {
    unsigned short* lA = &sA[buf][(wave * 8) * 64];
    unsigned short* lB = &sB[buf][(wave * 8) * 64];
    #pragma unroll
    for (int i = 0; i < 4; i++)
      __builtin_amdgcn_global_load_lds((const unsigned int*)(gA + (32 * i) * K + k0),
                                       (unsigned int*)(lA + 32 * i * 64), 16, 0, 0);
    #pragma unroll
    for (int i = 0; i < BN / 32; i++)
      __builtin_amdgcn_global_load_lds((const unsigned int*)(gB + (32 * i) * K + k0),
                                       (unsigned int*)(lB + 32 * i * 64), 16, 0, 0);
  };

  stage(0, 0);
  stage(64, 1);
  asm volatile("s_waitcnt vmcnt(6)" ::: "memory");
  __builtin_amdgcn_s_barrier();

  const int so0 = ((quad ^ (l16 & 7)) * 8);          // kk=0 read slot
  const int so1 = (((4 + quad) ^ (l16 & 7)) * 8);    // kk=1 read slot

  const int nk = K >> 6;
  int cur = 0;
  for (int kt = 0; kt < nk; kt++) {
    const unsigned short* rA = &sA[cur][0];
    const unsigned short* rB = &sB[cur][0];
    #pragma unroll
    for (int kk = 0; kk < 2; kk++) {
      const int so = kk ? so1 : so0;
      bf16x8 af[4], bfr[NJ];
      #pragma unroll
      for (int i = 0; i < 4; i++)
        af[i] = *(const bf16x8*)(&rA[(wm + i * 16 + l16) * 64 + so]);
      #pragma unroll
      for (int j = 0; j < NJ; j++)
        bfr[j] = *(const bf16x8*)(&rB[(wn + j * 16 + l16) * 64 + so]);
      __builtin_amdgcn_s_setprio(1);
      #pragma unroll
      for (int i = 0; i < 4; i++)
        #pragma unroll
        for (int j = 0; j < NJ; j++)
          acc[i][j] = __builtin_amdgcn_mfma_f32_16x16x32_bf16(af[i], bfr[j], acc[i][j], 0, 0, 0);
      __builtin_amdgcn_s_setprio(0);
    }
    if (kt + 2 < nk) {
      const int nb = (cur + 2 >= 3) ? cur - 1 : cur + 2;   // (kt+2)%3
      stage((kt + 2) * 64, nb);
      asm volatile("s_waitcnt vmcnt(6)" ::: "memory");
    } else {
      asm volatile("s_waitcnt vmcnt(0)" ::: "memory");
    }
    __builtin_amdgcn_s_barrier();
    cur = (cur == 2) ? 0 : cur + 1;
  }

  #pragma unroll
  for (int i = 0; i < 4; i++) {
    #pragma unroll
    for (int j = 0; j < NJ; j++) {
      int col = n0 + wn + j * 16 + l16;
      #pragma unroll
      for (int r = 0; r < 4; r++) {
        int row = m0 + wm + i * 16 + quad * 4 + r;
        float v = acc[i][j][r];
        if (MODE == 1 || MODE == 3) {
          out_f32[row * Nout + col] = v + bias[col] + resid[row * Nout + col];
        } else {
          v += bias[col];
          float w = v * (1.0f + 0.044715f * v * v);
          float gl = v / (1.0f + __expf(-1.5957691216f * w));
          out_bf[row * Nout + col] = f2bf(gl);
        }
      }
    }
  }
}

// ---------------- MLP2: 128x128 tile, 512 thr, 3-buffer counted-vmcnt --------
// MLP2 was L2-staging-BW bound at (128,64): 805 MB staged = ~54 B/cyc/CU (at
// the ~56 B/cyc L2 share). (128,128) cuts staged-bytes/output by 33% and
// keeps grid = 32m x 8n = 256 blocks = 1/CU. Round-13/14-verified T4
// skeleton: 3 LDS bufs (96 KB), prefetch distance 2, late issue, counted
// vmcnt + raw barriers, T5, T2 swizzle, m-local XCD map. Stage = 4 gloads/
// thread (2 A-chunks + 2 B-chunks of 64 rows) -> boundary vmcnt(4):
// outstanding = 4(t+1)+4(t+2)=8 -> retires exactly t+1, leaves t+2 in
// flight; tail vmcnt(0). 8 waves 2m x 4n, wave owns 64x32 (af[4] x bfr[2]).
__global__ __launch_bounds__(512, 1)
void gemm_mlp2(const unsigned short* __restrict__ A,
               const unsigned short* __restrict__ Bw,
               const float* __restrict__ bias,
               const float* __restrict__ resid,
               float* __restrict__ out_f32) {
  const int K = 4096;
  __shared__ unsigned short sA[3][128 * 64];
  __shared__ unsigned short sB[3][128 * 64];
  const int t = threadIdx.x;
  const int wave = t >> 6, lane = t & 63;
  const int quad = lane >> 4, l16 = lane & 15;
  const int wm = (wave & 1) * 64, wn = (wave >> 1) * 32;   // 2m x 4n
  const int id = blockIdx.x;
  const int xcd = id & 7, r_ = id >> 3;        // r_ in [0,32)
  const int m_blk = xcd * 4 + (r_ & 3);        // [0,32)  A-local
  const int n_blk = r_ >> 2;                   // [0,8)
  const int m0 = m_blk * 128, n0 = n_blk * 128;

  f32x4 acc[4][2];
  #pragma unroll
  for (int i = 0; i < 4; i++)
    #pragma unroll
    for (int j = 0; j < 2; j++) acc[i][j] = (f32x4){0.f, 0.f, 0.f, 0.f};

  const int sc = (((t & 7) ^ ((t >> 3) & 7)) * 8);   // swizzled source chunk
  const unsigned short* gA = A  + (m0 + (t >> 3)) * K + sc;   // t>>3 in [0,64)
  const unsigned short* gB = Bw + (n0 + (t >> 3)) * K + sc;

  auto stage = [&](int k0, int buf) {
    // 512 threads cover 64 rows per gload; wave w owns rows [8w,8w+8)
    #pragma unroll
    for (int i = 0; i < 2; i++)
      __builtin_amdgcn_global_load_lds((const unsigned int*)(gA + (64 * i) * K + k0),
                                       (unsigned int*)(&sA[buf][(64 * i + wave * 8) * 64]), 16, 0, 0);
    #pragma unroll
    for (int i = 0; i < 2; i++)
      __builtin_amdgcn_global_load_lds((const unsigned int*)(gB + (64 * i) * K + k0),
                                       (unsigned int*)(&sB[buf][(64 * i + wave * 8) * 64]), 16, 0, 0);
  };

  // prologue: tiles 0,1 -> bufs 0,1 (8 loads/thread); retire tile 0 only.
  stage(0, 0);
  stage(64, 1);
  asm volatile("s_waitcnt vmcnt(4)" ::: "memory");
  __builtin_amdgcn_s_barrier();

  const int so0 = ((quad ^ (l16 & 7)) * 8);          // kk=0 read slot
  const int so1 = (((4 + quad) ^ (l16 & 7)) * 8);    // kk=1 read slot

  const int nk = K >> 6;   // 64
  int cur = 0;
  for (int kt = 0; kt < nk; kt++) {
    const unsigned short* rA = &sA[cur][0];
    const unsigned short* rB = &sB[cur][0];
    #pragma unroll
    for (int kk = 0; kk < 2; kk++) {
      const int so = kk ? so1 : so0;
      bf16x8 af[4], bfr[2];
      #pragma unroll
      for (int i = 0; i < 4; i++)
        af[i] = *(const bf16x8*)(&rA[(wm + i * 16 + l16) * 64 + so]);
      #pragma unroll
      for (int j = 0; j < 2; j++)
        bfr[j] = *(const bf16x8*)(&rB[(wn + j * 16 + l16) * 64 + so]);
      __builtin_amdgcn_s_setprio(1);
      #pragma unroll
      for (int i = 0; i < 4; i++)
        #pragma unroll
        for (int j = 0; j < 2; j++)
          acc[i][j] = __builtin_amdgcn_mfma_f32_16x16x32_bf16(af[i], bfr[j], acc[i][j], 0, 0, 0);
      __builtin_amdgcn_s_setprio(0);
    }
    if (kt + 2 < nk) {
      const int nb = (cur + 2 >= 3) ? cur - 1 : cur + 2;   // (kt+2)%3
      stage((kt + 2) * 64, nb);
      asm volatile("s_waitcnt vmcnt(4)" ::: "memory");
    } else {
      asm volatile("s_waitcnt vmcnt(0)" ::: "memory");
    }
    __builtin_amdgcn_s_barrier();
    cur = (cur == 2) ? 0 : cur + 1;
  }

  #pragma unroll
  for (int i = 0; i < 4; i++) {
    #pragma unroll
    for (int j = 0; j < 2; j++) {
      int col = n0 + wn + j * 16 + l16;
      #pragma unroll
      for (int r = 0; r < 4; r++) {
        int row = m0 + wm + i * 16 + quad * 4 + r;
        out_f32[row * 1024 + col] = acc[i][j][r] + bias[col] + resid[row * 1024 + col];
      }
    }
  }
}

// ---------------- MLP1: 256x128 tile, 512 thr, 3-buffer counted-vmcnt --------
// (round-14 verified)
__global__ __launch_bounds__(512, 1)
void gemm_mlp1(const unsigned short* __restrict__ A,
               const unsigned short* __restrict__ Bw,
               const float* __restrict__ bias,
               unsigned short* __restrict__ out_bf) {
  const int K = 1024;
  __shared__ unsigned short sA[3][256 * 64];
  __shared__ unsigned short sB[3][128 * 64];
  const int t = threadIdx.x;
  const int wave = t >> 6, lane = t & 63;
  const int quad = lane >> 4, l16 = lane & 15;
  const int wm = (wave >> 1) * 64, wn = (wave & 1) * 64;   // 4m x 2n
  const int id = blockIdx.x;
  const int xcd = id & 7, r_ = id >> 3;        // r_ in [0,64)
  const int m_blk = xcd * 2 + (r_ & 1);        // [0,16)  A-local
  const int n_blk = r_ >> 1;                   // [0,32)
  const int m0 = m_blk * 256, n0 = n_blk * 128;

  f32x4 acc[4][4];
  #pragma unroll
  for (int i = 0; i < 4; i++)
    #pragma unroll
    for (int j = 0; j < 4; j++) acc[i][j] = (f32x4){0.f, 0.f, 0.f, 0.f};

  const int sc = (((t & 7) ^ ((t >> 3) & 7)) * 8);   // swizzled source chunk
  const unsigned short* gA = A  + (m0 + (t >> 3)) * K + sc;   // t>>3 in [0,64)
  const unsigned short* gB = Bw + (n0 + (t >> 3)) * K + sc;

  auto stage = [&](int k0, int buf) {
    #pragma unroll
    for (int i = 0; i < 4; i++)
      __builtin_amdgcn_global_load_lds((const unsigned int*)(gA + (64 * i) * K + k0),
                                       (unsigned int*)(&sA[buf][(64 * i + wave * 8) * 64]), 16, 0, 0);
    #pragma unroll
    for (int i = 0; i < 2; i++)
      __builtin_amdgcn_global_load_lds((const unsigned int*)(gB + (64 * i) * K + k0),
                                       (unsigned int*)(&sB[buf][(64 * i + wave * 8) * 64]), 16, 0, 0);
  };

  stage(0, 0);
  stage(64, 1);
  asm volatile("s_waitcnt vmcnt(6)" ::: "memory");
  __builtin_amdgcn_s_barrier();

  const int so0 = ((quad ^ (l16 & 7)) * 8);          // kk=0 read slot
  const int so1 = (((4 + quad) ^ (l16 & 7)) * 8);    // kk=1 read slot

  const int nk = K >> 6;   // 16
  int cur = 0;
  for (int kt = 0; kt < nk; kt++) {
    const unsigned short* rA = &sA[cur][0];
    const unsigned short* rB = &sB[cur][0];
    #pragma unroll
    for (int kk = 0; kk < 2; kk++) {
      const int so = kk ? so1 : so0;
      bf16x8 af[4], bfr[4];
      #pragma unroll
      for (int i = 0; i < 4; i++)
        af[i] = *(const bf16x8*)(&rA[(wm + i * 16 + l16) * 64 + so]);
      #pragma unroll
      for (int j = 0; j < 4; j++)
        bfr[j] = *(const bf16x8*)(&rB[(wn + j * 16 + l16) * 64 + so]);
      __builtin_amdgcn_s_setprio(1);
      #pragma unroll
      for (int i = 0; i < 4; i++)
        #pragma unroll
        for (int j = 0; j < 4; j++)
          acc[i][j] = __builtin_amdgcn_mfma_f32_16x16x32_bf16(af[i], bfr[j], acc[i][j], 0, 0, 0);
      __builtin_amdgcn_s_setprio(0);
    }
    if (kt + 2 < nk) {
      const int nb = (cur + 2 >= 3) ? cur - 1 : cur + 2;   // (kt+2)%3
      stage((kt + 2) * 64, nb);
      asm volatile("s_waitcnt vmcnt(6)" ::: "memory");
    } else {
      asm volatile("s_waitcnt vmcnt(0)" ::: "memory");
    }
    __builtin_amdgcn_s_barrier();
    cur = (cur == 2) ? 0 : cur + 1;
  }

  #pragma unroll
  for (int i = 0; i < 4; i++) {
    #pragma unroll
    for (int j = 0; j < 4; j++) {
      int col = n0 + wn + j * 16 + l16;
      float bb = bias[col];
      #pragma unroll
      for (int r = 0; r < 4; r++) {
        int row = m0 + wm + i * 16 + quad * 4 + r;
        float v = acc[i][j][r] + bb;
        float w = v * (1.0f + 0.044715f * v * v);
        float gl = v / (1.0f + __expf(-1.5957691216f * w));
        out_bf[row * 4096 + col] = f2bf(gl);
      }
    }
  }
}

// ---------------- QKV GEMM on the T4 skeleton, RoPE epilogue -----------------
// (round-12/13/14 verified)
__global__ __launch_bounds__(256)
void gemm_qkv_t4(const unsigned short* __restrict__ A,
                 const unsigned short* __restrict__ Bw,
                 const float* __restrict__ bq, const float* __restrict__ bk,
                 const float* __restrict__ bv,
                 const float* __restrict__ rc, const float* __restrict__ rs,
                 unsigned short* __restrict__ qo, unsigned short* __restrict__ ko,
                 unsigned short* __restrict__ vt) {
  const int K = C_;
  __shared__ unsigned short sA[3][128 * 64];
  __shared__ unsigned short sB[3][64 * 64];
  const int t = threadIdx.x;
  const int wave = t >> 6, lane = t & 63;
  const int quad = lane >> 4, l16 = lane & 15;
  const int wm = wave * 32;                        // 4m x 1n wave grid
  const int id = blockIdx.x;                       // [0,1536)
  const int xcd = id & 7, r_ = id >> 3;            // r_ in [0,192)
  const int m_blk = xcd * 4 + (r_ & 3);            // [0,32)  A-local
  const int n_blk = r_ >> 2;                       // [0,48)
  const int m0 = m_blk * 128, n0 = n_blk * 64;

  f32x4 acc[2][4];
  #pragma unroll
  for (int i = 0; i < 2; i++)
    #pragma unroll
    for (int j = 0; j < 4; j++) acc[i][j] = (f32x4){0.f, 0.f, 0.f, 0.f};

  const int sc = (((t & 7) ^ ((t >> 3) & 7)) * 8);
  const unsigned short* gA = A  + (m0 + (t >> 3)) * K + sc;
  const unsigned short* gB = Bw + (n0 + (t >> 3)) * K + sc;

  auto stage = [&](int k0, int buf) {
    unsigned short* lA = &sA[buf][(wave * 8) * 64];
    unsigned short* lB = &sB[buf][(wave * 8) * 64];
    #pragma unroll
    for (int i = 0; i < 4; i++)
      __builtin_amdgcn_global_load_lds((const unsigned int*)(gA + (32 * i) * K + k0),
                                       (unsigned int*)(lA + 32 * i * 64), 16, 0, 0);
    #pragma unroll
    for (int i = 0; i < 2; i++)
      __builtin_amdgcn_global_load_lds((const unsigned int*)(gB + (32 * i) * K + k0),
                                       (unsigned int*)(lB + 32 * i * 64), 16, 0, 0);
  };

  stage(0, 0);
  stage(64, 1);
  asm volatile("s_waitcnt vmcnt(6)" ::: "memory");
  __builtin_amdgcn_s_barrier();

  const int so0 = ((quad ^ (l16 & 7)) * 8);
  const int so1 = (((4 + quad) ^ (l16 & 7)) * 8);

  const int nk = K >> 6;   // 16
  int cur = 0;
  for (int kt = 0; kt < nk; kt++) {
    const unsigned short* rA = &sA[cur][0];
    const unsigned short* rB = &sB[cur][0];
    #pragma unroll
    for (int kk = 0; kk < 2; kk++) {
      const int so = kk ? so1 : so0;
      bf16x8 af[2], bfr[4];
      #pragma unroll
      for (int i = 0; i < 2; i++)
        af[i] = *(const bf16x8*)(&rA[(wm + i * 16 + l16) * 64 + so]);
      #pragma unroll
      for (int j = 0; j < 4; j++)
        bfr[j] = *(const bf16x8*)(&rB[(j * 16 + l16) * 64 + so]);
      __builtin_amdgcn_s_setprio(1);
      #pragma unroll
      for (int i = 0; i < 2; i++)
        #pragma unroll
        for (int j = 0; j < 4; j++)
          acc[i][j] = __builtin_amdgcn_mfma_f32_16x16x32_bf16(af[i], bfr[j], acc[i][j], 0, 0, 0);
      __builtin_amdgcn_s_setprio(0);
    }
    if (kt + 2 < nk) {
      const int nb = (cur + 2 >= 3) ? cur - 1 : cur + 2;   // (kt+2)%3
      stage((kt + 2) * 64, nb);
      asm volatile("s_waitcnt vmcnt(6)" ::: "memory");
    } else {
      asm volatile("s_waitcnt vmcnt(0)" ::: "memory");
    }
    __builtin_amdgcn_s_barrier();
    cur = (cur == 2) ? 0 : cur + 1;
  }

  const int rgn = n_blk >> 4;                 // 0=q, 1=k, 2=v
  const int h   = n_blk & 15;

  if (rgn == 2) {
    #pragma unroll
    for (int i = 0; i < 2; i++) {
      int row0 = m0 + wm + i * 16 + quad * 4;      // token of r=0
      int bidx = row0 >> 11, n0r = row0 & 2047;
      #pragma unroll
      for (int j = 0; j < 4; j++) {
        int d = j * 16 + l16;
        float bb = bv[h * 64 + d];
        __hip_bfloat162 p01 = __float22bfloat162_rn(float2{acc[i][j][0] + bb, acc[i][j][1] + bb});
        __hip_bfloat162 p23 = __float22bfloat162_rn(float2{acc[i][j][2] + bb, acc[i][j][3] + bb});
        unsigned int u01, u23;
        __builtin_memcpy(&u01, &p01, 4);
        __builtin_memcpy(&u23, &p23, 4);
        *(uint2*)(vt + (((bidx * 16 + h) * 64) + d) * 2048 + n0r) = make_uint2(u01, u23);
      }
    }
  } else {
    const float* bia = (rgn == 0) ? bq : bk;
    unsigned short* outp = (rgn == 0) ? qo : ko;
    #pragma unroll
    for (int i = 0; i < 2; i++) {
      #pragma unroll
      for (int r = 0; r < 4; r++) {
        int row = m0 + wm + i * 16 + quad * 4 + r;
        int bidx = row >> 11, n = row & 2047;
        #pragma unroll
        for (int j = 0; j < 4; j++) {
          int d = j * 16 + l16;
          int c = h * 64 + d;                      // within-region column
          int oi = ((bidx * 16 + h) * 2048 + n) * 64 + d;
          float val = acc[i][j][r] + bia[c];
          float pv  = acc[i][j ^ 2][r] + bia[c ^ 32];
          float rot = (j < 2) ? -pv : pv;          // rotate_half
          float y = val * rc[n * 64 + d] + rot * rs[n * 64 + d];
          if (rgn == 0) y *= 0.125f;               // fold D^-0.5 into q
          outp[oi] = f2bf(y);
        }
      }
    }
  }
}

// ---------------- Flash attention v7: 8-wave blocks + kv-split + T5 ----------
__global__ __launch_bounds__(512)
void flash_attn(const unsigned short* __restrict__ q,
                const unsigned short* __restrict__ k,
                const unsigned short* __restrict__ vt,
                unsigned short* __restrict__ o0h,
                unsigned short* __restrict__ o1h,
                float* __restrict__ l0g, float* __restrict__ l1g) {
  __shared__ unsigned short sK[2][64 * 64];
  __shared__ unsigned short sVt[2][64 * 64];
  __shared__ unsigned short sPt[2][8][16 * 72];
  const int t = threadIdx.x;
  const int wave = t >> 6, lane = t & 63;
  const int quad = lane >> 4, l16 = lane & 15;
  const int id = blockIdx.x;
  const int bh = (id & 7) * 4 + ((id >> 3) & 3);  // 4 heads per XCD (L2-local)
  const int qb = (id >> 5) & 7;                   // 8 blocks of 256 q-rows
  const int kvh = id >> 8;                        // kv half
  const int base = bh * (N_ * D_);

  bf16x8 qa[2][2];
  #pragma unroll
  for (int qt = 0; qt < 2; qt++) {
    int qrow = qb * 256 + wave * 32 + qt * 16 + l16;
    #pragma unroll
    for (int kk = 0; kk < 2; kk++)
      qa[qt][kk] = *(const bf16x8*)(q + base + qrow * D_ + kk * 32 + quad * 8);
  }
  float l_i[2] = {0.f, 0.f};
  f32x4 o_acc[2][4];
  #pragma unroll
  for (int qt = 0; qt < 2; qt++)
    #pragma unroll
    for (int dt = 0; dt < 4; dt++) o_acc[qt][dt] = (f32x4){0.f, 0.f, 0.f, 0.f};

  const int sc = (((t & 7) ^ ((t >> 3) & 7)) * 8);   // T2 source chunk
  const unsigned short* gK  = k  + base + (t >> 3) * 64 + sc;
  const unsigned short* gVt = vt + bh * (64 * 2048) + (t >> 3) * 2048 + sc;

  auto stage = [&](int kt, int buf) {
    __builtin_amdgcn_global_load_lds((const unsigned int*)(gK + kt * 64 * 64),
                                     (unsigned int*)(&sK[buf][(wave * 8) * 64]), 16, 0, 0);
    __builtin_amdgcn_global_load_lds((const unsigned int*)(gVt + kt * 64),
                                     (unsigned int*)(&sVt[buf][(wave * 8) * 64]), 16, 0, 0);
  };
  const int kt0 = kvh * 16, kt1 = kt0 + 16;
  stage(kt0, 0);
  __syncthreads();

  const int so0 = ((quad ^ (l16 & 7)) * 8);          // kk=0 read slot
  const int so1 = (((4 + quad) ^ (l16 & 7)) * 8);    // kk=1 read slot

  for (int kt = kt0; kt < kt1; kt++) {
    const int cur = kt & 1;
    if (kt + 1 < kt1) stage(kt + 1, cur ^ 1);

    f32x4 s_acc[2][4];
    __builtin_amdgcn_s_setprio(1);
    #pragma unroll
    for (int nt = 0; nt < 4; nt++) {
      bf16x8 kb0 = *(const bf16x8*)(&sK[cur][(nt * 16 + l16) * 64 + so0]);
      bf16x8 kb1 = *(const bf16x8*)(&sK[cur][(nt * 16 + l16) * 64 + so1]);
      #pragma unroll
      for (int qt = 0; qt < 2; qt++) {
        f32x4 a = (f32x4){0.f, 0.f, 0.f, 0.f};
        a = __builtin_amdgcn_mfma_f32_16x16x32_bf16(kb0, qa[qt][0], a, 0, 0, 0);
        a = __builtin_amdgcn_mfma_f32_16x16x32_bf16(kb1, qa[qt][1], a, 0, 0, 0);
        s_acc[qt][nt] = a;
      }
    }
    __builtin_amdgcn_s_setprio(0);
    #pragma unroll
    for (int qt = 0; qt < 2; qt++) {
      float rsum = 0.f;
      #pragma unroll
      for (int nt = 0; nt < 4; nt++)
        #pragma unroll
        for (int r = 0; r < 4; r++) {
          float p = __expf(s_acc[qt][nt][r]);
          s_acc[qt][nt][r] = p;
          rsum += p;
        }
      rsum += __shfl_xor(rsum, 16);
      rsum += __shfl_xor(rsum, 32);
      l_i[qt] += rsum;
      #pragma unroll
      for (int nt = 0; nt < 4; nt++) {
        __hip_bfloat162 p01 = __float22bfloat162_rn(float2{s_acc[qt][nt][0], s_acc[qt][nt][1]});
        __hip_bfloat162 p23 = __float22bfloat162_rn(float2{s_acc[qt][nt][2], s_acc[qt][nt][3]});
        unsigned int u01, u23;
        __builtin_memcpy(&u01, &p01, 4);
        __builtin_memcpy(&u23, &p23, 4);
        *(uint2*)(&sPt[qt][wave][l16 * 72 + nt * 16 + quad * 4]) = make_uint2(u01, u23);
      }
    }
    __asm__ volatile("s_waitcnt lgkmcnt(0)" ::: "memory");
    bf16x8 pt[2][2];
    #pragma unroll
    for (int qt = 0; qt < 2; qt++) {
      pt[qt][0] = *(const bf16x8*)(&sPt[qt][wave][l16 * 72 + quad * 8]);
      pt[qt][1] = *(const bf16x8*)(&sPt[qt][wave][l16 * 72 + 32 + quad * 8]);
    }
    __builtin_amdgcn_s_setprio(1);
    #pragma unroll
    for (int dt = 0; dt < 4; dt++) {
      int d0 = dt * 16 + l16;
      bf16x8 va0 = *(const bf16x8*)(&sVt[cur][d0 * 64 + so0]);
      bf16x8 va1 = *(const bf16x8*)(&sVt[cur][d0 * 64 + so1]);
      #pragma unroll
      for (int qt = 0; qt < 2; qt++) {
        o_acc[qt][dt] = __builtin_amdgcn_mfma_f32_16x16x32_bf16(va0, pt[qt][0], o_acc[qt][dt], 0, 0, 0);
        o_acc[qt][dt] = __builtin_amdgcn_mfma_f32_16x16x32_bf16(va1, pt[qt][1], o_acc[qt][dt], 0, 0, 0);
      }
    }
    __builtin_amdgcn_s_setprio(0);
    __syncthreads();
  }

  unsigned short* op = kvh ? o1h : o0h;
  float* lp = kvh ? l1g : l0g;
  const int b = bh >> 4, h = bh & 15;
  #pragma unroll
  for (int qt = 0; qt < 2; qt++) {
    const int qrow = qb * 256 + wave * 32 + qt * 16 + l16;
    if (quad == 0) lp[bh * 2048 + qrow] = l_i[qt];
    const int tok = b * N_ + qrow;
    #pragma unroll
    for (int dt = 0; dt < 4; dt++) {
      __hip_bfloat162 p01 = __float22bfloat162_rn(float2{o_acc[qt][dt][0], o_acc[qt][dt][1]});
      __hip_bfloat162 p23 = __float22bfloat162_rn(float2{o_acc[qt][dt][2], o_acc[qt][dt][3]});
      unsigned int u01, u23;
      __builtin_memcpy(&u01, &p01, 4);
      __builtin_memcpy(&u23, &p23, 4);
      int col = h * 64 + dt * 16 + quad * 4;
      *(uint2*)(op + tok * C_ + col) = make_uint2(u01, u23);
    }
  }
}

// ---------------- combine the two kv halves: ao = (o0+o1)/(l0+l1) ------------
__global__ __launch_bounds__(256)
void attn_norm(const unsigned short* __restrict__ o0h,
               const unsigned short* __restrict__ o1h,
               const float* __restrict__ l0g, const float* __restrict__ l1g,
               unsigned short* __restrict__ o) {
  const int i = (blockIdx.x * 256 + threadIdx.x) * 8;
  const int row = i >> 10, c = i & 1023;
  const int h = c >> 6;
  const int b = row >> 11, n = row & 2047;
  const int li = (b * 16 + h) * 2048 + n;
  const float inv = 1.0f / (l0g[li] + l1g[li]);
  ushort4 a0 = *(const ushort4*)(o0h + i);
  ushort4 a1 = *(const ushort4*)(o0h + i + 4);
  ushort4 b0 = *(const ushort4*)(o1h + i);
  ushort4 b1 = *(const ushort4*)(o1h + i + 4);
  ushort4 r0, r1;
  r0.x = f2bf((bf2f(a0.x) + bf2f(b0.x)) * inv);
  r0.y = f2bf((bf2f(a0.y) + bf2f(b0.y)) * inv);
  r0.z = f2bf((bf2f(a0.z) + bf2f(b0.z)) * inv);
  r0.w = f2bf((bf2f(a0.w) + bf2f(b0.w)) * inv);
  r1.x = f2bf((bf2f(a1.x) + bf2f(b1.x)) * inv);
  r1.y = f2bf((bf2f(a1.y) + bf2f(b1.y)) * inv);
  r1.z = f2bf((bf2f(a1.z) + bf2f(b1.z)) * inv);
  r1.w = f2bf((bf2f(a1.w) + bf2f(b1.w)) * inv);
  *(ushort4*)(o + i) = r0;
  *(ushort4*)(o + i + 4) = r1;
}

// ---------------- launcher ---------------------------------------------------
extern "C" void kernel_launch(void* const* d_in, const int* in_sizes, int n_in,
                              void* d_out, int out_size, void* d_ws, size_t ws_size,
                              hipStream_t stream) {
  const float* x   = (const float*)d_in[0];
  const float* rc  = (const float*)d_in[1];
  const float* rs  = (const float*)d_in[2];
  const float* g1  = (const float*)d_in[3];
  const float* be1 = (const float*)d_in[4];
  const float* Wq  = (const float*)d_in[5];
  const float* bq  = (const float*)d_in[6];
  const float* Wk  = (const float*)d_in[7];
  const float* bk  = (const float*)d_in[8];
  const float* Wv  = (const float*)d_in[9];
  const float* bv  = (const float*)d_in[10];
  const float* Wo  = (const float*)d_in[11];
  const float* bo  = (const float*)d_in[12];
  const float* g2  = (const float*)d_in[13];
  const float* be2 = (const float*)d_in[14];
  const float* W1  = (const float*)d_in[15];
  const float* b1m = (const float*)d_in[16];
  const float* W2  = (const float*)d_in[17];
  const float* b2m = (const float*)d_in[18];
  float* out = (float*)d_out;

  char* ws = (char*)d_ws;
  unsigned short* wqkv = (unsigned short*)(ws + 0);           // 6 MB
  unsigned short* wo   = (unsigned short*)(ws + 6291456);     // 2 MB
  unsigned short* w1   = (unsigned short*)(ws + 8388608);     // 8 MB
  unsigned short* w2   = (unsigned short*)(ws + 16777216);    // 8 MB
  unsigned short* h1   = (unsigned short*)(ws + 25165824);    // 8 MB (ln out; attn o1 partial; ln2 out)
  unsigned short* qa   = (unsigned short*)(ws + 33554432);    // 8 MB
  unsigned short* ka   = (unsigned short*)(ws + 41943040);    // 8 MB
  unsigned short* va   = (unsigned short*)(ws + 50331648);    // 8 MB (V^T: B*H x D x N)
  unsigned short* ao   = (unsigned short*)(ws + 58720256);    // 8 MB (attn o0 partial -> normalized)
  float*          x1   = (float*)(ws + 67108864);             // 16 MB
  float*          l0   = (float*)(ws + 67108864);             // 256 KB (dead before x1 written)
  float*          l1   = l0 + 65536;                          // 256 KB
  unsigned short* u    = (unsigned short*)(ws + 33554432);    // overlays qa..ao (dead by MLP1)

  // fused weight-cvt + LN1 (one dispatch; all outputs ready before QKV)
  ln1_cvt<<<16384, 256, 0, stream>>>(
      x, g1, be1, h1,
      (const float4*)Wq, (const float4*)Wk, (const float4*)Wv, (const float4*)Wo,
      (const float4*)W1, (const float4*)W2,
      (ushort4*)wqkv, (ushort4*)(wqkv + 1048576), (ushort4*)(wqkv + 2097152),
      (ushort4*)wo, (ushort4*)w1, (ushort4*)w2);

  gemm_qkv_t4<<<1536, 256, 0, stream>>>(h1, wqkv, bq, bk, bv, rc, rs, qa, ka, va);
  flash_attn<<<512, 512, 0, stream>>>(qa, ka, va, ao, h1, l0, l1);
  attn_norm<<<2048, 256, 0, stream>>>(ao, h1, l0, l1, ao);
  gemm_bt<1, 64><<<dim3(16, 32), 256, 0, stream>>>(ao, wo, 1024, 1024, 2, bo, x, nullptr, x1);
  ln_kernel<<<4096, 256, 0, stream>>>(x1, g2, be2, h1);
  gemm_mlp1<<<512, 512, 0, stream>>>(h1, w1, b1m, u);
  gemm_mlp2<<<256, 512, 0, stream>>>(u, w2, b2m, x1, out);
}

// Round 16
// 344.390 us; speedup vs baseline: 1.1325x; 1.0038x over previous
//
#include <hip/hip_runtime.h>
#include <hip/hip_bf16.h>

#define B_ 2
#define N_ 2048
#define C_ 1024
#define H_ 16
#define D_ 64
#define F_ 4096
#define M_ 4096  // B_*N_

typedef __attribute__((ext_vector_type(8))) short bf16x8;
typedef __attribute__((ext_vector_type(4))) float f32x4;

__device__ inline unsigned short f2bf(float f) {
  unsigned int u = __float_as_uint(f);
  u = (u + 0x7FFFu + ((u >> 16) & 1u)) >> 16;
  return (unsigned short)u;
}
__device__ inline float bf2f(unsigned short u) {
  unsigned int x = ((unsigned int)u) << 16;
  return __uint_as_float(x);
}

// ---------------- fused: all-weights fp32->bf16  +  LayerNorm1 ---------------
__global__ __launch_bounds__(256)
void ln1_cvt(const float* __restrict__ x, const float* __restrict__ g,
             const float* __restrict__ bln, unsigned short* __restrict__ out,
             const float4* __restrict__ s0, const float4* __restrict__ s1,
             const float4* __restrict__ s2, const float4* __restrict__ s3,
             const float4* __restrict__ s4, const float4* __restrict__ s5,
             ushort4* __restrict__ d0, ushort4* __restrict__ d1,
             ushort4* __restrict__ d2, ushort4* __restrict__ d3,
             ushort4* __restrict__ d4, ushort4* __restrict__ d5) {
  const int b = blockIdx.x;
  if (b < 12288) {
    const float4* s; ushort4* d; int i;
    if      (b < 1024) { s = s0; d = d0; i = b * 256 + threadIdx.x; }
    else if (b < 2048) { s = s1; d = d1; i = (b - 1024) * 256 + threadIdx.x; }
    else if (b < 3072) { s = s2; d = d2; i = (b - 2048) * 256 + threadIdx.x; }
    else if (b < 4096) { s = s3; d = d3; i = (b - 3072) * 256 + threadIdx.x; }
    else if (b < 8192) { s = s4; d = d4; i = (b - 4096) * 256 + threadIdx.x; }
    else               { s = s5; d = d5; i = (b - 8192) * 256 + threadIdx.x; }
    float4 f = s[i];
    ushort4 o;
    o.x = f2bf(f.x); o.y = f2bf(f.y); o.z = f2bf(f.z); o.w = f2bf(f.w);
    d[i] = o;
    return;
  }
  __shared__ float red[8];
  const int row = b - 12288;
  const int t = threadIdx.x;
  const float4 xv = *(const float4*)(x + row * 1024 + t * 4);
  float s  = xv.x + xv.y + xv.z + xv.w;
  float sq = xv.x * xv.x + xv.y * xv.y + xv.z * xv.z + xv.w * xv.w;
  #pragma unroll
  for (int off = 32; off >= 1; off >>= 1) {
    s  += __shfl_down(s, off);
    sq += __shfl_down(sq, off);
  }
  const int lane = t & 63, wave = t >> 6;
  if (lane == 0) { red[wave * 2] = s; red[wave * 2 + 1] = sq; }
  __syncthreads();
  float ts = red[0] + red[2] + red[4] + red[6];
  float tq = red[1] + red[3] + red[5] + red[7];
  float mean = ts * (1.0f / 1024.0f);
  float var  = tq * (1.0f / 1024.0f) - mean * mean;
  float rstd = rsqrtf(var + 1e-6f);
  float xs[4] = {xv.x, xv.y, xv.z, xv.w};
  #pragma unroll
  for (int i = 0; i < 4; i++) {
    int c = t * 4 + i;
    float y = (xs[i] - mean) * rstd * g[c] + bln[c];
    out[row * 1024 + c] = f2bf(y);
  }
}

// ---------------- LayerNorm: fp32 in -> bf16 out (ln2) ------------------------
__global__ __launch_bounds__(256)
void ln_kernel(const float* __restrict__ x, const float* __restrict__ g,
               const float* __restrict__ b, unsigned short* __restrict__ out) {
  __shared__ float red[8];
  const int row = blockIdx.x;
  const int t = threadIdx.x;
  const float4 xv = *(const float4*)(x + row * 1024 + t * 4);
  float s  = xv.x + xv.y + xv.z + xv.w;
  float sq = xv.x * xv.x + xv.y * xv.y + xv.z * xv.z + xv.w * xv.w;
  #pragma unroll
  for (int off = 32; off >= 1; off >>= 1) {
    s  += __shfl_down(s, off);
    sq += __shfl_down(sq, off);
  }
  const int lane = t & 63, wave = t >> 6;
  if (lane == 0) { red[wave * 2] = s; red[wave * 2 + 1] = sq; }
  __syncthreads();
  float ts = red[0] + red[2] + red[4] + red[6];
  float tq = red[1] + red[3] + red[5] + red[7];
  float mean = ts * (1.0f / 1024.0f);
  float var  = tq * (1.0f / 1024.0f) - mean * mean;
  float rstd = rsqrtf(var + 1e-6f);
  float xs[4] = {xv.x, xv.y, xv.z, xv.w};
  #pragma unroll
  for (int i = 0; i < 4; i++) {
    int c = t * 4 + i;
    float y = (xs[i] - mean) * rstd * g[c] + b[c];
    out[row * 1024 + c] = f2bf(y);
  }
}

// ---------------- GEMM (128x64 tile, 3-buffer counted-vmcnt, T2, m-local) ----
// MODE 1: +bias +resid -> fp32 [O-proj]  (K=1024, grid 512, 2 blocks/CU)
template<int MODE, int BN>
__global__ __launch_bounds__(256)
void gemm_bt(const unsigned short* __restrict__ A,
             const unsigned short* __restrict__ Bw,
             int K, int Nout, int npc,
             const float* __restrict__ bias,
             const float* __restrict__ resid,
             unsigned short* __restrict__ out_bf,
             float* __restrict__ out_f32) {
  constexpr int NJ = BN / 32;
  static_assert(BN == 64, "vmcnt literal assumes 6 loads per stage");
  __shared__ unsigned short sA[3][128 * 64];
  __shared__ unsigned short sB[3][BN * 64];
  const int t = threadIdx.x;
  const int wave = t >> 6, lane = t & 63;
  const int quad = lane >> 4, l16 = lane & 15;
  const int wm = (wave & 1) * 64, wn = (wave >> 1) * (BN / 2);
  const int id = blockIdx.y * gridDim.x + blockIdx.x;
  const int xcd = id & 7, r_ = id >> 3;
  const int m_blk = xcd * 4 + (r_ & 3);
  const int n_blk = r_ >> 2;
  const int m0 = m_blk * 128, n0 = n_blk * BN;

  f32x4 acc[4][NJ];
  #pragma unroll
  for (int i = 0; i < 4; i++)
    #pragma unroll
    for (int j = 0; j < NJ; j++) acc[i][j] = (f32x4){0.f, 0.f, 0.f, 0.f};

  const int sc = (((t & 7) ^ ((t >> 3) & 7)) * 8);   // swizzled source chunk
  const unsigned short* gA = A  + (m0 + (t >> 3)) * K + sc;
  const unsigned short* gB = Bw + (n0 + (t >> 3)) * K + sc;

  auto stage = [&](int k0, int buf) {
    unsigned short* lA = &sA[buf][(wave * 8) * 64];
    unsigned short* lB = &sB[buf][(wave * 8) * 64];
    #pragma unroll
    for (int i = 0; i < 4; i++)
      __builtin_amdgcn_global_load_lds((const unsigned int*)(gA + (32 * i) * K + k0),
                                       (unsigned int*)(lA + 32 * i * 64), 16, 0, 0);
    #pragma unroll
    for (int i = 0; i < BN / 32; i++)
      __builtin_amdgcn_global_load_lds((const unsigned int*)(gB + (32 * i) * K + k0),
                                       (unsigned int*)(lB + 32 * i * 64), 16, 0, 0);
  };

  stage(0, 0);
  stage(64, 1);
  asm volatile("s_waitcnt vmcnt(6)" ::: "memory");
  __builtin_amdgcn_s_barrier();

  const int so0 = ((quad ^ (l16 & 7)) * 8);          // kk=0 read slot
  const int so1 = (((4 + quad) ^ (l16 & 7)) * 8);    // kk=1 read slot

  const int nk = K >> 6;
  int cur = 0;
  for (int kt = 0; kt < nk; kt++) {
    const unsigned short* rA = &sA[cur][0];
    const unsigned short* rB = &sB[cur][0];
    #pragma unroll
    for (int kk = 0; kk < 2; kk++) {
      const int so = kk ? so1 : so0;
      bf16x8 af[4], bfr[NJ];
      #pragma unroll
      for (int i = 0; i < 4; i++)
        af[i] = *(const bf16x8*)(&rA[(wm + i * 16 + l16) * 64 + so]);
      #pragma unroll
      for (int j = 0; j < NJ; j++)
        bfr[j] = *(const bf16x8*)(&rB[(wn + j * 16 + l16) * 64 + so]);
      __builtin_amdgcn_s_setprio(1);
      #pragma unroll
      for (int i = 0; i < 4; i++)
        #pragma unroll
        for (int j = 0; j < NJ; j++)
          acc[i][j] = __builtin_amdgcn_mfma_f32_16x16x32_bf16(af[i], bfr[j], acc[i][j], 0, 0, 0);
      __builtin_amdgcn_s_setprio(0);
    }
    if (kt + 2 < nk) {
      const int nb = (cur + 2 >= 3) ? cur - 1 : cur + 2;   // (kt+2)%3
      stage((kt + 2) * 64, nb);
      asm volatile("s_waitcnt vmcnt(6)" ::: "memory");
    } else {
      asm volatile("s_waitcnt vmcnt(0)" ::: "memory");
    }
    __builtin_amdgcn_s_barrier();
    cur = (cur == 2) ? 0 : cur + 1;
  }

  #pragma unroll
  for (int i = 0; i < 4; i++) {
    #pragma unroll
    for (int j = 0; j < NJ; j++) {
      int col = n0 + wn + j * 16 + l16;
      #pragma unroll
      for (int r = 0; r < 4; r++) {
        int row = m0 + wm + i * 16 + quad * 4 + r;
        float v = acc[i][j][r];
        if (MODE == 1 || MODE == 3) {
          out_f32[row * Nout + col] = v + bias[col] + resid[row * Nout + col];
        } else {
          v += bias[col];
          float w = v * (1.0f + 0.044715f * v * v);
          float gl = v / (1.0f + __expf(-1.5957691216f * w));
          out_bf[row * Nout + col] = f2bf(gl);
        }
      }
    }
  }
}

// ---------------- MLP2: 128x128 tile, 512 thr, 3-buffer counted-vmcnt --------
// (round-15 verified)
__global__ __launch_bounds__(512, 1)
void gemm_mlp2(const unsigned short* __restrict__ A,
               const unsigned short* __restrict__ Bw,
               const float* __restrict__ bias,
               const float* __restrict__ resid,
               float* __restrict__ out_f32) {
  const int K = 4096;
  __shared__ unsigned short sA[3][128 * 64];
  __shared__ unsigned short sB[3][128 * 64];
  const int t = threadIdx.x;
  const int wave = t >> 6, lane = t & 63;
  const int quad = lane >> 4, l16 = lane & 15;
  const int wm = (wave & 1) * 64, wn = (wave >> 1) * 32;   // 2m x 4n
  const int id = blockIdx.x;
  const int xcd = id & 7, r_ = id >> 3;        // r_ in [0,32)
  const int m_blk = xcd * 4 + (r_ & 3);        // [0,32)  A-local
  const int n_blk = r_ >> 2;                   // [0,8)
  const int m0 = m_blk * 128, n0 = n_blk * 128;

  f32x4 acc[4][2];
  #pragma unroll
  for (int i = 0; i < 4; i++)
    #pragma unroll
    for (int j = 0; j < 2; j++) acc[i][j] = (f32x4){0.f, 0.f, 0.f, 0.f};

  const int sc = (((t & 7) ^ ((t >> 3) & 7)) * 8);   // swizzled source chunk
  const unsigned short* gA = A  + (m0 + (t >> 3)) * K + sc;   // t>>3 in [0,64)
  const unsigned short* gB = Bw + (n0 + (t >> 3)) * K + sc;

  auto stage = [&](int k0, int buf) {
    #pragma unroll
    for (int i = 0; i < 2; i++)
      __builtin_amdgcn_global_load_lds((const unsigned int*)(gA + (64 * i) * K + k0),
                                       (unsigned int*)(&sA[buf][(64 * i + wave * 8) * 64]), 16, 0, 0);
    #pragma unroll
    for (int i = 0; i < 2; i++)
      __builtin_amdgcn_global_load_lds((const unsigned int*)(gB + (64 * i) * K + k0),
                                       (unsigned int*)(&sB[buf][(64 * i + wave * 8) * 64]), 16, 0, 0);
  };

  stage(0, 0);
  stage(64, 1);
  asm volatile("s_waitcnt vmcnt(4)" ::: "memory");
  __builtin_amdgcn_s_barrier();

  const int so0 = ((quad ^ (l16 & 7)) * 8);          // kk=0 read slot
  const int so1 = (((4 + quad) ^ (l16 & 7)) * 8);    // kk=1 read slot

  const int nk = K >> 6;   // 64
  int cur = 0;
  for (int kt = 0; kt < nk; kt++) {
    const unsigned short* rA = &sA[cur][0];
    const unsigned short* rB = &sB[cur][0];
    #pragma unroll
    for (int kk = 0; kk < 2; kk++) {
      const int so = kk ? so1 : so0;
      bf16x8 af[4], bfr[2];
      #pragma unroll
      for (int i = 0; i < 4; i++)
        af[i] = *(const bf16x8*)(&rA[(wm + i * 16 + l16) * 64 + so]);
      #pragma unroll
      for (int j = 0; j < 2; j++)
        bfr[j] = *(const bf16x8*)(&rB[(wn + j * 16 + l16) * 64 + so]);
      __builtin_amdgcn_s_setprio(1);
      #pragma unroll
      for (int i = 0; i < 4; i++)
        #pragma unroll
        for (int j = 0; j < 2; j++)
          acc[i][j] = __builtin_amdgcn_mfma_f32_16x16x32_bf16(af[i], bfr[j], acc[i][j], 0, 0, 0);
      __builtin_amdgcn_s_setprio(0);
    }
    if (kt + 2 < nk) {
      const int nb = (cur + 2 >= 3) ? cur - 1 : cur + 2;   // (kt+2)%3
      stage((kt + 2) * 64, nb);
      asm volatile("s_waitcnt vmcnt(4)" ::: "memory");
    } else {
      asm volatile("s_waitcnt vmcnt(0)" ::: "memory");
    }
    __builtin_amdgcn_s_barrier();
    cur = (cur == 2) ? 0 : cur + 1;
  }

  #pragma unroll
  for (int i = 0; i < 4; i++) {
    #pragma unroll
    for (int j = 0; j < 2; j++) {
      int col = n0 + wn + j * 16 + l16;
      #pragma unroll
      for (int r = 0; r < 4; r++) {
        int row = m0 + wm + i * 16 + quad * 4 + r;
        out_f32[row * 1024 + col] = acc[i][j][r] + bias[col] + resid[row * 1024 + col];
      }
    }
  }
}

// ---------------- MLP1: 256x128 tile, 512 thr, 3-buffer counted-vmcnt --------
// (round-14/15 verified)
__global__ __launch_bounds__(512, 1)
void gemm_mlp1(const unsigned short* __restrict__ A,
               const unsigned short* __restrict__ Bw,
               const float* __restrict__ bias,
               unsigned short* __restrict__ out_bf) {
  const int K = 1024;
  __shared__ unsigned short sA[3][256 * 64];
  __shared__ unsigned short sB[3][128 * 64];
  const int t = threadIdx.x;
  const int wave = t >> 6, lane = t & 63;
  const int quad = lane >> 4, l16 = lane & 15;
  const int wm = (wave >> 1) * 64, wn = (wave & 1) * 64;   // 4m x 2n
  const int id = blockIdx.x;
  const int xcd = id & 7, r_ = id >> 3;        // r_ in [0,64)
  const int m_blk = xcd * 2 + (r_ & 1);        // [0,16)  A-local
  const int n_blk = r_ >> 1;                   // [0,32)
  const int m0 = m_blk * 256, n0 = n_blk * 128;

  f32x4 acc[4][4];
  #pragma unroll
  for (int i = 0; i < 4; i++)
    #pragma unroll
    for (int j = 0; j < 4; j++) acc[i][j] = (f32x4){0.f, 0.f, 0.f, 0.f};

  const int sc = (((t & 7) ^ ((t >> 3) & 7)) * 8);   // swizzled source chunk
  const unsigned short* gA = A  + (m0 + (t >> 3)) * K + sc;   // t>>3 in [0,64)
  const unsigned short* gB = Bw + (n0 + (t >> 3)) * K + sc;

  auto stage = [&](int k0, int buf) {
    #pragma unroll
    for (int i = 0; i < 4; i++)
      __builtin_amdgcn_global_load_lds((const unsigned int*)(gA + (64 * i) * K + k0),
                                       (unsigned int*)(&sA[buf][(64 * i + wave * 8) * 64]), 16, 0, 0);
    #pragma unroll
    for (int i = 0; i < 2; i++)
      __builtin_amdgcn_global_load_lds((const unsigned int*)(gB + (64 * i) * K + k0),
                                       (unsigned int*)(&sB[buf][(64 * i + wave * 8) * 64]), 16, 0, 0);
  };

  stage(0, 0);
  stage(64, 1);
  asm volatile("s_waitcnt vmcnt(6)" ::: "memory");
  __builtin_amdgcn_s_barrier();

  const int so0 = ((quad ^ (l16 & 7)) * 8);          // kk=0 read slot
  const int so1 = (((4 + quad) ^ (l16 & 7)) * 8);    // kk=1 read slot

  const int nk = K >> 6;   // 16
  int cur = 0;
  for (int kt = 0; kt < nk; kt++) {
    const unsigned short* rA = &sA[cur][0];
    const unsigned short* rB = &sB[cur][0];
    #pragma unroll
    for (int kk = 0; kk < 2; kk++) {
      const int so = kk ? so1 : so0;
      bf16x8 af[4], bfr[4];
      #pragma unroll
      for (int i = 0; i < 4; i++)
        af[i] = *(const bf16x8*)(&rA[(wm + i * 16 + l16) * 64 + so]);
      #pragma unroll
      for (int j = 0; j < 4; j++)
        bfr[j] = *(const bf16x8*)(&rB[(wn + j * 16 + l16) * 64 + so]);
      __builtin_amdgcn_s_setprio(1);
      #pragma unroll
      for (int i = 0; i < 4; i++)
        #pragma unroll
        for (int j = 0; j < 4; j++)
          acc[i][j] = __builtin_amdgcn_mfma_f32_16x16x32_bf16(af[i], bfr[j], acc[i][j], 0, 0, 0);
      __builtin_amdgcn_s_setprio(0);
    }
    if (kt + 2 < nk) {
      const int nb = (cur + 2 >= 3) ? cur - 1 : cur + 2;   // (kt+2)%3
      stage((kt + 2) * 64, nb);
      asm volatile("s_waitcnt vmcnt(6)" ::: "memory");
    } else {
      asm volatile("s_waitcnt vmcnt(0)" ::: "memory");
    }
    __builtin_amdgcn_s_barrier();
    cur = (cur == 2) ? 0 : cur + 1;
  }

  #pragma unroll
  for (int i = 0; i < 4; i++) {
    #pragma unroll
    for (int j = 0; j < 4; j++) {
      int col = n0 + wn + j * 16 + l16;
      float bb = bias[col];
      #pragma unroll
      for (int r = 0; r < 4; r++) {
        int row = m0 + wm + i * 16 + quad * 4 + r;
        float v = acc[i][j][r] + bb;
        float w = v * (1.0f + 0.044715f * v * v);
        float gl = v / (1.0f + __expf(-1.5957691216f * w));
        out_bf[row * 4096 + col] = f2bf(gl);
      }
    }
  }
}

// ---------------- QKV GEMM on the T4 skeleton, RoPE epilogue -----------------
// (round-12..15 verified)
__global__ __launch_bounds__(256)
void gemm_qkv_t4(const unsigned short* __restrict__ A,
                 const unsigned short* __restrict__ Bw,
                 const float* __restrict__ bq, const float* __restrict__ bk,
                 const float* __restrict__ bv,
                 const float* __restrict__ rc, const float* __restrict__ rs,
                 unsigned short* __restrict__ qo, unsigned short* __restrict__ ko,
                 unsigned short* __restrict__ vt) {
  const int K = C_;
  __shared__ unsigned short sA[3][128 * 64];
  __shared__ unsigned short sB[3][64 * 64];
  const int t = threadIdx.x;
  const int wave = t >> 6, lane = t & 63;
  const int quad = lane >> 4, l16 = lane & 15;
  const int wm = wave * 32;                        // 4m x 1n wave grid
  const int id = blockIdx.x;                       // [0,1536)
  const int xcd = id & 7, r_ = id >> 3;            // r_ in [0,192)
  const int m_blk = xcd * 4 + (r_ & 3);            // [0,32)  A-local
  const int n_blk = r_ >> 2;                       // [0,48)
  const int m0 = m_blk * 128, n0 = n_blk * 64;

  f32x4 acc[2][4];
  #pragma unroll
  for (int i = 0; i < 2; i++)
    #pragma unroll
    for (int j = 0; j < 4; j++) acc[i][j] = (f32x4){0.f, 0.f, 0.f, 0.f};

  const int sc = (((t & 7) ^ ((t >> 3) & 7)) * 8);
  const unsigned short* gA = A  + (m0 + (t >> 3)) * K + sc;
  const unsigned short* gB = Bw + (n0 + (t >> 3)) * K + sc;

  auto stage = [&](int k0, int buf) {
    unsigned short* lA = &sA[buf][(wave * 8) * 64];
    unsigned short* lB = &sB[buf][(wave * 8) * 64];
    #pragma unroll
    for (int i = 0; i < 4; i++)
      __builtin_amdgcn_global_load_lds((const unsigned int*)(gA + (32 * i) * K + k0),
                                       (unsigned int*)(lA + 32 * i * 64), 16, 0, 0);
    #pragma unroll
    for (int i = 0; i < 2; i++)
      __builtin_amdgcn_global_load_lds((const unsigned int*)(gB + (32 * i) * K + k0),
                                       (unsigned int*)(lB + 32 * i * 64), 16, 0, 0);
  };

  stage(0, 0);
  stage(64, 1);
  asm volatile("s_waitcnt vmcnt(6)" ::: "memory");
  __builtin_amdgcn_s_barrier();

  const int so0 = ((quad ^ (l16 & 7)) * 8);
  const int so1 = (((4 + quad) ^ (l16 & 7)) * 8);

  const int nk = K >> 6;   // 16
  int cur = 0;
  for (int kt = 0; kt < nk; kt++) {
    const unsigned short* rA = &sA[cur][0];
    const unsigned short* rB = &sB[cur][0];
    #pragma unroll
    for (int kk = 0; kk < 2; kk++) {
      const int so = kk ? so1 : so0;
      bf16x8 af[2], bfr[4];
      #pragma unroll
      for (int i = 0; i < 2; i++)
        af[i] = *(const bf16x8*)(&rA[(wm + i * 16 + l16) * 64 + so]);
      #pragma unroll
      for (int j = 0; j < 4; j++)
        bfr[j] = *(const bf16x8*)(&rB[(j * 16 + l16) * 64 + so]);
      __builtin_amdgcn_s_setprio(1);
      #pragma unroll
      for (int i = 0; i < 2; i++)
        #pragma unroll
        for (int j = 0; j < 4; j++)
          acc[i][j] = __builtin_amdgcn_mfma_f32_16x16x32_bf16(af[i], bfr[j], acc[i][j], 0, 0, 0);
      __builtin_amdgcn_s_setprio(0);
    }
    if (kt + 2 < nk) {
      const int nb = (cur + 2 >= 3) ? cur - 1 : cur + 2;   // (kt+2)%3
      stage((kt + 2) * 64, nb);
      asm volatile("s_waitcnt vmcnt(6)" ::: "memory");
    } else {
      asm volatile("s_waitcnt vmcnt(0)" ::: "memory");
    }
    __builtin_amdgcn_s_barrier();
    cur = (cur == 2) ? 0 : cur + 1;
  }

  const int rgn = n_blk >> 4;                 // 0=q, 1=k, 2=v
  const int h   = n_blk & 15;

  if (rgn == 2) {
    #pragma unroll
    for (int i = 0; i < 2; i++) {
      int row0 = m0 + wm + i * 16 + quad * 4;      // token of r=0
      int bidx = row0 >> 11, n0r = row0 & 2047;
      #pragma unroll
      for (int j = 0; j < 4; j++) {
        int d = j * 16 + l16;
        float bb = bv[h * 64 + d];
        __hip_bfloat162 p01 = __float22bfloat162_rn(float2{acc[i][j][0] + bb, acc[i][j][1] + bb});
        __hip_bfloat162 p23 = __float22bfloat162_rn(float2{acc[i][j][2] + bb, acc[i][j][3] + bb});
        unsigned int u01, u23;
        __builtin_memcpy(&u01, &p01, 4);
        __builtin_memcpy(&u23, &p23, 4);
        *(uint2*)(vt + (((bidx * 16 + h) * 64) + d) * 2048 + n0r) = make_uint2(u01, u23);
      }
    }
  } else {
    const float* bia = (rgn == 0) ? bq : bk;
    unsigned short* outp = (rgn == 0) ? qo : ko;
    #pragma unroll
    for (int i = 0; i < 2; i++) {
      #pragma unroll
      for (int r = 0; r < 4; r++) {
        int row = m0 + wm + i * 16 + quad * 4 + r;
        int bidx = row >> 11, n = row & 2047;
        #pragma unroll
        for (int j = 0; j < 4; j++) {
          int d = j * 16 + l16;
          int c = h * 64 + d;                      // within-region column
          int oi = ((bidx * 16 + h) * 2048 + n) * 64 + d;
          float val = acc[i][j][r] + bia[c];
          float pv  = acc[i][j ^ 2][r] + bia[c ^ 32];
          float rot = (j < 2) ? -pv : pv;          // rotate_half
          float y = val * rc[n * 64 + d] + rot * rs[n * 64 + d];
          if (rgn == 0) y *= 0.125f;               // fold D^-0.5 into q
          outp[oi] = f2bf(y);
        }
      }
    }
  }
}

// ---------------- Flash attention v8: QBLK=128, 3 blocks/CU ------------------
// v7 at 2 blocks/CU (Occ 33%) was latency-bound. v8: one 16-row q-tile per
// wave (QBLK 256->128), sPt halves -> LDS 50KB -> 3 blocks/CU (24 waves),
// grid 32bh x 16qb x 2kvh = 1024. K/V staging DMA doubles (262MB ~ 5TB/s
// aggregate L2, well under ceiling; HBM unaffected). Body = verified v7
// specialized to a single qt. Partial/attn_norm format unchanged.
__global__ __launch_bounds__(512)
void flash_attn(const unsigned short* __restrict__ q,
                const unsigned short* __restrict__ k,
                const unsigned short* __restrict__ vt,
                unsigned short* __restrict__ o0h,
                unsigned short* __restrict__ o1h,
                float* __restrict__ l0g, float* __restrict__ l1g) {
  __shared__ unsigned short sK[2][64 * 64];
  __shared__ unsigned short sVt[2][64 * 64];
  __shared__ unsigned short sPt[8][16 * 72];
  const int t = threadIdx.x;
  const int wave = t >> 6, lane = t & 63;
  const int quad = lane >> 4, l16 = lane & 15;
  const int id = blockIdx.x;
  const int bh = (id & 7) * 4 + ((id >> 3) & 3);  // 4 heads per XCD (L2-local)
  const int qb = (id >> 5) & 15;                  // 16 blocks of 128 q-rows
  const int kvh = id >> 9;                        // kv half
  const int base = bh * (N_ * D_);

  bf16x8 qa[2];
  {
    int qrow = qb * 128 + wave * 16 + l16;
    #pragma unroll
    for (int kk = 0; kk < 2; kk++)
      qa[kk] = *(const bf16x8*)(q + base + qrow * D_ + kk * 32 + quad * 8);
  }
  float l_i = 0.f;
  f32x4 o_acc[4];
  #pragma unroll
  for (int dt = 0; dt < 4; dt++) o_acc[dt] = (f32x4){0.f, 0.f, 0.f, 0.f};

  const int sc = (((t & 7) ^ ((t >> 3) & 7)) * 8);   // T2 source chunk
  const unsigned short* gK  = k  + base + (t >> 3) * 64 + sc;
  const unsigned short* gVt = vt + bh * (64 * 2048) + (t >> 3) * 2048 + sc;

  auto stage = [&](int kt, int buf) {
    __builtin_amdgcn_global_load_lds((const unsigned int*)(gK + kt * 64 * 64),
                                     (unsigned int*)(&sK[buf][(wave * 8) * 64]), 16, 0, 0);
    __builtin_amdgcn_global_load_lds((const unsigned int*)(gVt + kt * 64),
                                     (unsigned int*)(&sVt[buf][(wave * 8) * 64]), 16, 0, 0);
  };
  const int kt0 = kvh * 16, kt1 = kt0 + 16;
  stage(kt0, 0);
  __syncthreads();

  const int so0 = ((quad ^ (l16 & 7)) * 8);          // kk=0 read slot
  const int so1 = (((4 + quad) ^ (l16 & 7)) * 8);    // kk=1 read slot

  for (int kt = kt0; kt < kt1; kt++) {
    const int cur = kt & 1;
    if (kt + 1 < kt1) stage(kt + 1, cur ^ 1);

    f32x4 s_acc[4];
    __builtin_amdgcn_s_setprio(1);
    #pragma unroll
    for (int nt = 0; nt < 4; nt++) {
      bf16x8 kb0 = *(const bf16x8*)(&sK[cur][(nt * 16 + l16) * 64 + so0]);
      bf16x8 kb1 = *(const bf16x8*)(&sK[cur][(nt * 16 + l16) * 64 + so1]);
      f32x4 a = (f32x4){0.f, 0.f, 0.f, 0.f};
      a = __builtin_amdgcn_mfma_f32_16x16x32_bf16(kb0, qa[0], a, 0, 0, 0);
      a = __builtin_amdgcn_mfma_f32_16x16x32_bf16(kb1, qa[1], a, 0, 0, 0);
      s_acc[nt] = a;
    }
    __builtin_amdgcn_s_setprio(0);
    {
      float rsum = 0.f;
      #pragma unroll
      for (int nt = 0; nt < 4; nt++)
        #pragma unroll
        for (int r = 0; r < 4; r++) {
          float p = __expf(s_acc[nt][r]);
          s_acc[nt][r] = p;
          rsum += p;
        }
      rsum += __shfl_xor(rsum, 16);
      rsum += __shfl_xor(rsum, 32);
      l_i += rsum;
      #pragma unroll
      for (int nt = 0; nt < 4; nt++) {
        __hip_bfloat162 p01 = __float22bfloat162_rn(float2{s_acc[nt][0], s_acc[nt][1]});
        __hip_bfloat162 p23 = __float22bfloat162_rn(float2{s_acc[nt][2], s_acc[nt][3]});
        unsigned int u01, u23;
        __builtin_memcpy(&u01, &p01, 4);
        __builtin_memcpy(&u23, &p23, 4);
        *(uint2*)(&sPt[wave][l16 * 72 + nt * 16 + quad * 4]) = make_uint2(u01, u23);
      }
    }
    __asm__ volatile("s_waitcnt lgkmcnt(0)" ::: "memory");
    bf16x8 pt0 = *(const bf16x8*)(&sPt[wave][l16 * 72 + quad * 8]);
    bf16x8 pt1 = *(const bf16x8*)(&sPt[wave][l16 * 72 + 32 + quad * 8]);
    __builtin_amdgcn_s_setprio(1);
    #pragma unroll
    for (int dt = 0; dt < 4; dt++) {
      int d0 = dt * 16 + l16;
      bf16x8 va0 = *(const bf16x8*)(&sVt[cur][d0 * 64 + so0]);
      bf16x8 va1 = *(const bf16x8*)(&sVt[cur][d0 * 64 + so1]);
      o_acc[dt] = __builtin_amdgcn_mfma_f32_16x16x32_bf16(va0, pt0, o_acc[dt], 0, 0, 0);
      o_acc[dt] = __builtin_amdgcn_mfma_f32_16x16x32_bf16(va1, pt1, o_acc[dt], 0, 0, 0);
    }
    __builtin_amdgcn_s_setprio(0);
    __syncthreads();
  }

  unsigned short* op = kvh ? o1h : o0h;
  float* lp = kvh ? l1g : l0g;
  const int b = bh >> 4, h = bh & 15;
  {
    const int qrow = qb * 128 + wave * 16 + l16;
    if (quad == 0) lp[bh * 2048 + qrow] = l_i;
    const int tok = b * N_ + qrow;
    #pragma unroll
    for (int dt = 0; dt < 4; dt++) {
      __hip_bfloat162 p01 = __float22bfloat162_rn(float2{o_acc[dt][0], o_acc[dt][1]});
      __hip_bfloat162 p23 = __float22bfloat162_rn(float2{o_acc[dt][2], o_acc[dt][3]});
      unsigned int u01, u23;
      __builtin_memcpy(&u01, &p01, 4);
      __builtin_memcpy(&u23, &p23, 4);
      int col = h * 64 + dt * 16 + quad * 4;
      *(uint2*)(op + tok * C_ + col) = make_uint2(u01, u23);
    }
  }
}

// ---------------- combine the two kv halves: ao = (o0+o1)/(l0+l1) ------------
__global__ __launch_bounds__(256)
void attn_norm(const unsigned short* __restrict__ o0h,
               const unsigned short* __restrict__ o1h,
               const float* __restrict__ l0g, const float* __restrict__ l1g,
               unsigned short* __restrict__ o) {
  const int i = (blockIdx.x * 256 + threadIdx.x) * 8;
  const int row = i >> 10, c = i & 1023;
  const int h = c >> 6;
  const int b = row >> 11, n = row & 2047;
  const int li = (b * 16 + h) * 2048 + n;
  const float inv = 1.0f / (l0g[li] + l1g[li]);
  ushort4 a0 = *(const ushort4*)(o0h + i);
  ushort4 a1 = *(const ushort4*)(o0h + i + 4);
  ushort4 b0 = *(const ushort4*)(o1h + i);
  ushort4 b1 = *(const ushort4*)(o1h + i + 4);
  ushort4 r0, r1;
  r0.x = f2bf((bf2f(a0.x) + bf2f(b0.x)) * inv);
  r0.y = f2bf((bf2f(a0.y) + bf2f(b0.y)) * inv);
  r0.z = f2bf((bf2f(a0.z) + bf2f(b0.z)) * inv);
  r0.w = f2bf((bf2f(a0.w) + bf2f(b0.w)) * inv);
  r1.x = f2bf((bf2f(a1.x) + bf2f(b1.x)) * inv);
  r1.y = f2bf((bf2f(a1.y) + bf2f(b1.y)) * inv);
  r1.z = f2bf((bf2f(a1.z) + bf2f(b1.z)) * inv);
  r1.w = f2bf((bf2f(a1.w) + bf2f(b1.w)) * inv);
  *(ushort4*)(o + i) = r0;
  *(ushort4*)(o + i + 4) = r1;
}

// ---------------- launcher ---------------------------------------------------
extern "C" void kernel_launch(void* const* d_in, const int* in_sizes, int n_in,
                              void* d_out, int out_size, void* d_ws, size_t ws_size,
                              hipStream_t stream) {
  const float* x   = (const float*)d_in[0];
  const float* rc  = (const float*)d_in[1];
  const float* rs  = (const float*)d_in[2];
  const float* g1  = (const float*)d_in[3];
  const float* be1 = (const float*)d_in[4];
  const float* Wq  = (const float*)d_in[5];
  const float* bq  = (const float*)d_in[6];
  const float* Wk  = (const float*)d_in[7];
  const float* bk  = (const float*)d_in[8];
  const float* Wv  = (const float*)d_in[9];
  const float* bv  = (const float*)d_in[10];
  const float* Wo  = (const float*)d_in[11];
  const float* bo  = (const float*)d_in[12];
  const float* g2  = (const float*)d_in[13];
  const float* be2 = (const float*)d_in[14];
  const float* W1  = (const float*)d_in[15];
  const float* b1m = (const float*)d_in[16];
  const float* W2  = (const float*)d_in[17];
  const float* b2m = (const float*)d_in[18];
  float* out = (float*)d_out;

  char* ws = (char*)d_ws;
  unsigned short* wqkv = (unsigned short*)(ws + 0);           // 6 MB
  unsigned short* wo   = (unsigned short*)(ws + 6291456);     // 2 MB
  unsigned short* w1   = (unsigned short*)(ws + 8388608);     // 8 MB
  unsigned short* w2   = (unsigned short*)(ws + 16777216);    // 8 MB
  unsigned short* h1   = (unsigned short*)(ws + 25165824);    // 8 MB (ln out; attn o1 partial; ln2 out)
  unsigned short* qa   = (unsigned short*)(ws + 33554432);    // 8 MB
  unsigned short* ka   = (unsigned short*)(ws + 41943040);    // 8 MB
  unsigned short* va   = (unsigned short*)(ws + 50331648);    // 8 MB (V^T: B*H x D x N)
  unsigned short* ao   = (unsigned short*)(ws + 58720256);    // 8 MB (attn o0 partial -> normalized)
  float*          x1   = (float*)(ws + 67108864);             // 16 MB
  float*          l0   = (float*)(ws + 67108864);             // 256 KB (dead before x1 written)
  float*          l1   = l0 + 65536;                          // 256 KB
  unsigned short* u    = (unsigned short*)(ws + 33554432);    // overlays qa..ao (dead by MLP1)

  // fused weight-cvt + LN1 (one dispatch; all outputs ready before QKV)
  ln1_cvt<<<16384, 256, 0, stream>>>(
      x, g1, be1, h1,
      (const float4*)Wq, (const float4*)Wk, (const float4*)Wv, (const float4*)Wo,
      (const float4*)W1, (const float4*)W2,
      (ushort4*)wqkv, (ushort4*)(wqkv + 1048576), (ushort4*)(wqkv + 2097152),
      (ushort4*)wo, (ushort4*)w1, (ushort4*)w2);

  gemm_qkv_t4<<<1536, 256, 0, stream>>>(h1, wqkv, bq, bk, bv, rc, rs, qa, ka, va);
  flash_attn<<<1024, 512, 0, stream>>>(qa, ka, va, ao, h1, l0, l1);
  attn_norm<<<2048, 256, 0, stream>>>(ao, h1, l0, l1, ao);
  gemm_bt<1, 64><<<dim3(16, 32), 256, 0, stream>>>(ao, wo, 1024, 1024, 2, bo, x, nullptr, x1);
  ln_kernel<<<4096, 256, 0, stream>>>(x1, g2, be2, h1);
  gemm_mlp1<<<512, 512, 0, stream>>>(h1, w1, b1m, u);
  gemm_mlp2<<<256, 512, 0, stream>>>(u, w2, b2m, x1, out);
}